// Round 6
// baseline (797.484 us; speedup 1.0000x reference)
//
#include <hip/hip_runtime.h>
#include <cstddef>
#include <cstdint>

#define N_NODES 102400
#define N_EDGES 3276800
#define N_GRAPHS 1024
#define NBUCK 400            // node >> 8 -> 400 buckets of 256 nodes
#define NBB 512              // binning blocks
#define EPB 6400             // edges per binning block (NBB*EPB == N_EDGES)
#define MAXB 12288           // per-bucket staging capacity in k_csr (avg 8192)
#define N64 ((size_t)N_NODES * 64)

typedef unsigned short ushortT;
typedef unsigned int uintT;
typedef __attribute__((ext_vector_type(8))) short bf16x8;
typedef __attribute__((ext_vector_type(4))) float f32x4;

__device__ __forceinline__ float b2f(ushortT h) {
    return __uint_as_float(((uintT)h) << 16);
}
__device__ __forceinline__ ushortT f2b(float f) {
    uintT u = __float_as_uint(f);
    uintT r = (u + 0x7fffu + ((u >> 16) & 1u)) >> 16;
    return (ushortT)r;
}

// ---------------------------------------------------------------------------
// Pass A: per-block LDS histograms of dst AND src coarse buckets.
// Zero global atomics, zero scattered writes.
// ---------------------------------------------------------------------------
__global__ __launch_bounds__(256) void k_binA(const int* __restrict__ src,
                                              const int* __restrict__ dst,
                                              int* __restrict__ blkCntD,
                                              int* __restrict__ blkCntS) {
    __shared__ int hd[NBUCK], hs[NBUCK];
    int t = threadIdx.x;
    for (int i = t; i < NBUCK; i += 256) { hd[i] = 0; hs[i] = 0; }
    __syncthreads();
    int base = blockIdx.x * EPB;
    for (int k = 0; k < EPB / 256; k++) {
        int e = base + k * 256 + t;
        atomicAdd(&hd[dst[e] >> 8], 1);
        atomicAdd(&hs[src[e] >> 8], 1);
    }
    __syncthreads();
    for (int i = t; i < NBUCK; i += 256) {
        blkCntD[(size_t)blockIdx.x * NBUCK + i] = hd[i];
        blkCntS[(size_t)blockIdx.x * NBUCK + i] = hs[i];
    }
}

// Per-bucket exclusive scan over NBB block counts -> blkRel[block][buck],
// plus bucket totals. (launched once for D, once for S)
__global__ __launch_bounds__(256) void k_bbase(const int* __restrict__ blkCnt,
                                               int* __restrict__ blkRel,
                                               int* __restrict__ bucketTot) {
    __shared__ int sc[NBB];
    int b = blockIdx.x, t = threadIdx.x;
    int v0 = blkCnt[(size_t)t * NBUCK + b];
    int v1 = blkCnt[(size_t)(t + 256) * NBUCK + b];
    sc[t] = v0; sc[t + 256] = v1;
    __syncthreads();
    for (int o = 1; o < NBB; o <<= 1) {
        int x0 = (t >= o) ? sc[t - o] : 0;
        int x1 = (t + 256 >= o) ? sc[t + 256 - o] : 0;
        __syncthreads();
        sc[t] += x0; sc[t + 256] += x1;
        __syncthreads();
    }
    blkRel[(size_t)t * NBUCK + b] = sc[t] - v0;
    blkRel[(size_t)(t + 256) * NBUCK + b] = sc[t + 256] - v1;
    if (t == 255) bucketTot[b] = sc[NBB - 1];
}

// Serial scans of 400 bucket totals -> bucket bases (D and S), rowp tail.
__global__ void k_bscan(const int* __restrict__ bucketTotD,
                        const int* __restrict__ bucketTotS,
                        int* __restrict__ binBaseD,
                        int* __restrict__ binBaseS,
                        int* __restrict__ rowp) {
    int t = threadIdx.x;
    if (t == 0) {
        int run = 0;
        for (int i = 0; i < NBUCK; i++) { binBaseD[i] = run; run += bucketTotD[i]; }
        binBaseD[NBUCK] = run;
        rowp[N_NODES] = run;
    } else if (t == 64) {
        int run = 0;
        for (int i = 0; i < NBUCK; i++) { binBaseS[i] = run; run += bucketTotS[i]; }
        binBaseS[NBUCK] = run;
    }
}

// ---------------------------------------------------------------------------
// Pass B (dst): deterministic LDS-staged counting sort into dst-bucket
// regions. No global atomics; flush in bucket order -> coalesced stores.
// edsD: x = (src<<8)|dstLow, y = attr bits.
// ---------------------------------------------------------------------------
__global__ __launch_bounds__(256) void k_binB(const int* __restrict__ src,
                                              const int* __restrict__ dst,
                                              const float* __restrict__ attr,
                                              const int* __restrict__ blkCnt,
                                              const int* __restrict__ blkRel,
                                              const int* __restrict__ binBaseD,
                                              int2* __restrict__ edsD) {
    __shared__ int spos[EPB];       // global position per staged slot
    __shared__ int sx[EPB];         // payload x (also scan scratch)
    __shared__ int sy[EPB];         // payload y
    __shared__ int lcur[NBUCK];     // local cursors
    __shared__ int delta[NBUCK];    // global base - local base per bucket
    int bx = blockIdx.x, t = threadIdx.x;

    // local exclusive scan of this block's 400 bucket counts (padded to 512)
    int* sc = sx;
    int v0 = blkCnt[(size_t)bx * NBUCK + t];
    int v1 = (t + 256 < NBUCK) ? blkCnt[(size_t)bx * NBUCK + t + 256] : 0;
    sc[t] = v0; sc[t + 256] = v1;
    __syncthreads();
    for (int o = 1; o < 512; o <<= 1) {
        int x0 = (t >= o) ? sc[t - o] : 0;
        int x1 = (t + 256 >= o) ? sc[t + 256 - o] : 0;
        __syncthreads();
        sc[t] += x0; sc[t + 256] += x1;
        __syncthreads();
    }
    {
        int e0 = sc[t] - v0;
        lcur[t] = e0;
        delta[t] = binBaseD[t] + blkRel[(size_t)bx * NBUCK + t] - e0;
        if (t + 256 < NBUCK) {
            int e1 = sc[t + 256] - v1;
            lcur[t + 256] = e1;
            delta[t + 256] = binBaseD[t + 256] + blkRel[(size_t)bx * NBUCK + t + 256] - e1;
        }
    }
    __syncthreads();

    int base = bx * EPB;
    for (int k = 0; k < EPB / 256; k++) {
        int e = base + k * 256 + t;
        int s = src[e], d = dst[e];
        int a = __float_as_int(attr[e]);
        int bkt = d >> 8;
        int lp = atomicAdd(&lcur[bkt], 1);
        spos[lp] = lp + delta[bkt];
        sx[lp] = (s << 8) | (d & 255);
        sy[lp] = a;
    }
    __syncthreads();
    for (int k = 0; k < EPB / 256; k++) {
        int i = k * 256 + t;
        edsD[spos[i]] = make_int2(sx[i], sy[i]);
    }
}

// ---------------------------------------------------------------------------
// Pass B (src): same deterministic counting sort keyed by src bucket.
// edsS: x = srcLow, y = attr bits.
// ---------------------------------------------------------------------------
__global__ __launch_bounds__(256) void k_binBS(const int* __restrict__ src,
                                               const float* __restrict__ attr,
                                               const int* __restrict__ blkCnt,
                                               const int* __restrict__ blkRel,
                                               const int* __restrict__ binBaseS,
                                               int2* __restrict__ edsS) {
    __shared__ int spos[EPB];
    __shared__ int sx[EPB];
    __shared__ int sy[EPB];
    __shared__ int lcur[NBUCK];
    __shared__ int delta[NBUCK];
    int bx = blockIdx.x, t = threadIdx.x;

    int* sc = sx;
    int v0 = blkCnt[(size_t)bx * NBUCK + t];
    int v1 = (t + 256 < NBUCK) ? blkCnt[(size_t)bx * NBUCK + t + 256] : 0;
    sc[t] = v0; sc[t + 256] = v1;
    __syncthreads();
    for (int o = 1; o < 512; o <<= 1) {
        int x0 = (t >= o) ? sc[t - o] : 0;
        int x1 = (t + 256 >= o) ? sc[t + 256 - o] : 0;
        __syncthreads();
        sc[t] += x0; sc[t + 256] += x1;
        __syncthreads();
    }
    {
        int e0 = sc[t] - v0;
        lcur[t] = e0;
        delta[t] = binBaseS[t] + blkRel[(size_t)bx * NBUCK + t] - e0;
        if (t + 256 < NBUCK) {
            int e1 = sc[t + 256] - v1;
            lcur[t + 256] = e1;
            delta[t + 256] = binBaseS[t + 256] + blkRel[(size_t)bx * NBUCK + t + 256] - e1;
        }
    }
    __syncthreads();

    int base = bx * EPB;
    for (int k = 0; k < EPB / 256; k++) {
        int e = base + k * 256 + t;
        int s = src[e];
        int a = __float_as_int(attr[e]);
        int bkt = s >> 8;
        int lp = atomicAdd(&lcur[bkt], 1);
        spos[lp] = lp + delta[bkt];
        sx[lp] = s & 255;
        sy[lp] = a;
    }
    __syncthreads();
    for (int k = 0; k < EPB / 256; k++) {
        int i = k * 256 + t;
        edsS[spos[i]] = make_int2(sx[i], sy[i]);
    }
}

// Per-bucket weighted degree via LDS float accumulation -> dinv directly.
__global__ __launch_bounds__(256) void k_deg(const int2* __restrict__ edsS,
                                             const int* __restrict__ binBaseS,
                                             float* __restrict__ dinv) {
    __shared__ float degL[256];
    int b = blockIdx.x, t = threadIdx.x;
    degL[t] = 0.f;
    __syncthreads();
    int s0 = binBaseS[b], s1 = binBaseS[b + 1];
    for (int i = s0 + t; i < s1; i += 256) {
        int2 e = edsS[i];
        atomicAdd(&degL[e.x], __int_as_float(e.y));
    }
    __syncthreads();
    float d = degL[t];
    dinv[b * 256 + t] = d > 0.f ? rsqrtf(d) : 0.f;
}

// ---------------------------------------------------------------------------
// Per-bucket exact CSR, LDS-staged. cedge = -attr * dinv[src] * dinv[dst].
// Counting-sort key refined to (dstLow, src>>13): each row's edges come out
// sorted by src at 8192-node granularity -> during SpMM, the concurrently
// gathered src window shrinks ~2x per loop phase (L2 locality on all passes).
// ---------------------------------------------------------------------------
__global__ __launch_bounds__(512) void k_csr(const int2* __restrict__ edsD,
                                             const int* __restrict__ binBaseD,
                                             const float* __restrict__ dinvG,
                                             int* __restrict__ rowp,
                                             int2* __restrict__ cedge) {
    __shared__ int cnt2[256 * 16];   // (dstLow, src>>13) counters -> cursors
    __shared__ int cntL[256];        // per-row totals -> prefix
    __shared__ float dL[256];
    __shared__ int2 st[MAXB];
    int b = blockIdx.x, t = threadIdx.x;
    for (int i = t; i < 256 * 16; i += 512) cnt2[i] = 0;
    if (t < 256) dL[t] = dinvG[b * 256 + t];
    __syncthreads();
    int s0 = binBaseD[b], s1 = binBaseD[b + 1];
    for (int i = s0 + t; i < s1; i += 512) {
        int2 e = edsD[i];
        atomicAdd(&cnt2[(e.x & 255) * 16 + ((e.x >> 8) >> 13)], 1);
    }
    __syncthreads();
    // per-row totals + in-place exclusive scan over the 16 src bands
    if (t < 256) {
        int run = 0;
#pragma unroll
        for (int o = 0; o < 16; o++) {
            int c = cnt2[t * 16 + o];
            cnt2[t * 16 + o] = run;
            run += c;
        }
        cntL[t] = run;
    }
    __syncthreads();
    int v = (t < 256) ? cntL[t] : 0;
    for (int o = 1; o < 256; o <<= 1) {
        int x = (t < 256 && t >= o) ? cntL[t - o] : 0;
        __syncthreads();
        if (t < 256) cntL[t] += x;
        __syncthreads();
    }
    if (t < 256) {
        int excl = cntL[t] - v;
        rowp[b * 256 + t] = s0 + excl;
        // make band cursors absolute within the staging buffer
#pragma unroll
        for (int o = 0; o < 16; o++) cnt2[t * 16 + o] += excl;
    }
    __syncthreads();
    for (int i = s0 + t; i < s1; i += 512) {
        int2 e = edsD[i];
        int dl = e.x & 255;
        int sg = e.x >> 8;
        float w = -__int_as_float(e.y) * dinvG[sg] * dL[dl];
        int p = atomicAdd(&cnt2[dl * 16 + (sg >> 13)], 1);
        st[p] = make_int2(sg, __float_as_int(w));
    }
    __syncthreads();
    int n = s1 - s0;
    for (int i = t; i < n; i += 512) cedge[s0 + i] = st[i];
}

// ---------------------------------------------------------------------------
// x -> slot-major bf16 hi/lo tables: Xhi/Xlo[s][n][64], s = k>>6
// ---------------------------------------------------------------------------
__global__ __launch_bounds__(256) void k_cast(const float* __restrict__ x,
                                              ushortT* __restrict__ Xhi,
                                              ushortT* __restrict__ Xlo) {
    int i = blockIdx.x * 256 + threadIdx.x;   // [0, N*32)
    int n = i >> 5;
    int kq = (i & 31) * 4;
    float4 v = ((const float4*)x)[i];
    int s = kq >> 6, kk = kq & 63;
    size_t o = (size_t)s * N64 + (size_t)n * 64 + kk;
    ushort4 h, l;
    h.x = f2b(v.x); l.x = f2b(v.x - b2f(h.x));
    h.y = f2b(v.y); l.y = f2b(v.y - b2f(h.y));
    h.z = f2b(v.z); l.z = f2b(v.z - b2f(h.z));
    h.w = f2b(v.w); l.w = f2b(v.w - b2f(h.w));
    *(ushort4*)(Xhi + o) = h;
    *(ushort4*)(Xlo + o) = l;
}

// ---------------------------------------------------------------------------
// Weight prep: transposed [N][K] bf16 hi/lo tables.
// ---------------------------------------------------------------------------
template <int L>
__global__ void k_wprep(const float* __restrict__ w, ushortT* __restrict__ Wth,
                        ushortT* __restrict__ Wtl) {
    int i = blockIdx.x * 256 + threadIdx.x;
    float v;
    if (L == 1) {
        if (i >= 192 * 128) return;
        int n = i / 128, k = i % 128;
        if (n < 64)       v = w[k * 64 + n] - w[16384 + k * 64 + n];
        else if (n < 128) v = w[8192 + k * 64 + (n - 64)];
        else              v = w[16384 + k * 64 + (n - 128)];
    } else if (L == 2) {
        if (i >= 192 * 64) return;
        int n = i / 64, k = i % 64;
        if (n < 64)       v = w[k * 64 + n] - w[8192 + k * 64 + n];
        else if (n < 128) v = w[4096 + k * 64 + (n - 64)];
        else              v = w[8192 + k * 64 + (n - 128)];
    } else {
        if (i >= 128 * 192) return;
        int n = i / 192, k = i % 192;
        v = w[(k >> 6) * 8192 + (k & 63) * 128 + n];
    }
    ushortT h = f2b(v);
    Wth[i] = h;
    Wtl[i] = f2b(v - b2f(h));
}

// ---------------------------------------------------------------------------
// MFMA GEMM v2: one block = 256 rows x ALL NTOT cols (no blockIdx.y
// redundancy -> A read once). W (hi+lo) staged in LDS in 64-wide K-chunks
// (pad stride 72 shorts -> bank-stride 4 mod 32, conflict-free floor).
// 8 waves x (32 rows x NTOT cols) each; per k-step per wave:
// 4 global A loads + 2*NCT ds_reads + 6*NCT MFMAs (MFMA-dominated mix).
// acc = Ahi*Whi + Alo*Whi + Ahi*Wlo  (~fp32 accuracy).
// MODE 0: ct<8 -> fp32 out[n*128 + ct*16+m]; ct>=8 -> bf16 outb[n*64 + ...]
// MODE 1: fp32 out[n*128 + col] = relu(acc + bias[col])
// ---------------------------------------------------------------------------
template <int KTOT, int NTOT, int MODE>
__global__ __launch_bounds__(512) void k_mgemm(
    const ushortT* __restrict__ Ah0, const ushortT* __restrict__ Ah1,
    const ushortT* __restrict__ Ah2, const ushortT* __restrict__ Al0,
    const ushortT* __restrict__ Al1, const ushortT* __restrict__ Al2,
    const ushortT* __restrict__ Wth, const ushortT* __restrict__ Wtl,
    const float* __restrict__ bias, float* __restrict__ outf,
    ushortT* __restrict__ outb) {
    constexpr int KPAD = 72;          // 64-chunk + 8 shorts pad
    constexpr int NCT = NTOT / 16;
    __shared__ ushortT Bh[NTOT * KPAD];
    __shared__ ushortT Bl[NTOT * KPAD];
    const ushortT* Ah[3] = {Ah0, Ah1, Ah2};
    const ushortT* Al[3] = {Al0, Al1, Al2};
    int t = threadIdx.x;
    int lane = t & 63;
    int wv = t >> 6;                  // 8 waves
    int m = lane & 15, q = lane >> 4;
    int r0 = blockIdx.x * 256 + wv * 32;
    int ar0 = r0 + m;                 // row frag 0
    int ar1 = r0 + 16 + m;            // row frag 1

    f32x4 acc[2][NCT];
#pragma unroll
    for (int rf = 0; rf < 2; rf++)
#pragma unroll
        for (int ct = 0; ct < NCT; ct++)
#pragma unroll
            for (int j = 0; j < 4; j++) acc[rf][ct][j] = 0.f;

#pragma unroll
    for (int kc = 0; kc < KTOT / 64; kc++) {
        __syncthreads();
        // stage W[*, kc*64 .. kc*64+64) hi+lo into LDS (uint4 = 8 shorts)
        for (int i = t; i < NTOT * 8; i += 512) {
            int col = i >> 3, k = (i & 7) * 8;
            *(uint4*)(Bh + col * KPAD + k) =
                *(const uint4*)(Wth + (size_t)col * KTOT + kc * 64 + k);
            *(uint4*)(Bl + col * KPAD + k) =
                *(const uint4*)(Wtl + (size_t)col * KTOT + kc * 64 + k);
        }
        __syncthreads();
        const ushortT* Ahc = Ah[kc];
        const ushortT* Alc = Al[kc];
#pragma unroll
        for (int ks2 = 0; ks2 < 2; ks2++) {
            int kk = ks2 * 32 + q * 8;
            bf16x8 ah0 = *(const bf16x8*)(Ahc + (size_t)ar0 * 64 + kk);
            bf16x8 al0 = *(const bf16x8*)(Alc + (size_t)ar0 * 64 + kk);
            bf16x8 ah1 = *(const bf16x8*)(Ahc + (size_t)ar1 * 64 + kk);
            bf16x8 al1 = *(const bf16x8*)(Alc + (size_t)ar1 * 64 + kk);
#pragma unroll
            for (int ct = 0; ct < NCT; ct++) {
                int bo = (ct * 16 + m) * KPAD + ks2 * 32 + q * 8;
                bf16x8 bh = *(const bf16x8*)(Bh + bo);
                bf16x8 bl = *(const bf16x8*)(Bl + bo);
                acc[0][ct] = __builtin_amdgcn_mfma_f32_16x16x32_bf16(ah0, bh, acc[0][ct], 0, 0, 0);
                acc[0][ct] = __builtin_amdgcn_mfma_f32_16x16x32_bf16(al0, bh, acc[0][ct], 0, 0, 0);
                acc[0][ct] = __builtin_amdgcn_mfma_f32_16x16x32_bf16(ah0, bl, acc[0][ct], 0, 0, 0);
                acc[1][ct] = __builtin_amdgcn_mfma_f32_16x16x32_bf16(ah1, bh, acc[1][ct], 0, 0, 0);
                acc[1][ct] = __builtin_amdgcn_mfma_f32_16x16x32_bf16(al1, bh, acc[1][ct], 0, 0, 0);
                acc[1][ct] = __builtin_amdgcn_mfma_f32_16x16x32_bf16(ah1, bl, acc[1][ct], 0, 0, 0);
            }
        }
    }

#pragma unroll
    for (int rf = 0; rf < 2; rf++)
#pragma unroll
        for (int ct = 0; ct < NCT; ct++)
#pragma unroll
            for (int rg = 0; rg < 4; rg++) {
                int row = r0 + rf * 16 + q * 4 + rg;
                float v = acc[rf][ct][rg];
                if (MODE == 0) {
                    if (ct < 8)
                        outf[(size_t)row * 128 + ct * 16 + m] = v;
                    else
                        outb[(size_t)row * 64 + (ct - 8) * 16 + m] = f2b(v);
                } else {
                    int col = ct * 16 + m;
                    outf[(size_t)row * 128 + col] = fmaxf(v + bias[col], 0.f);
                }
            }
}

// ---------------------------------------------------------------------------
// SpMM, quarter-wave edge parallelism, 16 edges per iteration (4 independent
// cedge->gather chains per lane for memory-level parallelism). 16 lanes per
// edge-row; each lane loads uint2 = 4 bf16 features (one 128 B gather/edge).
// q = lane>>4 selects the edge within a 4-group; f = (lane&15)*4 features.
// Cross-quarter shfl_xor(16,32) reduction; quarters 0/1 write Yh/Yl.
// MODE 0: r = acc          MODE 1: r = aux + 2*acc
// MODE 2: r = 2*acc - aux  MODE 3: r = relu(aux + acc + bias)
// ---------------------------------------------------------------------------
template <int MODE, int SA, bool AUXB, bool WLO>
__global__ __launch_bounds__(256) void k_spmm(const int* __restrict__ rowp,
                                              const int2* __restrict__ cedge,
                                              const ushortT* __restrict__ Xb,
                                              const float* __restrict__ auxF,
                                              const ushortT* __restrict__ auxH,
                                              const ushortT* __restrict__ auxL,
                                              const float* __restrict__ bias,
                                              ushortT* __restrict__ Yh,
                                              ushortT* __restrict__ Yl) {
    int node = blockIdx.x * 4 + (threadIdx.x >> 6);
    int lane = threadIdx.x & 63;
    int q = lane >> 4;          // edge slot within group of 4
    int f = (lane & 15) * 4;    // feature base
    int s = rowp[node], e = rowp[node + 1];
    const ushortT* Xf = Xb + f;
    float a0 = 0.f, a1 = 0.f, a2 = 0.f, a3 = 0.f;
    for (int i = s; i < e; i += 16) {
        int i0 = min(i + q, e - 1);
        int i1 = min(i + 4 + q, e - 1);
        int i2 = min(i + 8 + q, e - 1);
        int i3 = min(i + 12 + q, e - 1);
        int2 ed0 = cedge[i0];
        int2 ed1 = cedge[i1];
        int2 ed2 = cedge[i2];
        int2 ed3 = cedge[i3];
        float w0 = (i + q < e) ? __int_as_float(ed0.y) : 0.f;
        float w1 = (i + 4 + q < e) ? __int_as_float(ed1.y) : 0.f;
        float w2 = (i + 8 + q < e) ? __int_as_float(ed2.y) : 0.f;
        float w3 = (i + 12 + q < e) ? __int_as_float(ed3.y) : 0.f;
        uint2 u0 = *(const uint2*)(Xf + ((size_t)ed0.x << 6));
        uint2 u1 = *(const uint2*)(Xf + ((size_t)ed1.x << 6));
        uint2 u2 = *(const uint2*)(Xf + ((size_t)ed2.x << 6));
        uint2 u3 = *(const uint2*)(Xf + ((size_t)ed3.x << 6));
        a0 = fmaf(w0, __uint_as_float(u0.x << 16), a0);
        a1 = fmaf(w0, __uint_as_float(u0.x & 0xffff0000u), a1);
        a2 = fmaf(w0, __uint_as_float(u0.y << 16), a2);
        a3 = fmaf(w0, __uint_as_float(u0.y & 0xffff0000u), a3);
        a0 = fmaf(w1, __uint_as_float(u1.x << 16), a0);
        a1 = fmaf(w1, __uint_as_float(u1.x & 0xffff0000u), a1);
        a2 = fmaf(w1, __uint_as_float(u1.y << 16), a2);
        a3 = fmaf(w1, __uint_as_float(u1.y & 0xffff0000u), a3);
        a0 = fmaf(w2, __uint_as_float(u2.x << 16), a0);
        a1 = fmaf(w2, __uint_as_float(u2.x & 0xffff0000u), a1);
        a2 = fmaf(w2, __uint_as_float(u2.y << 16), a2);
        a3 = fmaf(w2, __uint_as_float(u2.y & 0xffff0000u), a3);
        a0 = fmaf(w3, __uint_as_float(u3.x << 16), a0);
        a1 = fmaf(w3, __uint_as_float(u3.x & 0xffff0000u), a1);
        a2 = fmaf(w3, __uint_as_float(u3.y << 16), a2);
        a3 = fmaf(w3, __uint_as_float(u3.y & 0xffff0000u), a3);
    }
    // reduce across the 4 quarters (xor lane bits 4 and 5)
    a0 += __shfl_xor(a0, 16); a0 += __shfl_xor(a0, 32);
    a1 += __shfl_xor(a1, 16); a1 += __shfl_xor(a1, 32);
    a2 += __shfl_xor(a2, 16); a2 += __shfl_xor(a2, 32);
    a3 += __shfl_xor(a3, 16); a3 += __shfl_xor(a3, 32);

    if (q == 0 || (WLO && q == 1)) {
        float x0 = 0.f, x1 = 0.f, x2 = 0.f, x3 = 0.f;
        if (MODE != 0) {
            if (AUXB) {
                ushort4 ha = *(const ushort4*)(auxH + (size_t)node * 64 + f);
                ushort4 la = *(const ushort4*)(auxL + (size_t)node * 64 + f);
                x0 = b2f(ha.x) + b2f(la.x);
                x1 = b2f(ha.y) + b2f(la.y);
                x2 = b2f(ha.z) + b2f(la.z);
                x3 = b2f(ha.w) + b2f(la.w);
            } else {
                float4 av = *(const float4*)(auxF + (size_t)node * SA + f);
                x0 = av.x; x1 = av.y; x2 = av.z; x3 = av.w;
            }
        }
        float r0, r1, r2, r3;
        if (MODE == 0)      { r0 = a0; r1 = a1; r2 = a2; r3 = a3; }
        else if (MODE == 1) { r0 = x0 + 2.f * a0; r1 = x1 + 2.f * a1;
                              r2 = x2 + 2.f * a2; r3 = x3 + 2.f * a3; }
        else if (MODE == 2) { r0 = 2.f * a0 - x0; r1 = 2.f * a1 - x1;
                              r2 = 2.f * a2 - x2; r3 = 2.f * a3 - x3; }
        else {
            float4 bv = *(const float4*)(bias + f);
            r0 = fmaxf(x0 + a0 + bv.x, 0.f);
            r1 = fmaxf(x1 + a1 + bv.y, 0.f);
            r2 = fmaxf(x2 + a2 + bv.z, 0.f);
            r3 = fmaxf(x3 + a3 + bv.w, 0.f);
        }
        ushort4 h;
        h.x = f2b(r0); h.y = f2b(r1); h.z = f2b(r2); h.w = f2b(r3);
        if (q == 0) {
            *(ushort4*)(Yh + (size_t)node * 64 + f) = h;
        } else {
            ushort4 l;
            l.x = f2b(r0 - b2f(h.x));
            l.y = f2b(r1 - b2f(h.y));
            l.z = f2b(r2 - b2f(h.z));
            l.w = f2b(r3 - b2f(h.w));
            *(ushort4*)(Yl + (size_t)node * 64 + f) = l;
        }
    }
}

// ---------------------------------------------------------------------------
// Pooling: 64 consecutive nodes per block (batch sorted -> run-length)
// ---------------------------------------------------------------------------
__global__ __launch_bounds__(128) void k_pool(const int* __restrict__ batch,
                                              const float* __restrict__ H3,
                                              float* __restrict__ pooled,
                                              float* __restrict__ gcnt) {
    int t = threadIdx.x;
    int n0 = blockIdx.x * 64;
    int g = batch[n0];
    float a = 0.f;
    int c = 0;
    for (int k = 0; k < 64; k++) {
        int gn = batch[n0 + k];
        if (gn != g) {
            atomicAdd(&pooled[(size_t)g * 128 + t], a);
            if (t == 0) atomicAdd(&gcnt[g], (float)c);
            g = gn; a = 0.f; c = 0;
        }
        a += H3[(size_t)(n0 + k) * 128 + t];
        c++;
    }
    atomicAdd(&pooled[(size_t)g * 128 + t], a);
    if (t == 0) atomicAdd(&gcnt[g], (float)c);
}

__global__ void k_final(const float* __restrict__ pooled, const float* __restrict__ gcnt,
                        const float* __restrict__ lin_w, const float* __restrict__ lin_b,
                        float* __restrict__ out) {
    int g = blockIdx.x * 4 + (threadIdx.x >> 6);
    int lane = threadIdx.x & 63;
    if (g >= N_GRAPHS) return;
    float inv = 1.f / fmaxf(gcnt[g], 1.f);
    float v0 = pooled[(size_t)g * 128 + lane] * inv;
    float v1 = pooled[(size_t)g * 128 + 64 + lane] * inv;
    float p0 = v0 * lin_w[lane * 2 + 0] + v1 * lin_w[(lane + 64) * 2 + 0];
    float p1 = v0 * lin_w[lane * 2 + 1] + v1 * lin_w[(lane + 64) * 2 + 1];
    for (int o = 32; o > 0; o >>= 1) {
        p0 += __shfl_down(p0, o);
        p1 += __shfl_down(p1, o);
    }
    if (lane == 0) {
        out[g * 2 + 0] = p0 + lin_b[0];
        out[g * 2 + 1] = p1 + lin_b[1];
    }
}

// ---------------------------------------------------------------------------
extern "C" void kernel_launch(void* const* d_in, const int* in_sizes, int n_in,
                              void* d_out, int out_size, void* d_ws, size_t ws_size,
                              hipStream_t stream) {
    const float* x     = (const float*)d_in[0];
    const int*   src   = (const int*)d_in[1];
    const int*   dst   = src + N_EDGES;
    const float* eattr = (const float*)d_in[2];
    const int*   batch = (const int*)d_in[3];
    const float* w1    = (const float*)d_in[4];
    const float* b1    = (const float*)d_in[5];
    const float* w2    = (const float*)d_in[6];
    const float* b2    = (const float*)d_in[7];
    const float* w3    = (const float*)d_in[8];
    const float* b3    = (const float*)d_in[9];
    const float* lin_w = (const float*)d_in[10];
    const float* lin_b = (const float*)d_in[11];
    float* out = (float*)d_out;

    char* ws = (char*)d_ws;
    size_t off = 0;
    auto alloc = [&](size_t bytes) -> char* {
        char* p = ws + off;
        off += (bytes + 255) & ~(size_t)255;
        return p;
    };
    int*   blkCntD   = (int*)  alloc((size_t)NBB * NBUCK * 4);   // 819 KB
    int*   blkCntS   = (int*)  alloc((size_t)NBB * NBUCK * 4);
    int*   blkRelD   = (int*)  alloc((size_t)NBB * NBUCK * 4);
    int*   blkRelS   = (int*)  alloc((size_t)NBB * NBUCK * 4);
    int*   bucketTotD = (int*) alloc(NBUCK * 4);
    int*   bucketTotS = (int*) alloc(NBUCK * 4);
    int*   binBaseD  = (int*)  alloc((NBUCK + 1) * 4);
    int*   binBaseS  = (int*)  alloc((NBUCK + 1) * 4);
    float* dinv      = (float*)alloc((size_t)N_NODES * 4);
    int*   rowp      = (int*)  alloc((size_t)(N_NODES + 1) * 4);
    ushortT* Wt1h   = (ushortT*)alloc(192 * 128 * 2);
    ushortT* Wt1l   = (ushortT*)alloc(192 * 128 * 2);
    ushortT* Wt2h   = (ushortT*)alloc(192 * 64 * 2);
    ushortT* Wt2l   = (ushortT*)alloc(192 * 64 * 2);
    ushortT* Wt3h   = (ushortT*)alloc(128 * 192 * 2);
    ushortT* Wt3l   = (ushortT*)alloc(128 * 192 * 2);
    float* pooled   = (float*)alloc((size_t)(N_GRAPHS * 128 + N_GRAPHS) * 4);
    float* gcnt     = pooled + (size_t)N_GRAPHS * 128;
    int2*  cedge    = (int2*) alloc((size_t)N_EDGES * 8);      // 26.2 MB
    char*  Buf1     = alloc((size_t)N_EDGES * 16);             // 52.4 MB
    char*  Buf2     = alloc((size_t)N_NODES * 128 * 4);        // 52.4 MB
    char*  Buf3     = alloc(4 * N64 * 2);                      // 52.4 MB

    // Buf1: edsD|edsS (build)  ->  Xhi/Xlo [2][N][64]  ->  GThi [3][N][64]
    int2* edsD = (int2*)Buf1;
    int2* edsS = edsD + N_EDGES;
    ushortT* Xhi  = (ushortT*)Buf1;
    ushortT* Xlo  = Xhi + 2 * N64;
    ushortT* GThi = (ushortT*)Buf1;          // slots 0,1,2 contiguous
    // Buf2: P fp32 [N][128] (P0c | P1)  ->  H3 fp32 [N][128]
    float* P  = (float*)Buf2;
    float* H3 = (float*)Buf2;
    // Buf3: G0 | Qhi | H1hi | H1lo ; GTlo slots alias regions 0,2,3
    ushortT* G0    = (ushortT*)Buf3;
    ushortT* Qhi   = G0 + N64;
    ushortT* H1hi  = G0 + 2 * N64;
    ushortT* H1lo  = G0 + 3 * N64;
    ushortT* GTlo0 = G0;      // written after G0's last read
    ushortT* GTlo1 = H1hi;    // written after H1hi's last read
    ushortT* GTlo2 = H1lo;    // written after H1lo's last read

    hipMemsetAsync(pooled, 0, (size_t)(N_GRAPHS * 128 + N_GRAPHS) * 4, stream);

    // ---- CSR build: deterministic counting sorts, zero global atomics.
    k_binA<<<NBB, 256, 0, stream>>>(src, dst, blkCntD, blkCntS);
    k_bbase<<<NBUCK, 256, 0, stream>>>(blkCntD, blkRelD, bucketTotD);
    k_bbase<<<NBUCK, 256, 0, stream>>>(blkCntS, blkRelS, bucketTotS);
    k_bscan<<<1, 128, 0, stream>>>(bucketTotD, bucketTotS, binBaseD, binBaseS, rowp);
    k_binBS<<<NBB, 256, 0, stream>>>(src, eattr, blkCntS, blkRelS, binBaseS, edsS);
    k_deg<<<NBUCK, 256, 0, stream>>>(edsS, binBaseS, dinv);
    k_binB<<<NBB, 256, 0, stream>>>(src, dst, eattr, blkCntD, blkRelD, binBaseD, edsD);
    k_csr<<<NBUCK, 512, 0, stream>>>(edsD, binBaseD, dinv, rowp, cedge);

    // ---- Prep: x cast (after edsD/edsS consumed), weight transpose+split
    k_cast<<<N_NODES * 32 / 256, 256, 0, stream>>>(x, Xhi, Xlo);
    k_wprep<1><<<96, 256, 0, stream>>>(w1, Wt1h, Wt1l);
    k_wprep<2><<<48, 256, 0, stream>>>(w2, Wt2h, Wt2l);
    k_wprep<3><<<96, 256, 0, stream>>>(w3, Wt3h, Wt3l);

    // ---- Layer 1 (128 -> 64): P0c,P1 fp32 + P2 bf16 table (G0)
    k_mgemm<128, 192, 0><<<N_NODES / 256, 512, 0, stream>>>(
        Xhi, Xhi + N64, nullptr, Xlo, Xlo + N64, nullptr, Wt1h, Wt1l, nullptr, P, G0);
    // Q = P1 + 2*L*P2 -> Qhi
    k_spmm<1, 128, false, false><<<N_NODES / 4, 256, 0, stream>>>(
        rowp, cedge, G0, P + 64, nullptr, nullptr, nullptr, Qhi, nullptr);
    // H1 = relu(P0c + L*Q + b1) -> H1hi/H1lo
    k_spmm<3, 128, false, true><<<N_NODES / 4, 256, 0, stream>>>(
        rowp, cedge, Qhi, P, nullptr, nullptr, b1, H1hi, H1lo);

    // ---- Layer 2 (64 -> 64)
    k_mgemm<64, 192, 0><<<N_NODES / 256, 512, 0, stream>>>(
        H1hi, nullptr, nullptr, H1lo, nullptr, nullptr, Wt2h, Wt2l, nullptr, P, G0);
    k_spmm<1, 128, false, false><<<N_NODES / 4, 256, 0, stream>>>(
        rowp, cedge, G0, P + 64, nullptr, nullptr, nullptr, Qhi, nullptr);
    // T0 = relu(P0c + L*Q + b2) -> GThi[0]/GTlo[0]
    k_spmm<3, 128, false, true><<<N_NODES / 4, 256, 0, stream>>>(
        rowp, cedge, Qhi, P, nullptr, nullptr, b2, GThi, GTlo0);

    // ---- Layer 3 (64 -> 128), spmm-first
    // T1 = L*T0 -> GThi[1]/GTlo[1]
    k_spmm<0, 64, false, true><<<N_NODES / 4, 256, 0, stream>>>(
        rowp, cedge, GThi, nullptr, nullptr, nullptr, nullptr, GThi + N64, GTlo1);
    // T2 = 2*L*T1 - T0 -> GThi[2]/GTlo[2]  (Aux = T0 via hi+lo)
    k_spmm<2, 64, true, true><<<N_NODES / 4, 256, 0, stream>>>(
        rowp, cedge, GThi + N64, nullptr, GThi, GTlo0, nullptr, GThi + 2 * N64, GTlo2);
    // H3 = relu([T0|T1|T2] @ w3 + b3) -> H3 fp32
    k_mgemm<192, 128, 1><<<N_NODES / 256, 512, 0, stream>>>(
        GThi, GThi + N64, GThi + 2 * N64, GTlo0, GTlo1, GTlo2, Wt3h, Wt3l, b3, H3, nullptr);

    // ---- Pool + final linear
    k_pool<<<N_NODES / 64, 128, 0, stream>>>(batch, H3, pooled, gcnt);
    k_final<<<N_GRAPHS / 4, 256, 0, stream>>>(pooled, gcnt, lin_w, lin_b, out);
}

// Round 7
// 759.579 us; speedup vs baseline: 1.0499x; 1.0499x over previous
//
#include <hip/hip_runtime.h>
#include <cstddef>
#include <cstdint>

#define N_NODES 102400
#define N_EDGES 3276800
#define N_GRAPHS 1024
#define NBUCK 400            // node >> 8 -> 400 buckets of 256 nodes
#define NBB 512              // binning blocks
#define EPB 6400             // edges per binning block (NBB*EPB == N_EDGES)
#define MAXB 12288           // per-bucket staging capacity in k_csr (avg 8192)
#define N64 ((size_t)N_NODES * 64)

typedef unsigned short ushortT;
typedef unsigned int uintT;
typedef __attribute__((ext_vector_type(8))) short bf16x8;
typedef __attribute__((ext_vector_type(4))) float f32x4;

__device__ __forceinline__ float b2f(ushortT h) {
    return __uint_as_float(((uintT)h) << 16);
}
__device__ __forceinline__ ushortT f2b(float f) {
    uintT u = __float_as_uint(f);
    uintT r = (u + 0x7fffu + ((u >> 16) & 1u)) >> 16;
    return (ushortT)r;
}
__device__ __forceinline__ float loF(uintT w) { return __uint_as_float(w << 16); }
__device__ __forceinline__ float hiF(uintT w) { return __uint_as_float(w & 0xffff0000u); }

// ---------------------------------------------------------------------------
// Pass A: per-block LDS histograms of dst AND src coarse buckets.
// Zero global atomics, zero scattered writes.
// ---------------------------------------------------------------------------
__global__ __launch_bounds__(256) void k_binA(const int* __restrict__ src,
                                              const int* __restrict__ dst,
                                              int* __restrict__ blkCntD,
                                              int* __restrict__ blkCntS) {
    __shared__ int hd[NBUCK], hs[NBUCK];
    int t = threadIdx.x;
    for (int i = t; i < NBUCK; i += 256) { hd[i] = 0; hs[i] = 0; }
    __syncthreads();
    int base = blockIdx.x * EPB;
    for (int k = 0; k < EPB / 256; k++) {
        int e = base + k * 256 + t;
        atomicAdd(&hd[dst[e] >> 8], 1);
        atomicAdd(&hs[src[e] >> 8], 1);
    }
    __syncthreads();
    for (int i = t; i < NBUCK; i += 256) {
        blkCntD[(size_t)blockIdx.x * NBUCK + i] = hd[i];
        blkCntS[(size_t)blockIdx.x * NBUCK + i] = hs[i];
    }
}

// Per-bucket exclusive scan over NBB block counts -> blkRel[block][buck],
// plus bucket totals. (launched once for D, once for S)
__global__ __launch_bounds__(256) void k_bbase(const int* __restrict__ blkCnt,
                                               int* __restrict__ blkRel,
                                               int* __restrict__ bucketTot) {
    __shared__ int sc[NBB];
    int b = blockIdx.x, t = threadIdx.x;
    int v0 = blkCnt[(size_t)t * NBUCK + b];
    int v1 = blkCnt[(size_t)(t + 256) * NBUCK + b];
    sc[t] = v0; sc[t + 256] = v1;
    __syncthreads();
    for (int o = 1; o < NBB; o <<= 1) {
        int x0 = (t >= o) ? sc[t - o] : 0;
        int x1 = (t + 256 >= o) ? sc[t + 256 - o] : 0;
        __syncthreads();
        sc[t] += x0; sc[t + 256] += x1;
        __syncthreads();
    }
    blkRel[(size_t)t * NBUCK + b] = sc[t] - v0;
    blkRel[(size_t)(t + 256) * NBUCK + b] = sc[t + 256] - v1;
    if (t == 255) bucketTot[b] = sc[NBB - 1];
}

// Serial scans of 400 bucket totals -> bucket bases (D and S), rowp tail.
__global__ void k_bscan(const int* __restrict__ bucketTotD,
                        const int* __restrict__ bucketTotS,
                        int* __restrict__ binBaseD,
                        int* __restrict__ binBaseS,
                        int* __restrict__ rowp) {
    int t = threadIdx.x;
    if (t == 0) {
        int run = 0;
        for (int i = 0; i < NBUCK; i++) { binBaseD[i] = run; run += bucketTotD[i]; }
        binBaseD[NBUCK] = run;
        rowp[N_NODES] = run;
    } else if (t == 64) {
        int run = 0;
        for (int i = 0; i < NBUCK; i++) { binBaseS[i] = run; run += bucketTotS[i]; }
        binBaseS[NBUCK] = run;
    }
}

// ---------------------------------------------------------------------------
// Pass B (dst): deterministic LDS-staged counting sort into dst-bucket
// regions. No global atomics; flush in bucket order -> coalesced stores.
// edsD: x = (src<<8)|dstLow, y = attr bits.
// ---------------------------------------------------------------------------
__global__ __launch_bounds__(256) void k_binB(const int* __restrict__ src,
                                              const int* __restrict__ dst,
                                              const float* __restrict__ attr,
                                              const int* __restrict__ blkCnt,
                                              const int* __restrict__ blkRel,
                                              const int* __restrict__ binBaseD,
                                              int2* __restrict__ edsD) {
    __shared__ int spos[EPB];       // global position per staged slot
    __shared__ int sx[EPB];         // payload x (also scan scratch)
    __shared__ int sy[EPB];         // payload y
    __shared__ int lcur[NBUCK];     // local cursors
    __shared__ int delta[NBUCK];    // global base - local base per bucket
    int bx = blockIdx.x, t = threadIdx.x;

    // local exclusive scan of this block's 400 bucket counts (padded to 512)
    int* sc = sx;
    int v0 = blkCnt[(size_t)bx * NBUCK + t];
    int v1 = (t + 256 < NBUCK) ? blkCnt[(size_t)bx * NBUCK + t + 256] : 0;
    sc[t] = v0; sc[t + 256] = v1;
    __syncthreads();
    for (int o = 1; o < 512; o <<= 1) {
        int x0 = (t >= o) ? sc[t - o] : 0;
        int x1 = (t + 256 >= o) ? sc[t + 256 - o] : 0;
        __syncthreads();
        sc[t] += x0; sc[t + 256] += x1;
        __syncthreads();
    }
    {
        int e0 = sc[t] - v0;
        lcur[t] = e0;
        delta[t] = binBaseD[t] + blkRel[(size_t)bx * NBUCK + t] - e0;
        if (t + 256 < NBUCK) {
            int e1 = sc[t + 256] - v1;
            lcur[t + 256] = e1;
            delta[t + 256] = binBaseD[t + 256] + blkRel[(size_t)bx * NBUCK + t + 256] - e1;
        }
    }
    __syncthreads();

    int base = bx * EPB;
    for (int k = 0; k < EPB / 256; k++) {
        int e = base + k * 256 + t;
        int s = src[e], d = dst[e];
        int a = __float_as_int(attr[e]);
        int bkt = d >> 8;
        int lp = atomicAdd(&lcur[bkt], 1);
        spos[lp] = lp + delta[bkt];
        sx[lp] = (s << 8) | (d & 255);
        sy[lp] = a;
    }
    __syncthreads();
    for (int k = 0; k < EPB / 256; k++) {
        int i = k * 256 + t;
        edsD[spos[i]] = make_int2(sx[i], sy[i]);
    }
}

// ---------------------------------------------------------------------------
// Pass B (src): same deterministic counting sort keyed by src bucket.
// edsS: x = srcLow, y = attr bits.
// ---------------------------------------------------------------------------
__global__ __launch_bounds__(256) void k_binBS(const int* __restrict__ src,
                                               const float* __restrict__ attr,
                                               const int* __restrict__ blkCnt,
                                               const int* __restrict__ blkRel,
                                               const int* __restrict__ binBaseS,
                                               int2* __restrict__ edsS) {
    __shared__ int spos[EPB];
    __shared__ int sx[EPB];
    __shared__ int sy[EPB];
    __shared__ int lcur[NBUCK];
    __shared__ int delta[NBUCK];
    int bx = blockIdx.x, t = threadIdx.x;

    int* sc = sx;
    int v0 = blkCnt[(size_t)bx * NBUCK + t];
    int v1 = (t + 256 < NBUCK) ? blkCnt[(size_t)bx * NBUCK + t + 256] : 0;
    sc[t] = v0; sc[t + 256] = v1;
    __syncthreads();
    for (int o = 1; o < 512; o <<= 1) {
        int x0 = (t >= o) ? sc[t - o] : 0;
        int x1 = (t + 256 >= o) ? sc[t + 256 - o] : 0;
        __syncthreads();
        sc[t] += x0; sc[t + 256] += x1;
        __syncthreads();
    }
    {
        int e0 = sc[t] - v0;
        lcur[t] = e0;
        delta[t] = binBaseS[t] + blkRel[(size_t)bx * NBUCK + t] - e0;
        if (t + 256 < NBUCK) {
            int e1 = sc[t + 256] - v1;
            lcur[t + 256] = e1;
            delta[t + 256] = binBaseS[t + 256] + blkRel[(size_t)bx * NBUCK + t + 256] - e1;
        }
    }
    __syncthreads();

    int base = bx * EPB;
    for (int k = 0; k < EPB / 256; k++) {
        int e = base + k * 256 + t;
        int s = src[e];
        int a = __float_as_int(attr[e]);
        int bkt = s >> 8;
        int lp = atomicAdd(&lcur[bkt], 1);
        spos[lp] = lp + delta[bkt];
        sx[lp] = s & 255;
        sy[lp] = a;
    }
    __syncthreads();
    for (int k = 0; k < EPB / 256; k++) {
        int i = k * 256 + t;
        edsS[spos[i]] = make_int2(sx[i], sy[i]);
    }
}

// Per-bucket weighted degree via LDS float accumulation -> dinv directly.
__global__ __launch_bounds__(256) void k_deg(const int2* __restrict__ edsS,
                                             const int* __restrict__ binBaseS,
                                             float* __restrict__ dinv) {
    __shared__ float degL[256];
    int b = blockIdx.x, t = threadIdx.x;
    degL[t] = 0.f;
    __syncthreads();
    int s0 = binBaseS[b], s1 = binBaseS[b + 1];
    for (int i = s0 + t; i < s1; i += 256) {
        int2 e = edsS[i];
        atomicAdd(&degL[e.x], __int_as_float(e.y));
    }
    __syncthreads();
    float d = degL[t];
    dinv[b * 256 + t] = d > 0.f ? rsqrtf(d) : 0.f;
}

// ---------------------------------------------------------------------------
// Per-bucket exact CSR, LDS-staged. cedge = -attr * dinv[src] * dinv[dst].
// Counting-sort key (dstLow, src>>13): rows come out src-banded (kept from
// round 5 — neutral perf, better determinism of gather windows).
// ---------------------------------------------------------------------------
__global__ __launch_bounds__(512) void k_csr(const int2* __restrict__ edsD,
                                             const int* __restrict__ binBaseD,
                                             const float* __restrict__ dinvG,
                                             int* __restrict__ rowp,
                                             int2* __restrict__ cedge) {
    __shared__ int cnt2[256 * 16];   // (dstLow, src>>13) counters -> cursors
    __shared__ int cntL[256];        // per-row totals -> prefix
    __shared__ float dL[256];
    __shared__ int2 st[MAXB];
    int b = blockIdx.x, t = threadIdx.x;
    for (int i = t; i < 256 * 16; i += 512) cnt2[i] = 0;
    if (t < 256) dL[t] = dinvG[b * 256 + t];
    __syncthreads();
    int s0 = binBaseD[b], s1 = binBaseD[b + 1];
    for (int i = s0 + t; i < s1; i += 512) {
        int2 e = edsD[i];
        atomicAdd(&cnt2[(e.x & 255) * 16 + ((e.x >> 8) >> 13)], 1);
    }
    __syncthreads();
    // per-row totals + in-place exclusive scan over the 16 src bands
    if (t < 256) {
        int run = 0;
#pragma unroll
        for (int o = 0; o < 16; o++) {
            int c = cnt2[t * 16 + o];
            cnt2[t * 16 + o] = run;
            run += c;
        }
        cntL[t] = run;
    }
    __syncthreads();
    int v = (t < 256) ? cntL[t] : 0;
    for (int o = 1; o < 256; o <<= 1) {
        int x = (t < 256 && t >= o) ? cntL[t - o] : 0;
        __syncthreads();
        if (t < 256) cntL[t] += x;
        __syncthreads();
    }
    if (t < 256) {
        int excl = cntL[t] - v;
        rowp[b * 256 + t] = s0 + excl;
        // make band cursors absolute within the staging buffer
#pragma unroll
        for (int o = 0; o < 16; o++) cnt2[t * 16 + o] += excl;
    }
    __syncthreads();
    for (int i = s0 + t; i < s1; i += 512) {
        int2 e = edsD[i];
        int dl = e.x & 255;
        int sg = e.x >> 8;
        float w = -__int_as_float(e.y) * dinvG[sg] * dL[dl];
        int p = atomicAdd(&cnt2[dl * 16 + (sg >> 13)], 1);
        st[p] = make_int2(sg, __float_as_int(w));
    }
    __syncthreads();
    int n = s1 - s0;
    for (int i = t; i < n; i += 512) cedge[s0 + i] = st[i];
}

// ---------------------------------------------------------------------------
// x -> slot-major bf16 hi/lo tables: Xhi/Xlo[s][n][64], s = k>>6
// ---------------------------------------------------------------------------
__global__ __launch_bounds__(256) void k_cast(const float* __restrict__ x,
                                              ushortT* __restrict__ Xhi,
                                              ushortT* __restrict__ Xlo) {
    int i = blockIdx.x * 256 + threadIdx.x;   // [0, N*32)
    int n = i >> 5;
    int kq = (i & 31) * 4;
    float4 v = ((const float4*)x)[i];
    int s = kq >> 6, kk = kq & 63;
    size_t o = (size_t)s * N64 + (size_t)n * 64 + kk;
    ushort4 h, l;
    h.x = f2b(v.x); l.x = f2b(v.x - b2f(h.x));
    h.y = f2b(v.y); l.y = f2b(v.y - b2f(h.y));
    h.z = f2b(v.z); l.z = f2b(v.z - b2f(h.z));
    h.w = f2b(v.w); l.w = f2b(v.w - b2f(h.w));
    *(ushort4*)(Xhi + o) = h;
    *(ushort4*)(Xlo + o) = l;
}

// ---------------------------------------------------------------------------
// Weight prep: transposed [N][K] bf16 hi/lo tables.
// ---------------------------------------------------------------------------
template <int L>
__global__ void k_wprep(const float* __restrict__ w, ushortT* __restrict__ Wth,
                        ushortT* __restrict__ Wtl) {
    int i = blockIdx.x * 256 + threadIdx.x;
    float v;
    if (L == 1) {
        if (i >= 192 * 128) return;
        int n = i / 128, k = i % 128;
        if (n < 64)       v = w[k * 64 + n] - w[16384 + k * 64 + n];
        else if (n < 128) v = w[8192 + k * 64 + (n - 64)];
        else              v = w[16384 + k * 64 + (n - 128)];
    } else if (L == 2) {
        if (i >= 192 * 64) return;
        int n = i / 64, k = i % 64;
        if (n < 64)       v = w[k * 64 + n] - w[8192 + k * 64 + n];
        else if (n < 128) v = w[4096 + k * 64 + (n - 64)];
        else              v = w[8192 + k * 64 + (n - 128)];
    } else {
        if (i >= 128 * 192) return;
        int n = i / 192, k = i % 192;
        v = w[(k >> 6) * 8192 + (k & 63) * 128 + n];
    }
    ushortT h = f2b(v);
    Wth[i] = h;
    Wtl[i] = f2b(v - b2f(h));
}

// ---------------------------------------------------------------------------
// MFMA GEMM v2: one block = 256 rows x ALL NTOT cols (no blockIdx.y
// redundancy -> A read once). W (hi+lo) staged in LDS in 64-wide K-chunks
// (pad stride 72 shorts -> bank-stride 4 mod 32, conflict-free floor).
// 8 waves x (32 rows x NTOT cols) each; per k-step per wave:
// 4 global A loads + 2*NCT ds_reads + 6*NCT MFMAs (MFMA-dominated mix).
// acc = Ahi*Whi + Alo*Whi + Ahi*Wlo  (~fp32 accuracy).
// MODE 0: ct<8 -> fp32 out[n*128 + ct*16+m]; ct>=8 -> bf16 outb[n*64 + ...]
// MODE 1: fp32 out[n*128 + col] = relu(acc + bias[col])
// ---------------------------------------------------------------------------
template <int KTOT, int NTOT, int MODE>
__global__ __launch_bounds__(512) void k_mgemm(
    const ushortT* __restrict__ Ah0, const ushortT* __restrict__ Ah1,
    const ushortT* __restrict__ Ah2, const ushortT* __restrict__ Al0,
    const ushortT* __restrict__ Al1, const ushortT* __restrict__ Al2,
    const ushortT* __restrict__ Wth, const ushortT* __restrict__ Wtl,
    const float* __restrict__ bias, float* __restrict__ outf,
    ushortT* __restrict__ outb) {
    constexpr int KPAD = 72;          // 64-chunk + 8 shorts pad
    constexpr int NCT = NTOT / 16;
    __shared__ ushortT Bh[NTOT * KPAD];
    __shared__ ushortT Bl[NTOT * KPAD];
    const ushortT* Ah[3] = {Ah0, Ah1, Ah2};
    const ushortT* Al[3] = {Al0, Al1, Al2};
    int t = threadIdx.x;
    int lane = t & 63;
    int wv = t >> 6;                  // 8 waves
    int m = lane & 15, q = lane >> 4;
    int r0 = blockIdx.x * 256 + wv * 32;
    int ar0 = r0 + m;                 // row frag 0
    int ar1 = r0 + 16 + m;            // row frag 1

    f32x4 acc[2][NCT];
#pragma unroll
    for (int rf = 0; rf < 2; rf++)
#pragma unroll
        for (int ct = 0; ct < NCT; ct++)
#pragma unroll
            for (int j = 0; j < 4; j++) acc[rf][ct][j] = 0.f;

#pragma unroll
    for (int kc = 0; kc < KTOT / 64; kc++) {
        __syncthreads();
        // stage W[*, kc*64 .. kc*64+64) hi+lo into LDS (uint4 = 8 shorts)
        for (int i = t; i < NTOT * 8; i += 512) {
            int col = i >> 3, k = (i & 7) * 8;
            *(uint4*)(Bh + col * KPAD + k) =
                *(const uint4*)(Wth + (size_t)col * KTOT + kc * 64 + k);
            *(uint4*)(Bl + col * KPAD + k) =
                *(const uint4*)(Wtl + (size_t)col * KTOT + kc * 64 + k);
        }
        __syncthreads();
        const ushortT* Ahc = Ah[kc];
        const ushortT* Alc = Al[kc];
#pragma unroll
        for (int ks2 = 0; ks2 < 2; ks2++) {
            int kk = ks2 * 32 + q * 8;
            bf16x8 ah0 = *(const bf16x8*)(Ahc + (size_t)ar0 * 64 + kk);
            bf16x8 al0 = *(const bf16x8*)(Alc + (size_t)ar0 * 64 + kk);
            bf16x8 ah1 = *(const bf16x8*)(Ahc + (size_t)ar1 * 64 + kk);
            bf16x8 al1 = *(const bf16x8*)(Alc + (size_t)ar1 * 64 + kk);
#pragma unroll
            for (int ct = 0; ct < NCT; ct++) {
                int bo = (ct * 16 + m) * KPAD + ks2 * 32 + q * 8;
                bf16x8 bh = *(const bf16x8*)(Bh + bo);
                bf16x8 bl = *(const bf16x8*)(Bl + bo);
                acc[0][ct] = __builtin_amdgcn_mfma_f32_16x16x32_bf16(ah0, bh, acc[0][ct], 0, 0, 0);
                acc[0][ct] = __builtin_amdgcn_mfma_f32_16x16x32_bf16(al0, bh, acc[0][ct], 0, 0, 0);
                acc[0][ct] = __builtin_amdgcn_mfma_f32_16x16x32_bf16(ah0, bl, acc[0][ct], 0, 0, 0);
                acc[1][ct] = __builtin_amdgcn_mfma_f32_16x16x32_bf16(ah1, bh, acc[1][ct], 0, 0, 0);
                acc[1][ct] = __builtin_amdgcn_mfma_f32_16x16x32_bf16(al1, bh, acc[1][ct], 0, 0, 0);
                acc[1][ct] = __builtin_amdgcn_mfma_f32_16x16x32_bf16(ah1, bl, acc[1][ct], 0, 0, 0);
            }
        }
    }

#pragma unroll
    for (int rf = 0; rf < 2; rf++)
#pragma unroll
        for (int ct = 0; ct < NCT; ct++)
#pragma unroll
            for (int rg = 0; rg < 4; rg++) {
                int row = r0 + rf * 16 + q * 4 + rg;
                float v = acc[rf][ct][rg];
                if (MODE == 0) {
                    if (ct < 8)
                        outf[(size_t)row * 128 + ct * 16 + m] = v;
                    else
                        outb[(size_t)row * 64 + (ct - 8) * 16 + m] = f2b(v);
                } else {
                    int col = ct * 16 + m;
                    outf[(size_t)row * 128 + col] = fmaxf(v + bias[col], 0.f);
                }
            }
}

// ---------------------------------------------------------------------------
// SpMM v3: 8 lanes per edge-row, each lane gathers uint4 = 8 bf16 features
// (16 B/lane coalescing sweet spot; one gather inst covers 8 edges, 1024 B).
// 16 edges per iteration via 2 slots -> 2 gather + 2 cedge insts per iter
// (half the VMEM instruction count of v2). q = lane>>3 edge slot in group
// of 8; f = (lane&7)*8 feature base. Cross-group shfl_xor(8,16,32) reduce;
// groups 0/1 write Yh/Yl.
// MODE 0: r = acc          MODE 1: r = aux + 2*acc
// MODE 2: r = 2*acc - aux  MODE 3: r = relu(aux + acc + bias)
// ---------------------------------------------------------------------------
template <int MODE, int SA, bool AUXB, bool WLO>
__global__ __launch_bounds__(256) void k_spmm(const int* __restrict__ rowp,
                                              const int2* __restrict__ cedge,
                                              const ushortT* __restrict__ Xb,
                                              const float* __restrict__ auxF,
                                              const ushortT* __restrict__ auxH,
                                              const ushortT* __restrict__ auxL,
                                              const float* __restrict__ bias,
                                              ushortT* __restrict__ Yh,
                                              ushortT* __restrict__ Yl) {
    int node = blockIdx.x * 4 + (threadIdx.x >> 6);
    int lane = threadIdx.x & 63;
    int q = lane >> 3;          // edge slot within group of 8
    int f = (lane & 7) * 8;     // feature base (8 features/lane)
    int s = rowp[node], e = rowp[node + 1];
    const ushortT* Xf = Xb + f;
    float a0 = 0.f, a1 = 0.f, a2 = 0.f, a3 = 0.f;
    float a4 = 0.f, a5 = 0.f, a6 = 0.f, a7 = 0.f;
    for (int i = s; i < e; i += 16) {
        int i0 = min(i + q, e - 1);
        int i1 = min(i + 8 + q, e - 1);
        int2 ed0 = cedge[i0];
        int2 ed1 = cedge[i1];
        float w0 = (i + q < e) ? __int_as_float(ed0.y) : 0.f;
        float w1 = (i + 8 + q < e) ? __int_as_float(ed1.y) : 0.f;
        uint4 u0 = *(const uint4*)(Xf + ((size_t)ed0.x << 6));
        uint4 u1 = *(const uint4*)(Xf + ((size_t)ed1.x << 6));
        a0 = fmaf(w0, loF(u0.x), a0);
        a1 = fmaf(w0, hiF(u0.x), a1);
        a2 = fmaf(w0, loF(u0.y), a2);
        a3 = fmaf(w0, hiF(u0.y), a3);
        a4 = fmaf(w0, loF(u0.z), a4);
        a5 = fmaf(w0, hiF(u0.z), a5);
        a6 = fmaf(w0, loF(u0.w), a6);
        a7 = fmaf(w0, hiF(u0.w), a7);
        a0 = fmaf(w1, loF(u1.x), a0);
        a1 = fmaf(w1, hiF(u1.x), a1);
        a2 = fmaf(w1, loF(u1.y), a2);
        a3 = fmaf(w1, hiF(u1.y), a3);
        a4 = fmaf(w1, loF(u1.z), a4);
        a5 = fmaf(w1, hiF(u1.z), a5);
        a6 = fmaf(w1, loF(u1.w), a6);
        a7 = fmaf(w1, hiF(u1.w), a7);
    }
    // reduce across the 8 groups (xor lane bits 3, 4, 5)
    a0 += __shfl_xor(a0, 8); a0 += __shfl_xor(a0, 16); a0 += __shfl_xor(a0, 32);
    a1 += __shfl_xor(a1, 8); a1 += __shfl_xor(a1, 16); a1 += __shfl_xor(a1, 32);
    a2 += __shfl_xor(a2, 8); a2 += __shfl_xor(a2, 16); a2 += __shfl_xor(a2, 32);
    a3 += __shfl_xor(a3, 8); a3 += __shfl_xor(a3, 16); a3 += __shfl_xor(a3, 32);
    a4 += __shfl_xor(a4, 8); a4 += __shfl_xor(a4, 16); a4 += __shfl_xor(a4, 32);
    a5 += __shfl_xor(a5, 8); a5 += __shfl_xor(a5, 16); a5 += __shfl_xor(a5, 32);
    a6 += __shfl_xor(a6, 8); a6 += __shfl_xor(a6, 16); a6 += __shfl_xor(a6, 32);
    a7 += __shfl_xor(a7, 8); a7 += __shfl_xor(a7, 16); a7 += __shfl_xor(a7, 32);

    if (q == 0 || (WLO && q == 1)) {
        float x0 = 0.f, x1 = 0.f, x2 = 0.f, x3 = 0.f;
        float x4 = 0.f, x5 = 0.f, x6 = 0.f, x7 = 0.f;
        if (MODE != 0) {
            if (AUXB) {
                uint4 ha = *(const uint4*)(auxH + (size_t)node * 64 + f);
                uint4 la = *(const uint4*)(auxL + (size_t)node * 64 + f);
                x0 = loF(ha.x) + loF(la.x);
                x1 = hiF(ha.x) + hiF(la.x);
                x2 = loF(ha.y) + loF(la.y);
                x3 = hiF(ha.y) + hiF(la.y);
                x4 = loF(ha.z) + loF(la.z);
                x5 = hiF(ha.z) + hiF(la.z);
                x6 = loF(ha.w) + loF(la.w);
                x7 = hiF(ha.w) + hiF(la.w);
            } else {
                float4 av0 = *(const float4*)(auxF + (size_t)node * SA + f);
                float4 av1 = *(const float4*)(auxF + (size_t)node * SA + f + 4);
                x0 = av0.x; x1 = av0.y; x2 = av0.z; x3 = av0.w;
                x4 = av1.x; x5 = av1.y; x6 = av1.z; x7 = av1.w;
            }
        }
        float r0, r1, r2, r3, r4, r5, r6, r7;
        if (MODE == 0) {
            r0 = a0; r1 = a1; r2 = a2; r3 = a3;
            r4 = a4; r5 = a5; r6 = a6; r7 = a7;
        } else if (MODE == 1) {
            r0 = x0 + 2.f * a0; r1 = x1 + 2.f * a1;
            r2 = x2 + 2.f * a2; r3 = x3 + 2.f * a3;
            r4 = x4 + 2.f * a4; r5 = x5 + 2.f * a5;
            r6 = x6 + 2.f * a6; r7 = x7 + 2.f * a7;
        } else if (MODE == 2) {
            r0 = 2.f * a0 - x0; r1 = 2.f * a1 - x1;
            r2 = 2.f * a2 - x2; r3 = 2.f * a3 - x3;
            r4 = 2.f * a4 - x4; r5 = 2.f * a5 - x5;
            r6 = 2.f * a6 - x6; r7 = 2.f * a7 - x7;
        } else {
            float4 bv0 = *(const float4*)(bias + f);
            float4 bv1 = *(const float4*)(bias + f + 4);
            r0 = fmaxf(x0 + a0 + bv0.x, 0.f);
            r1 = fmaxf(x1 + a1 + bv0.y, 0.f);
            r2 = fmaxf(x2 + a2 + bv0.z, 0.f);
            r3 = fmaxf(x3 + a3 + bv0.w, 0.f);
            r4 = fmaxf(x4 + a4 + bv1.x, 0.f);
            r5 = fmaxf(x5 + a5 + bv1.y, 0.f);
            r6 = fmaxf(x6 + a6 + bv1.z, 0.f);
            r7 = fmaxf(x7 + a7 + bv1.w, 0.f);
        }
        ushortT h0 = f2b(r0), h1 = f2b(r1), h2 = f2b(r2), h3 = f2b(r3);
        ushortT h4 = f2b(r4), h5 = f2b(r5), h6 = f2b(r6), h7 = f2b(r7);
        if (q == 0) {
            uint4 pk;
            pk.x = (uintT)h0 | ((uintT)h1 << 16);
            pk.y = (uintT)h2 | ((uintT)h3 << 16);
            pk.z = (uintT)h4 | ((uintT)h5 << 16);
            pk.w = (uintT)h6 | ((uintT)h7 << 16);
            *(uint4*)(Yh + (size_t)node * 64 + f) = pk;
        } else {
            uint4 pk;
            pk.x = (uintT)f2b(r0 - b2f(h0)) | ((uintT)f2b(r1 - b2f(h1)) << 16);
            pk.y = (uintT)f2b(r2 - b2f(h2)) | ((uintT)f2b(r3 - b2f(h3)) << 16);
            pk.z = (uintT)f2b(r4 - b2f(h4)) | ((uintT)f2b(r5 - b2f(h5)) << 16);
            pk.w = (uintT)f2b(r6 - b2f(h6)) | ((uintT)f2b(r7 - b2f(h7)) << 16);
            *(uint4*)(Yl + (size_t)node * 64 + f) = pk;
        }
    }
}

// ---------------------------------------------------------------------------
// Pooling: 64 consecutive nodes per block (batch sorted -> run-length)
// ---------------------------------------------------------------------------
__global__ __launch_bounds__(128) void k_pool(const int* __restrict__ batch,
                                              const float* __restrict__ H3,
                                              float* __restrict__ pooled,
                                              float* __restrict__ gcnt) {
    int t = threadIdx.x;
    int n0 = blockIdx.x * 64;
    int g = batch[n0];
    float a = 0.f;
    int c = 0;
    for (int k = 0; k < 64; k++) {
        int gn = batch[n0 + k];
        if (gn != g) {
            atomicAdd(&pooled[(size_t)g * 128 + t], a);
            if (t == 0) atomicAdd(&gcnt[g], (float)c);
            g = gn; a = 0.f; c = 0;
        }
        a += H3[(size_t)(n0 + k) * 128 + t];
        c++;
    }
    atomicAdd(&pooled[(size_t)g * 128 + t], a);
    if (t == 0) atomicAdd(&gcnt[g], (float)c);
}

__global__ void k_final(const float* __restrict__ pooled, const float* __restrict__ gcnt,
                        const float* __restrict__ lin_w, const float* __restrict__ lin_b,
                        float* __restrict__ out) {
    int g = blockIdx.x * 4 + (threadIdx.x >> 6);
    int lane = threadIdx.x & 63;
    if (g >= N_GRAPHS) return;
    float inv = 1.f / fmaxf(gcnt[g], 1.f);
    float v0 = pooled[(size_t)g * 128 + lane] * inv;
    float v1 = pooled[(size_t)g * 128 + 64 + lane] * inv;
    float p0 = v0 * lin_w[lane * 2 + 0] + v1 * lin_w[(lane + 64) * 2 + 0];
    float p1 = v0 * lin_w[lane * 2 + 1] + v1 * lin_w[(lane + 64) * 2 + 1];
    for (int o = 32; o > 0; o >>= 1) {
        p0 += __shfl_down(p0, o);
        p1 += __shfl_down(p1, o);
    }
    if (lane == 0) {
        out[g * 2 + 0] = p0 + lin_b[0];
        out[g * 2 + 1] = p1 + lin_b[1];
    }
}

// ---------------------------------------------------------------------------
extern "C" void kernel_launch(void* const* d_in, const int* in_sizes, int n_in,
                              void* d_out, int out_size, void* d_ws, size_t ws_size,
                              hipStream_t stream) {
    const float* x     = (const float*)d_in[0];
    const int*   src   = (const int*)d_in[1];
    const int*   dst   = src + N_EDGES;
    const float* eattr = (const float*)d_in[2];
    const int*   batch = (const int*)d_in[3];
    const float* w1    = (const float*)d_in[4];
    const float* b1    = (const float*)d_in[5];
    const float* w2    = (const float*)d_in[6];
    const float* b2    = (const float*)d_in[7];
    const float* w3    = (const float*)d_in[8];
    const float* b3    = (const float*)d_in[9];
    const float* lin_w = (const float*)d_in[10];
    const float* lin_b = (const float*)d_in[11];
    float* out = (float*)d_out;

    char* ws = (char*)d_ws;
    size_t off = 0;
    auto alloc = [&](size_t bytes) -> char* {
        char* p = ws + off;
        off += (bytes + 255) & ~(size_t)255;
        return p;
    };
    int*   blkCntD   = (int*)  alloc((size_t)NBB * NBUCK * 4);   // 819 KB
    int*   blkCntS   = (int*)  alloc((size_t)NBB * NBUCK * 4);
    int*   blkRelD   = (int*)  alloc((size_t)NBB * NBUCK * 4);
    int*   blkRelS   = (int*)  alloc((size_t)NBB * NBUCK * 4);
    int*   bucketTotD = (int*) alloc(NBUCK * 4);
    int*   bucketTotS = (int*) alloc(NBUCK * 4);
    int*   binBaseD  = (int*)  alloc((NBUCK + 1) * 4);
    int*   binBaseS  = (int*)  alloc((NBUCK + 1) * 4);
    float* dinv      = (float*)alloc((size_t)N_NODES * 4);
    int*   rowp      = (int*)  alloc((size_t)(N_NODES + 1) * 4);
    ushortT* Wt1h   = (ushortT*)alloc(192 * 128 * 2);
    ushortT* Wt1l   = (ushortT*)alloc(192 * 128 * 2);
    ushortT* Wt2h   = (ushortT*)alloc(192 * 64 * 2);
    ushortT* Wt2l   = (ushortT*)alloc(192 * 64 * 2);
    ushortT* Wt3h   = (ushortT*)alloc(128 * 192 * 2);
    ushortT* Wt3l   = (ushortT*)alloc(128 * 192 * 2);
    float* pooled   = (float*)alloc((size_t)(N_GRAPHS * 128 + N_GRAPHS) * 4);
    float* gcnt     = pooled + (size_t)N_GRAPHS * 128;
    int2*  cedge    = (int2*) alloc((size_t)N_EDGES * 8);      // 26.2 MB
    char*  Buf1     = alloc((size_t)N_EDGES * 16);             // 52.4 MB
    char*  Buf2     = alloc((size_t)N_NODES * 128 * 4);        // 52.4 MB
    char*  Buf3     = alloc(4 * N64 * 2);                      // 52.4 MB

    // Buf1: edsD|edsS (build)  ->  Xhi/Xlo [2][N][64]  ->  GThi [3][N][64]
    int2* edsD = (int2*)Buf1;
    int2* edsS = edsD + N_EDGES;
    ushortT* Xhi  = (ushortT*)Buf1;
    ushortT* Xlo  = Xhi + 2 * N64;
    ushortT* GThi = (ushortT*)Buf1;          // slots 0,1,2 contiguous
    // Buf2: P fp32 [N][128] (P0c | P1)  ->  H3 fp32 [N][128]
    float* P  = (float*)Buf2;
    float* H3 = (float*)Buf2;
    // Buf3: G0 | Qhi | H1hi | H1lo ; GTlo slots alias regions 0,2,3
    ushortT* G0    = (ushortT*)Buf3;
    ushortT* Qhi   = G0 + N64;
    ushortT* H1hi  = G0 + 2 * N64;
    ushortT* H1lo  = G0 + 3 * N64;
    ushortT* GTlo0 = G0;      // written after G0's last read
    ushortT* GTlo1 = H1hi;    // written after H1hi's last read
    ushortT* GTlo2 = H1lo;    // written after H1lo's last read

    hipMemsetAsync(pooled, 0, (size_t)(N_GRAPHS * 128 + N_GRAPHS) * 4, stream);

    // ---- CSR build: deterministic counting sorts, zero global atomics.
    k_binA<<<NBB, 256, 0, stream>>>(src, dst, blkCntD, blkCntS);
    k_bbase<<<NBUCK, 256, 0, stream>>>(blkCntD, blkRelD, bucketTotD);
    k_bbase<<<NBUCK, 256, 0, stream>>>(blkCntS, blkRelS, bucketTotS);
    k_bscan<<<1, 128, 0, stream>>>(bucketTotD, bucketTotS, binBaseD, binBaseS, rowp);
    k_binBS<<<NBB, 256, 0, stream>>>(src, eattr, blkCntS, blkRelS, binBaseS, edsS);
    k_deg<<<NBUCK, 256, 0, stream>>>(edsS, binBaseS, dinv);
    k_binB<<<NBB, 256, 0, stream>>>(src, dst, eattr, blkCntD, blkRelD, binBaseD, edsD);
    k_csr<<<NBUCK, 512, 0, stream>>>(edsD, binBaseD, dinv, rowp, cedge);

    // ---- Prep: x cast (after edsD/edsS consumed), weight transpose+split
    k_cast<<<N_NODES * 32 / 256, 256, 0, stream>>>(x, Xhi, Xlo);
    k_wprep<1><<<96, 256, 0, stream>>>(w1, Wt1h, Wt1l);
    k_wprep<2><<<48, 256, 0, stream>>>(w2, Wt2h, Wt2l);
    k_wprep<3><<<96, 256, 0, stream>>>(w3, Wt3h, Wt3l);

    // ---- Layer 1 (128 -> 64): P0c,P1 fp32 + P2 bf16 table (G0)
    k_mgemm<128, 192, 0><<<N_NODES / 256, 512, 0, stream>>>(
        Xhi, Xhi + N64, nullptr, Xlo, Xlo + N64, nullptr, Wt1h, Wt1l, nullptr, P, G0);
    // Q = P1 + 2*L*P2 -> Qhi
    k_spmm<1, 128, false, false><<<N_NODES / 4, 256, 0, stream>>>(
        rowp, cedge, G0, P + 64, nullptr, nullptr, nullptr, Qhi, nullptr);
    // H1 = relu(P0c + L*Q + b1) -> H1hi/H1lo
    k_spmm<3, 128, false, true><<<N_NODES / 4, 256, 0, stream>>>(
        rowp, cedge, Qhi, P, nullptr, nullptr, b1, H1hi, H1lo);

    // ---- Layer 2 (64 -> 64)
    k_mgemm<64, 192, 0><<<N_NODES / 256, 512, 0, stream>>>(
        H1hi, nullptr, nullptr, H1lo, nullptr, nullptr, Wt2h, Wt2l, nullptr, P, G0);
    k_spmm<1, 128, false, false><<<N_NODES / 4, 256, 0, stream>>>(
        rowp, cedge, G0, P + 64, nullptr, nullptr, nullptr, Qhi, nullptr);
    // T0 = relu(P0c + L*Q + b2) -> GThi[0]/GTlo[0]
    k_spmm<3, 128, false, true><<<N_NODES / 4, 256, 0, stream>>>(
        rowp, cedge, Qhi, P, nullptr, nullptr, b2, GThi, GTlo0);

    // ---- Layer 3 (64 -> 128), spmm-first
    // T1 = L*T0 -> GThi[1]/GTlo[1]
    k_spmm<0, 64, false, true><<<N_NODES / 4, 256, 0, stream>>>(
        rowp, cedge, GThi, nullptr, nullptr, nullptr, nullptr, GThi + N64, GTlo1);
    // T2 = 2*L*T1 - T0 -> GThi[2]/GTlo[2]  (Aux = T0 via hi+lo)
    k_spmm<2, 64, true, true><<<N_NODES / 4, 256, 0, stream>>>(
        rowp, cedge, GThi + N64, nullptr, GThi, GTlo0, nullptr, GThi + 2 * N64, GTlo2);
    // H3 = relu([T0|T1|T2] @ w3 + b3) -> H3 fp32
    k_mgemm<192, 128, 1><<<N_NODES / 256, 512, 0, stream>>>(
        GThi, GThi + N64, GThi + 2 * N64, GTlo0, GTlo1, GTlo2, Wt3h, Wt3l, b3, H3, nullptr);

    // ---- Pool + final linear
    k_pool<<<N_NODES / 64, 128, 0, stream>>>(batch, H3, pooled, gcnt);
    k_final<<<N_GRAPHS / 4, 256, 0, stream>>>(pooled, gcnt, lin_w, lin_b, out);
}

// Round 8
// 739.144 us; speedup vs baseline: 1.0789x; 1.0276x over previous
//
#include <hip/hip_runtime.h>
#include <cstddef>
#include <cstdint>

#define N_NODES 102400
#define N_EDGES 3276800
#define N_GRAPHS 1024
#define NBUCK 400            // node >> 8 -> 400 buckets of 256 nodes
#define NBB 512              // binning blocks
#define EPB 6400             // edges per binning block (NBB*EPB == N_EDGES)
#define MAXB 12288           // per-bucket staging capacity in k_csr (avg 8192)
#define N64 ((size_t)N_NODES * 64)

typedef unsigned short ushortT;
typedef unsigned int uintT;
typedef __attribute__((ext_vector_type(8))) short bf16x8;
typedef __attribute__((ext_vector_type(4))) float f32x4;

__device__ __forceinline__ float b2f(ushortT h) {
    return __uint_as_float(((uintT)h) << 16);
}
__device__ __forceinline__ ushortT f2b(float f) {
    uintT u = __float_as_uint(f);
    uintT r = (u + 0x7fffu + ((u >> 16) & 1u)) >> 16;
    return (ushortT)r;
}
__device__ __forceinline__ float loF(uintT w) { return __uint_as_float(w << 16); }
__device__ __forceinline__ float hiF(uintT w) { return __uint_as_float(w & 0xffff0000u); }

// ---------------------------------------------------------------------------
// Pass A: per-block LDS histograms of dst AND src coarse buckets.
// int4 loads (4 edges/inst). Zero global atomics, zero scattered writes.
// ---------------------------------------------------------------------------
__global__ __launch_bounds__(256) void k_binA(const int* __restrict__ src,
                                              const int* __restrict__ dst,
                                              int* __restrict__ blkCntD,
                                              int* __restrict__ blkCntS) {
    __shared__ int hd[NBUCK], hs[NBUCK];
    int t = threadIdx.x;
    for (int i = t; i < NBUCK; i += 256) { hd[i] = 0; hs[i] = 0; }
    __syncthreads();
    int base = blockIdx.x * EPB;
    const int4* s4 = (const int4*)(src + base);
    const int4* d4 = (const int4*)(dst + base);
    for (int v = t; v < EPB / 4; v += 256) {
        int4 d = d4[v];
        int4 s = s4[v];
        atomicAdd(&hd[d.x >> 8], 1);
        atomicAdd(&hd[d.y >> 8], 1);
        atomicAdd(&hd[d.z >> 8], 1);
        atomicAdd(&hd[d.w >> 8], 1);
        atomicAdd(&hs[s.x >> 8], 1);
        atomicAdd(&hs[s.y >> 8], 1);
        atomicAdd(&hs[s.z >> 8], 1);
        atomicAdd(&hs[s.w >> 8], 1);
    }
    __syncthreads();
    for (int i = t; i < NBUCK; i += 256) {
        blkCntD[(size_t)blockIdx.x * NBUCK + i] = hd[i];
        blkCntS[(size_t)blockIdx.x * NBUCK + i] = hs[i];
    }
}

// Per-bucket exclusive scan over NBB block counts -> blkRel[block][buck],
// plus bucket totals. (launched once for D, once for S)
__global__ __launch_bounds__(256) void k_bbase(const int* __restrict__ blkCnt,
                                               int* __restrict__ blkRel,
                                               int* __restrict__ bucketTot) {
    __shared__ int sc[NBB];
    int b = blockIdx.x, t = threadIdx.x;
    int v0 = blkCnt[(size_t)t * NBUCK + b];
    int v1 = blkCnt[(size_t)(t + 256) * NBUCK + b];
    sc[t] = v0; sc[t + 256] = v1;
    __syncthreads();
    for (int o = 1; o < NBB; o <<= 1) {
        int x0 = (t >= o) ? sc[t - o] : 0;
        int x1 = (t + 256 >= o) ? sc[t + 256 - o] : 0;
        __syncthreads();
        sc[t] += x0; sc[t + 256] += x1;
        __syncthreads();
    }
    blkRel[(size_t)t * NBUCK + b] = sc[t] - v0;
    blkRel[(size_t)(t + 256) * NBUCK + b] = sc[t + 256] - v1;
    if (t == 255) bucketTot[b] = sc[NBB - 1];
}

// Serial scans of 400 bucket totals -> bucket bases (D and S), rowp tail.
__global__ void k_bscan(const int* __restrict__ bucketTotD,
                        const int* __restrict__ bucketTotS,
                        int* __restrict__ binBaseD,
                        int* __restrict__ binBaseS,
                        int* __restrict__ rowp) {
    int t = threadIdx.x;
    if (t == 0) {
        int run = 0;
        for (int i = 0; i < NBUCK; i++) { binBaseD[i] = run; run += bucketTotD[i]; }
        binBaseD[NBUCK] = run;
        rowp[N_NODES] = run;
    } else if (t == 64) {
        int run = 0;
        for (int i = 0; i < NBUCK; i++) { binBaseS[i] = run; run += bucketTotS[i]; }
        binBaseS[NBUCK] = run;
    }
}

// ---------------------------------------------------------------------------
// Pass B fused: BOTH deterministic counting sorts (dst-keyed -> edsD and
// src-keyed -> edsS) in one pass over src/dst/attr (39 MB read instead of
// 65 MB across two kernels). Staging position arrays store the ushort
// bucket id; global position = slot + delta[bucket] applied at flush.
// LDS: 2 x (sx 25.6K + sy 25.6K + spos 12.8K) + 4 x 1.6K = 134.4 KB.
// edsD: x = (src<<8)|dstLow, y = attr bits.  edsS: x = srcLow, y = attr.
// ---------------------------------------------------------------------------
__global__ __launch_bounds__(512) void k_binB2(const int* __restrict__ src,
                                               const int* __restrict__ dst,
                                               const float* __restrict__ attr,
                                               const int* __restrict__ blkCntD,
                                               const int* __restrict__ blkCntS,
                                               const int* __restrict__ blkRelD,
                                               const int* __restrict__ blkRelS,
                                               const int* __restrict__ binBaseD,
                                               const int* __restrict__ binBaseS,
                                               int2* __restrict__ edsD,
                                               int2* __restrict__ edsS) {
    __shared__ int sxD[EPB];        // D payload x (also D scan scratch)
    __shared__ int syD[EPB];        // D payload y
    __shared__ ushortT spD[EPB];    // D bucket id per slot
    __shared__ int sxS[EPB];        // S payload x (also S scan scratch)
    __shared__ int syS[EPB];        // S payload y
    __shared__ ushortT spS[EPB];    // S bucket id per slot
    __shared__ int lcurD[NBUCK], deltaD[NBUCK];
    __shared__ int lcurS[NBUCK], deltaS[NBUCK];
    int bx = blockIdx.x, t = threadIdx.x;

    // local exclusive scans of this block's 400 bucket counts (512-wide)
    int vD = (t < NBUCK) ? blkCntD[(size_t)bx * NBUCK + t] : 0;
    int vS = (t < NBUCK) ? blkCntS[(size_t)bx * NBUCK + t] : 0;
    sxD[t] = vD; sxS[t] = vS;
    __syncthreads();
    for (int o = 1; o < 512; o <<= 1) {
        int xD = (t >= o) ? sxD[t - o] : 0;
        int xS = (t >= o) ? sxS[t - o] : 0;
        __syncthreads();
        sxD[t] += xD; sxS[t] += xS;
        __syncthreads();
    }
    if (t < NBUCK) {
        int eD = sxD[t] - vD;
        lcurD[t] = eD;
        deltaD[t] = binBaseD[t] + blkRelD[(size_t)bx * NBUCK + t] - eD;
        int eS = sxS[t] - vS;
        lcurS[t] = eS;
        deltaS[t] = binBaseS[t] + blkRelS[(size_t)bx * NBUCK + t] - eS;
    }
    __syncthreads();

    int base = bx * EPB;
    for (int v = t; v < EPB / 2; v += 512) {
        int e0 = base + v * 2;
        int2 s2 = *(const int2*)(src + e0);
        int2 d2 = *(const int2*)(dst + e0);
        float2 a2 = *(const float2*)(attr + e0);
        int bkt, lp;
        // edge 0
        bkt = d2.x >> 8;
        lp = atomicAdd(&lcurD[bkt], 1);
        spD[lp] = (ushortT)bkt; sxD[lp] = (s2.x << 8) | (d2.x & 255);
        syD[lp] = __float_as_int(a2.x);
        bkt = s2.x >> 8;
        lp = atomicAdd(&lcurS[bkt], 1);
        spS[lp] = (ushortT)bkt; sxS[lp] = s2.x & 255;
        syS[lp] = __float_as_int(a2.x);
        // edge 1
        bkt = d2.y >> 8;
        lp = atomicAdd(&lcurD[bkt], 1);
        spD[lp] = (ushortT)bkt; sxD[lp] = (s2.y << 8) | (d2.y & 255);
        syD[lp] = __float_as_int(a2.y);
        bkt = s2.y >> 8;
        lp = atomicAdd(&lcurS[bkt], 1);
        spS[lp] = (ushortT)bkt; sxS[lp] = s2.y & 255;
        syS[lp] = __float_as_int(a2.y);
    }
    __syncthreads();
    // flush: slots sorted by bucket -> near-contiguous global stores
    for (int i = t; i < EPB; i += 512) {
        edsD[i + deltaD[spD[i]]] = make_int2(sxD[i], syD[i]);
        edsS[i + deltaS[spS[i]]] = make_int2(sxS[i], syS[i]);
    }
}

// Per-bucket weighted degree via LDS float accumulation -> dinv directly.
__global__ __launch_bounds__(256) void k_deg(const int2* __restrict__ edsS,
                                             const int* __restrict__ binBaseS,
                                             float* __restrict__ dinv) {
    __shared__ float degL[256];
    int b = blockIdx.x, t = threadIdx.x;
    degL[t] = 0.f;
    __syncthreads();
    int s0 = binBaseS[b], s1 = binBaseS[b + 1];
    for (int i = s0 + t; i < s1; i += 256) {
        int2 e = edsS[i];
        atomicAdd(&degL[e.x], __int_as_float(e.y));
    }
    __syncthreads();
    float d = degL[t];
    dinv[b * 256 + t] = d > 0.f ? rsqrtf(d) : 0.f;
}

// ---------------------------------------------------------------------------
// Per-bucket exact CSR, LDS-staged. cedge = -attr * dinv[src] * dinv[dst].
// Counting-sort key (dstLow, src>>13): rows come out src-banded.
// ---------------------------------------------------------------------------
__global__ __launch_bounds__(512) void k_csr(const int2* __restrict__ edsD,
                                             const int* __restrict__ binBaseD,
                                             const float* __restrict__ dinvG,
                                             int* __restrict__ rowp,
                                             int2* __restrict__ cedge) {
    __shared__ int cnt2[256 * 16];   // (dstLow, src>>13) counters -> cursors
    __shared__ int cntL[256];        // per-row totals -> prefix
    __shared__ float dL[256];
    __shared__ int2 st[MAXB];
    int b = blockIdx.x, t = threadIdx.x;
    for (int i = t; i < 256 * 16; i += 512) cnt2[i] = 0;
    if (t < 256) dL[t] = dinvG[b * 256 + t];
    __syncthreads();
    int s0 = binBaseD[b], s1 = binBaseD[b + 1];
    for (int i = s0 + t; i < s1; i += 512) {
        int2 e = edsD[i];
        atomicAdd(&cnt2[(e.x & 255) * 16 + ((e.x >> 8) >> 13)], 1);
    }
    __syncthreads();
    // per-row totals + in-place exclusive scan over the 16 src bands
    if (t < 256) {
        int run = 0;
#pragma unroll
        for (int o = 0; o < 16; o++) {
            int c = cnt2[t * 16 + o];
            cnt2[t * 16 + o] = run;
            run += c;
        }
        cntL[t] = run;
    }
    __syncthreads();
    int v = (t < 256) ? cntL[t] : 0;
    for (int o = 1; o < 256; o <<= 1) {
        int x = (t < 256 && t >= o) ? cntL[t - o] : 0;
        __syncthreads();
        if (t < 256) cntL[t] += x;
        __syncthreads();
    }
    if (t < 256) {
        int excl = cntL[t] - v;
        rowp[b * 256 + t] = s0 + excl;
        // make band cursors absolute within the staging buffer
#pragma unroll
        for (int o = 0; o < 16; o++) cnt2[t * 16 + o] += excl;
    }
    __syncthreads();
    for (int i = s0 + t; i < s1; i += 512) {
        int2 e = edsD[i];
        int dl = e.x & 255;
        int sg = e.x >> 8;
        float w = -__int_as_float(e.y) * dinvG[sg] * dL[dl];
        int p = atomicAdd(&cnt2[dl * 16 + (sg >> 13)], 1);
        st[p] = make_int2(sg, __float_as_int(w));
    }
    __syncthreads();
    int n = s1 - s0;
    for (int i = t; i < n; i += 512) cedge[s0 + i] = st[i];
}

// ---------------------------------------------------------------------------
// x -> slot-major bf16 hi/lo tables: Xhi/Xlo[s][n][64], s = k>>6
// ---------------------------------------------------------------------------
__global__ __launch_bounds__(256) void k_cast(const float* __restrict__ x,
                                              ushortT* __restrict__ Xhi,
                                              ushortT* __restrict__ Xlo) {
    int i = blockIdx.x * 256 + threadIdx.x;   // [0, N*32)
    int n = i >> 5;
    int kq = (i & 31) * 4;
    float4 v = ((const float4*)x)[i];
    int s = kq >> 6, kk = kq & 63;
    size_t o = (size_t)s * N64 + (size_t)n * 64 + kk;
    ushort4 h, l;
    h.x = f2b(v.x); l.x = f2b(v.x - b2f(h.x));
    h.y = f2b(v.y); l.y = f2b(v.y - b2f(h.y));
    h.z = f2b(v.z); l.z = f2b(v.z - b2f(h.z));
    h.w = f2b(v.w); l.w = f2b(v.w - b2f(h.w));
    *(ushort4*)(Xhi + o) = h;
    *(ushort4*)(Xlo + o) = l;
}

// ---------------------------------------------------------------------------
// Weight prep: transposed [N][K] bf16 hi/lo tables.
// ---------------------------------------------------------------------------
template <int L>
__global__ void k_wprep(const float* __restrict__ w, ushortT* __restrict__ Wth,
                        ushortT* __restrict__ Wtl) {
    int i = blockIdx.x * 256 + threadIdx.x;
    float v;
    if (L == 1) {
        if (i >= 192 * 128) return;
        int n = i / 128, k = i % 128;
        if (n < 64)       v = w[k * 64 + n] - w[16384 + k * 64 + n];
        else if (n < 128) v = w[8192 + k * 64 + (n - 64)];
        else              v = w[16384 + k * 64 + (n - 128)];
    } else if (L == 2) {
        if (i >= 192 * 64) return;
        int n = i / 64, k = i % 64;
        if (n < 64)       v = w[k * 64 + n] - w[8192 + k * 64 + n];
        else if (n < 128) v = w[4096 + k * 64 + (n - 64)];
        else              v = w[8192 + k * 64 + (n - 128)];
    } else {
        if (i >= 128 * 192) return;
        int n = i / 192, k = i % 192;
        v = w[(k >> 6) * 8192 + (k & 63) * 128 + n];
    }
    ushortT h = f2b(v);
    Wth[i] = h;
    Wtl[i] = f2b(v - b2f(h));
}

// ---------------------------------------------------------------------------
// MFMA GEMM v2: one block = 256 rows x ALL NTOT cols (no blockIdx.y
// redundancy -> A read once). W (hi+lo) staged in LDS in 64-wide K-chunks
// (pad stride 72 shorts -> bank-stride 4 mod 32, conflict-free floor).
// 8 waves x (32 rows x NTOT cols) each; per k-step per wave:
// 4 global A loads + 2*NCT ds_reads + 6*NCT MFMAs (MFMA-dominated mix).
// acc = Ahi*Whi + Alo*Whi + Ahi*Wlo  (~fp32 accuracy).
// MODE 0: ct<8 -> fp32 out[n*128 + ct*16+m]; ct>=8 -> bf16 outb[n*64 + ...]
// MODE 1: fp32 out[n*128 + col] = relu(acc + bias[col])
// ---------------------------------------------------------------------------
template <int KTOT, int NTOT, int MODE>
__global__ __launch_bounds__(512) void k_mgemm(
    const ushortT* __restrict__ Ah0, const ushortT* __restrict__ Ah1,
    const ushortT* __restrict__ Ah2, const ushortT* __restrict__ Al0,
    const ushortT* __restrict__ Al1, const ushortT* __restrict__ Al2,
    const ushortT* __restrict__ Wth, const ushortT* __restrict__ Wtl,
    const float* __restrict__ bias, float* __restrict__ outf,
    ushortT* __restrict__ outb) {
    constexpr int KPAD = 72;          // 64-chunk + 8 shorts pad
    constexpr int NCT = NTOT / 16;
    __shared__ ushortT Bh[NTOT * KPAD];
    __shared__ ushortT Bl[NTOT * KPAD];
    const ushortT* Ah[3] = {Ah0, Ah1, Ah2};
    const ushortT* Al[3] = {Al0, Al1, Al2};
    int t = threadIdx.x;
    int lane = t & 63;
    int wv = t >> 6;                  // 8 waves
    int m = lane & 15, q = lane >> 4;
    int r0 = blockIdx.x * 256 + wv * 32;
    int ar0 = r0 + m;                 // row frag 0
    int ar1 = r0 + 16 + m;            // row frag 1

    f32x4 acc[2][NCT];
#pragma unroll
    for (int rf = 0; rf < 2; rf++)
#pragma unroll
        for (int ct = 0; ct < NCT; ct++)
#pragma unroll
            for (int j = 0; j < 4; j++) acc[rf][ct][j] = 0.f;

#pragma unroll
    for (int kc = 0; kc < KTOT / 64; kc++) {
        __syncthreads();
        // stage W[*, kc*64 .. kc*64+64) hi+lo into LDS (uint4 = 8 shorts)
        for (int i = t; i < NTOT * 8; i += 512) {
            int col = i >> 3, k = (i & 7) * 8;
            *(uint4*)(Bh + col * KPAD + k) =
                *(const uint4*)(Wth + (size_t)col * KTOT + kc * 64 + k);
            *(uint4*)(Bl + col * KPAD + k) =
                *(const uint4*)(Wtl + (size_t)col * KTOT + kc * 64 + k);
        }
        __syncthreads();
        const ushortT* Ahc = Ah[kc];
        const ushortT* Alc = Al[kc];
#pragma unroll
        for (int ks2 = 0; ks2 < 2; ks2++) {
            int kk = ks2 * 32 + q * 8;
            bf16x8 ah0 = *(const bf16x8*)(Ahc + (size_t)ar0 * 64 + kk);
            bf16x8 al0 = *(const bf16x8*)(Alc + (size_t)ar0 * 64 + kk);
            bf16x8 ah1 = *(const bf16x8*)(Ahc + (size_t)ar1 * 64 + kk);
            bf16x8 al1 = *(const bf16x8*)(Alc + (size_t)ar1 * 64 + kk);
#pragma unroll
            for (int ct = 0; ct < NCT; ct++) {
                int bo = (ct * 16 + m) * KPAD + ks2 * 32 + q * 8;
                bf16x8 bh = *(const bf16x8*)(Bh + bo);
                bf16x8 bl = *(const bf16x8*)(Bl + bo);
                acc[0][ct] = __builtin_amdgcn_mfma_f32_16x16x32_bf16(ah0, bh, acc[0][ct], 0, 0, 0);
                acc[0][ct] = __builtin_amdgcn_mfma_f32_16x16x32_bf16(al0, bh, acc[0][ct], 0, 0, 0);
                acc[0][ct] = __builtin_amdgcn_mfma_f32_16x16x32_bf16(ah0, bl, acc[0][ct], 0, 0, 0);
                acc[1][ct] = __builtin_amdgcn_mfma_f32_16x16x32_bf16(ah1, bh, acc[1][ct], 0, 0, 0);
                acc[1][ct] = __builtin_amdgcn_mfma_f32_16x16x32_bf16(al1, bh, acc[1][ct], 0, 0, 0);
                acc[1][ct] = __builtin_amdgcn_mfma_f32_16x16x32_bf16(ah1, bl, acc[1][ct], 0, 0, 0);
            }
        }
    }

#pragma unroll
    for (int rf = 0; rf < 2; rf++)
#pragma unroll
        for (int ct = 0; ct < NCT; ct++)
#pragma unroll
            for (int rg = 0; rg < 4; rg++) {
                int row = r0 + rf * 16 + q * 4 + rg;
                float v = acc[rf][ct][rg];
                if (MODE == 0) {
                    if (ct < 8)
                        outf[(size_t)row * 128 + ct * 16 + m] = v;
                    else
                        outb[(size_t)row * 64 + (ct - 8) * 16 + m] = f2b(v);
                } else {
                    int col = ct * 16 + m;
                    outf[(size_t)row * 128 + col] = fmaxf(v + bias[col], 0.f);
                }
            }
}

// ---------------------------------------------------------------------------
// SpMM v3: 8 lanes per edge-row, each lane gathers uint4 = 8 bf16 features
// (16 B/lane coalescing sweet spot; one gather inst covers 8 edges, 1024 B).
// 16 edges per iteration via 2 slots -> 2 gather + 2 cedge insts per iter.
// q = lane>>3 edge slot in group of 8; f = (lane&7)*8 feature base.
// Cross-group shfl_xor(8,16,32) reduce; groups 0/1 write Yh/Yl.
// MODE 0: r = acc          MODE 1: r = aux + 2*acc
// MODE 2: r = 2*acc - aux  MODE 3: r = relu(aux + acc + bias)
// ---------------------------------------------------------------------------
template <int MODE, int SA, bool AUXB, bool WLO>
__global__ __launch_bounds__(256) void k_spmm(const int* __restrict__ rowp,
                                              const int2* __restrict__ cedge,
                                              const ushortT* __restrict__ Xb,
                                              const float* __restrict__ auxF,
                                              const ushortT* __restrict__ auxH,
                                              const ushortT* __restrict__ auxL,
                                              const float* __restrict__ bias,
                                              ushortT* __restrict__ Yh,
                                              ushortT* __restrict__ Yl) {
    int node = blockIdx.x * 4 + (threadIdx.x >> 6);
    int lane = threadIdx.x & 63;
    int q = lane >> 3;          // edge slot within group of 8
    int f = (lane & 7) * 8;     // feature base (8 features/lane)
    int s = rowp[node], e = rowp[node + 1];
    const ushortT* Xf = Xb + f;
    float a0 = 0.f, a1 = 0.f, a2 = 0.f, a3 = 0.f;
    float a4 = 0.f, a5 = 0.f, a6 = 0.f, a7 = 0.f;
    for (int i = s; i < e; i += 16) {
        int i0 = min(i + q, e - 1);
        int i1 = min(i + 8 + q, e - 1);
        int2 ed0 = cedge[i0];
        int2 ed1 = cedge[i1];
        float w0 = (i + q < e) ? __int_as_float(ed0.y) : 0.f;
        float w1 = (i + 8 + q < e) ? __int_as_float(ed1.y) : 0.f;
        uint4 u0 = *(const uint4*)(Xf + ((size_t)ed0.x << 6));
        uint4 u1 = *(const uint4*)(Xf + ((size_t)ed1.x << 6));
        a0 = fmaf(w0, loF(u0.x), a0);
        a1 = fmaf(w0, hiF(u0.x), a1);
        a2 = fmaf(w0, loF(u0.y), a2);
        a3 = fmaf(w0, hiF(u0.y), a3);
        a4 = fmaf(w0, loF(u0.z), a4);
        a5 = fmaf(w0, hiF(u0.z), a5);
        a6 = fmaf(w0, loF(u0.w), a6);
        a7 = fmaf(w0, hiF(u0.w), a7);
        a0 = fmaf(w1, loF(u1.x), a0);
        a1 = fmaf(w1, hiF(u1.x), a1);
        a2 = fmaf(w1, loF(u1.y), a2);
        a3 = fmaf(w1, hiF(u1.y), a3);
        a4 = fmaf(w1, loF(u1.z), a4);
        a5 = fmaf(w1, hiF(u1.z), a5);
        a6 = fmaf(w1, loF(u1.w), a6);
        a7 = fmaf(w1, hiF(u1.w), a7);
    }
    // reduce across the 8 groups (xor lane bits 3, 4, 5)
    a0 += __shfl_xor(a0, 8); a0 += __shfl_xor(a0, 16); a0 += __shfl_xor(a0, 32);
    a1 += __shfl_xor(a1, 8); a1 += __shfl_xor(a1, 16); a1 += __shfl_xor(a1, 32);
    a2 += __shfl_xor(a2, 8); a2 += __shfl_xor(a2, 16); a2 += __shfl_xor(a2, 32);
    a3 += __shfl_xor(a3, 8); a3 += __shfl_xor(a3, 16); a3 += __shfl_xor(a3, 32);
    a4 += __shfl_xor(a4, 8); a4 += __shfl_xor(a4, 16); a4 += __shfl_xor(a4, 32);
    a5 += __shfl_xor(a5, 8); a5 += __shfl_xor(a5, 16); a5 += __shfl_xor(a5, 32);
    a6 += __shfl_xor(a6, 8); a6 += __shfl_xor(a6, 16); a6 += __shfl_xor(a6, 32);
    a7 += __shfl_xor(a7, 8); a7 += __shfl_xor(a7, 16); a7 += __shfl_xor(a7, 32);

    if (q == 0 || (WLO && q == 1)) {
        float x0 = 0.f, x1 = 0.f, x2 = 0.f, x3 = 0.f;
        float x4 = 0.f, x5 = 0.f, x6 = 0.f, x7 = 0.f;
        if (MODE != 0) {
            if (AUXB) {
                uint4 ha = *(const uint4*)(auxH + (size_t)node * 64 + f);
                uint4 la = *(const uint4*)(auxL + (size_t)node * 64 + f);
                x0 = loF(ha.x) + loF(la.x);
                x1 = hiF(ha.x) + hiF(la.x);
                x2 = loF(ha.y) + loF(la.y);
                x3 = hiF(ha.y) + hiF(la.y);
                x4 = loF(ha.z) + loF(la.z);
                x5 = hiF(ha.z) + hiF(la.z);
                x6 = loF(ha.w) + loF(la.w);
                x7 = hiF(ha.w) + hiF(la.w);
            } else {
                float4 av0 = *(const float4*)(auxF + (size_t)node * SA + f);
                float4 av1 = *(const float4*)(auxF + (size_t)node * SA + f + 4);
                x0 = av0.x; x1 = av0.y; x2 = av0.z; x3 = av0.w;
                x4 = av1.x; x5 = av1.y; x6 = av1.z; x7 = av1.w;
            }
        }
        float r0, r1, r2, r3, r4, r5, r6, r7;
        if (MODE == 0) {
            r0 = a0; r1 = a1; r2 = a2; r3 = a3;
            r4 = a4; r5 = a5; r6 = a6; r7 = a7;
        } else if (MODE == 1) {
            r0 = x0 + 2.f * a0; r1 = x1 + 2.f * a1;
            r2 = x2 + 2.f * a2; r3 = x3 + 2.f * a3;
            r4 = x4 + 2.f * a4; r5 = x5 + 2.f * a5;
            r6 = x6 + 2.f * a6; r7 = x7 + 2.f * a7;
        } else if (MODE == 2) {
            r0 = 2.f * a0 - x0; r1 = 2.f * a1 - x1;
            r2 = 2.f * a2 - x2; r3 = 2.f * a3 - x3;
            r4 = 2.f * a4 - x4; r5 = 2.f * a5 - x5;
            r6 = 2.f * a6 - x6; r7 = 2.f * a7 - x7;
        } else {
            float4 bv0 = *(const float4*)(bias + f);
            float4 bv1 = *(const float4*)(bias + f + 4);
            r0 = fmaxf(x0 + a0 + bv0.x, 0.f);
            r1 = fmaxf(x1 + a1 + bv0.y, 0.f);
            r2 = fmaxf(x2 + a2 + bv0.z, 0.f);
            r3 = fmaxf(x3 + a3 + bv0.w, 0.f);
            r4 = fmaxf(x4 + a4 + bv1.x, 0.f);
            r5 = fmaxf(x5 + a5 + bv1.y, 0.f);
            r6 = fmaxf(x6 + a6 + bv1.z, 0.f);
            r7 = fmaxf(x7 + a7 + bv1.w, 0.f);
        }
        ushortT h0 = f2b(r0), h1 = f2b(r1), h2 = f2b(r2), h3 = f2b(r3);
        ushortT h4 = f2b(r4), h5 = f2b(r5), h6 = f2b(r6), h7 = f2b(r7);
        if (q == 0) {
            uint4 pk;
            pk.x = (uintT)h0 | ((uintT)h1 << 16);
            pk.y = (uintT)h2 | ((uintT)h3 << 16);
            pk.z = (uintT)h4 | ((uintT)h5 << 16);
            pk.w = (uintT)h6 | ((uintT)h7 << 16);
            *(uint4*)(Yh + (size_t)node * 64 + f) = pk;
        } else {
            uint4 pk;
            pk.x = (uintT)f2b(r0 - b2f(h0)) | ((uintT)f2b(r1 - b2f(h1)) << 16);
            pk.y = (uintT)f2b(r2 - b2f(h2)) | ((uintT)f2b(r3 - b2f(h3)) << 16);
            pk.z = (uintT)f2b(r4 - b2f(h4)) | ((uintT)f2b(r5 - b2f(h5)) << 16);
            pk.w = (uintT)f2b(r6 - b2f(h6)) | ((uintT)f2b(r7 - b2f(h7)) << 16);
            *(uint4*)(Yl + (size_t)node * 64 + f) = pk;
        }
    }
}

// ---------------------------------------------------------------------------
// Pooling: 64 consecutive nodes per block (batch sorted -> run-length)
// ---------------------------------------------------------------------------
__global__ __launch_bounds__(128) void k_pool(const int* __restrict__ batch,
                                              const float* __restrict__ H3,
                                              float* __restrict__ pooled,
                                              float* __restrict__ gcnt) {
    int t = threadIdx.x;
    int n0 = blockIdx.x * 64;
    int g = batch[n0];
    float a = 0.f;
    int c = 0;
    for (int k = 0; k < 64; k++) {
        int gn = batch[n0 + k];
        if (gn != g) {
            atomicAdd(&pooled[(size_t)g * 128 + t], a);
            if (t == 0) atomicAdd(&gcnt[g], (float)c);
            g = gn; a = 0.f; c = 0;
        }
        a += H3[(size_t)(n0 + k) * 128 + t];
        c++;
    }
    atomicAdd(&pooled[(size_t)g * 128 + t], a);
    if (t == 0) atomicAdd(&gcnt[g], (float)c);
}

__global__ void k_final(const float* __restrict__ pooled, const float* __restrict__ gcnt,
                        const float* __restrict__ lin_w, const float* __restrict__ lin_b,
                        float* __restrict__ out) {
    int g = blockIdx.x * 4 + (threadIdx.x >> 6);
    int lane = threadIdx.x & 63;
    if (g >= N_GRAPHS) return;
    float inv = 1.f / fmaxf(gcnt[g], 1.f);
    float v0 = pooled[(size_t)g * 128 + lane] * inv;
    float v1 = pooled[(size_t)g * 128 + 64 + lane] * inv;
    float p0 = v0 * lin_w[lane * 2 + 0] + v1 * lin_w[(lane + 64) * 2 + 0];
    float p1 = v0 * lin_w[lane * 2 + 1] + v1 * lin_w[(lane + 64) * 2 + 1];
    for (int o = 32; o > 0; o >>= 1) {
        p0 += __shfl_down(p0, o);
        p1 += __shfl_down(p1, o);
    }
    if (lane == 0) {
        out[g * 2 + 0] = p0 + lin_b[0];
        out[g * 2 + 1] = p1 + lin_b[1];
    }
}

// ---------------------------------------------------------------------------
extern "C" void kernel_launch(void* const* d_in, const int* in_sizes, int n_in,
                              void* d_out, int out_size, void* d_ws, size_t ws_size,
                              hipStream_t stream) {
    const float* x     = (const float*)d_in[0];
    const int*   src   = (const int*)d_in[1];
    const int*   dst   = src + N_EDGES;
    const float* eattr = (const float*)d_in[2];
    const int*   batch = (const int*)d_in[3];
    const float* w1    = (const float*)d_in[4];
    const float* b1    = (const float*)d_in[5];
    const float* w2    = (const float*)d_in[6];
    const float* b2    = (const float*)d_in[7];
    const float* w3    = (const float*)d_in[8];
    const float* b3    = (const float*)d_in[9];
    const float* lin_w = (const float*)d_in[10];
    const float* lin_b = (const float*)d_in[11];
    float* out = (float*)d_out;

    char* ws = (char*)d_ws;
    size_t off = 0;
    auto alloc = [&](size_t bytes) -> char* {
        char* p = ws + off;
        off += (bytes + 255) & ~(size_t)255;
        return p;
    };
    int*   blkCntD   = (int*)  alloc((size_t)NBB * NBUCK * 4);   // 819 KB
    int*   blkCntS   = (int*)  alloc((size_t)NBB * NBUCK * 4);
    int*   blkRelD   = (int*)  alloc((size_t)NBB * NBUCK * 4);
    int*   blkRelS   = (int*)  alloc((size_t)NBB * NBUCK * 4);
    int*   bucketTotD = (int*) alloc(NBUCK * 4);
    int*   bucketTotS = (int*) alloc(NBUCK * 4);
    int*   binBaseD  = (int*)  alloc((NBUCK + 1) * 4);
    int*   binBaseS  = (int*)  alloc((NBUCK + 1) * 4);
    float* dinv      = (float*)alloc((size_t)N_NODES * 4);
    int*   rowp      = (int*)  alloc((size_t)(N_NODES + 1) * 4);
    ushortT* Wt1h   = (ushortT*)alloc(192 * 128 * 2);
    ushortT* Wt1l   = (ushortT*)alloc(192 * 128 * 2);
    ushortT* Wt2h   = (ushortT*)alloc(192 * 64 * 2);
    ushortT* Wt2l   = (ushortT*)alloc(192 * 64 * 2);
    ushortT* Wt3h   = (ushortT*)alloc(128 * 192 * 2);
    ushortT* Wt3l   = (ushortT*)alloc(128 * 192 * 2);
    float* pooled   = (float*)alloc((size_t)(N_GRAPHS * 128 + N_GRAPHS) * 4);
    float* gcnt     = pooled + (size_t)N_GRAPHS * 128;
    int2*  cedge    = (int2*) alloc((size_t)N_EDGES * 8);      // 26.2 MB
    char*  Buf1     = alloc((size_t)N_EDGES * 16);             // 52.4 MB
    char*  Buf2     = alloc((size_t)N_NODES * 128 * 4);        // 52.4 MB
    char*  Buf3     = alloc(4 * N64 * 2);                      // 52.4 MB

    // Buf1: edsD|edsS (build)  ->  Xhi/Xlo [2][N][64]  ->  GThi [3][N][64]
    int2* edsD = (int2*)Buf1;
    int2* edsS = edsD + N_EDGES;
    ushortT* Xhi  = (ushortT*)Buf1;
    ushortT* Xlo  = Xhi + 2 * N64;
    ushortT* GThi = (ushortT*)Buf1;          // slots 0,1,2 contiguous
    // Buf2: P fp32 [N][128] (P0c | P1)  ->  H3 fp32 [N][128]
    float* P  = (float*)Buf2;
    float* H3 = (float*)Buf2;
    // Buf3: G0 | Qhi | H1hi | H1lo ; GTlo slots alias regions 0,2,3
    ushortT* G0    = (ushortT*)Buf3;
    ushortT* Qhi   = G0 + N64;
    ushortT* H1hi  = G0 + 2 * N64;
    ushortT* H1lo  = G0 + 3 * N64;
    ushortT* GTlo0 = G0;      // written after G0's last read
    ushortT* GTlo1 = H1hi;    // written after H1hi's last read
    ushortT* GTlo2 = H1lo;    // written after H1lo's last read

    hipMemsetAsync(pooled, 0, (size_t)(N_GRAPHS * 128 + N_GRAPHS) * 4, stream);

    // ---- CSR build: deterministic counting sorts, zero global atomics.
    k_binA<<<NBB, 256, 0, stream>>>(src, dst, blkCntD, blkCntS);
    k_bbase<<<NBUCK, 256, 0, stream>>>(blkCntD, blkRelD, bucketTotD);
    k_bbase<<<NBUCK, 256, 0, stream>>>(blkCntS, blkRelS, bucketTotS);
    k_bscan<<<1, 128, 0, stream>>>(bucketTotD, bucketTotS, binBaseD, binBaseS, rowp);
    k_binB2<<<NBB, 512, 0, stream>>>(src, dst, eattr, blkCntD, blkCntS,
                                     blkRelD, blkRelS, binBaseD, binBaseS,
                                     edsD, edsS);
    k_deg<<<NBUCK, 256, 0, stream>>>(edsS, binBaseS, dinv);
    k_csr<<<NBUCK, 512, 0, stream>>>(edsD, binBaseD, dinv, rowp, cedge);

    // ---- Prep: x cast (after edsD/edsS consumed), weight transpose+split
    k_cast<<<N_NODES * 32 / 256, 256, 0, stream>>>(x, Xhi, Xlo);
    k_wprep<1><<<96, 256, 0, stream>>>(w1, Wt1h, Wt1l);
    k_wprep<2><<<48, 256, 0, stream>>>(w2, Wt2h, Wt2l);
    k_wprep<3><<<96, 256, 0, stream>>>(w3, Wt3h, Wt3l);

    // ---- Layer 1 (128 -> 64): P0c,P1 fp32 + P2 bf16 table (G0)
    k_mgemm<128, 192, 0><<<N_NODES / 256, 512, 0, stream>>>(
        Xhi, Xhi + N64, nullptr, Xlo, Xlo + N64, nullptr, Wt1h, Wt1l, nullptr, P, G0);
    // Q = P1 + 2*L*P2 -> Qhi
    k_spmm<1, 128, false, false><<<N_NODES / 4, 256, 0, stream>>>(
        rowp, cedge, G0, P + 64, nullptr, nullptr, nullptr, Qhi, nullptr);
    // H1 = relu(P0c + L*Q + b1) -> H1hi/H1lo
    k_spmm<3, 128, false, true><<<N_NODES / 4, 256, 0, stream>>>(
        rowp, cedge, Qhi, P, nullptr, nullptr, b1, H1hi, H1lo);

    // ---- Layer 2 (64 -> 64)
    k_mgemm<64, 192, 0><<<N_NODES / 256, 512, 0, stream>>>(
        H1hi, nullptr, nullptr, H1lo, nullptr, nullptr, Wt2h, Wt2l, nullptr, P, G0);
    k_spmm<1, 128, false, false><<<N_NODES / 4, 256, 0, stream>>>(
        rowp, cedge, G0, P + 64, nullptr, nullptr, nullptr, Qhi, nullptr);
    // T0 = relu(P0c + L*Q + b2) -> GThi[0]/GTlo[0]
    k_spmm<3, 128, false, true><<<N_NODES / 4, 256, 0, stream>>>(
        rowp, cedge, Qhi, P, nullptr, nullptr, b2, GThi, GTlo0);

    // ---- Layer 3 (64 -> 128), spmm-first
    // T1 = L*T0 -> GThi[1]/GTlo[1]
    k_spmm<0, 64, false, true><<<N_NODES / 4, 256, 0, stream>>>(
        rowp, cedge, GThi, nullptr, nullptr, nullptr, nullptr, GThi + N64, GTlo1);
    // T2 = 2*L*T1 - T0 -> GThi[2]/GTlo[2]  (Aux = T0 via hi+lo)
    k_spmm<2, 64, true, true><<<N_NODES / 4, 256, 0, stream>>>(
        rowp, cedge, GThi + N64, nullptr, GThi, GTlo0, nullptr, GThi + 2 * N64, GTlo2);
    // H3 = relu([T0|T1|T2] @ w3 + b3) -> H3 fp32
    k_mgemm<192, 128, 1><<<N_NODES / 256, 512, 0, stream>>>(
        GThi, GThi + N64, GThi + 2 * N64, GTlo0, GTlo1, GTlo2, Wt3h, Wt3l, b3, H3, nullptr);

    // ---- Pool + final linear
    k_pool<<<N_NODES / 64, 128, 0, stream>>>(batch, H3, pooled, gcnt);
    k_final<<<N_GRAPHS / 4, 256, 0, stream>>>(pooled, gcnt, lin_w, lin_b, out);
}

// Round 9
// 727.413 us; speedup vs baseline: 1.0963x; 1.0161x over previous
//
#include <hip/hip_runtime.h>
#include <cstddef>
#include <cstdint>

#define N_NODES 102400
#define N_EDGES 3276800
#define N_GRAPHS 1024
#define NBUCK 400            // node >> 8 -> 400 buckets of 256 nodes
#define NBB 1024             // binning blocks
#define EPB 3200             // edges per binning block (NBB*EPB == N_EDGES)
#define MAXB 12288           // per-bucket staging capacity in k_csr (avg 8192)
#define N64 ((size_t)N_NODES * 64)

typedef unsigned short ushortT;
typedef unsigned int uintT;
typedef __attribute__((ext_vector_type(8))) short bf16x8;
typedef __attribute__((ext_vector_type(4))) float f32x4;

__device__ __forceinline__ float b2f(ushortT h) {
    return __uint_as_float(((uintT)h) << 16);
}
__device__ __forceinline__ ushortT f2b(float f) {
    uintT u = __float_as_uint(f);
    uintT r = (u + 0x7fffu + ((u >> 16) & 1u)) >> 16;
    return (ushortT)r;
}
__device__ __forceinline__ float loF(uintT w) { return __uint_as_float(w << 16); }
__device__ __forceinline__ float hiF(uintT w) { return __uint_as_float(w & 0xffff0000u); }

// ---------------------------------------------------------------------------
// Pass A: per-block LDS histograms of dst AND src coarse buckets.
// int4 loads (4 edges/inst). Zero global atomics, zero scattered writes.
// ---------------------------------------------------------------------------
__global__ __launch_bounds__(256) void k_binA(const int* __restrict__ src,
                                              const int* __restrict__ dst,
                                              int* __restrict__ blkCntD,
                                              int* __restrict__ blkCntS) {
    __shared__ int hd[NBUCK], hs[NBUCK];
    int t = threadIdx.x;
    for (int i = t; i < NBUCK; i += 256) { hd[i] = 0; hs[i] = 0; }
    __syncthreads();
    int base = blockIdx.x * EPB;
    const int4* s4 = (const int4*)(src + base);
    const int4* d4 = (const int4*)(dst + base);
    for (int v = t; v < EPB / 4; v += 256) {
        int4 d = d4[v];
        int4 s = s4[v];
        atomicAdd(&hd[d.x >> 8], 1);
        atomicAdd(&hd[d.y >> 8], 1);
        atomicAdd(&hd[d.z >> 8], 1);
        atomicAdd(&hd[d.w >> 8], 1);
        atomicAdd(&hs[s.x >> 8], 1);
        atomicAdd(&hs[s.y >> 8], 1);
        atomicAdd(&hs[s.z >> 8], 1);
        atomicAdd(&hs[s.w >> 8], 1);
    }
    __syncthreads();
    for (int i = t; i < NBUCK; i += 256) {
        blkCntD[(size_t)blockIdx.x * NBUCK + i] = hd[i];
        blkCntS[(size_t)blockIdx.x * NBUCK + i] = hs[i];
    }
}

// Per-bucket exclusive scan over NBB block counts -> blkRel[block][buck],
// plus bucket totals. (launched once for D, once for S)
__global__ __launch_bounds__(512) void k_bbase(const int* __restrict__ blkCnt,
                                               int* __restrict__ blkRel,
                                               int* __restrict__ bucketTot) {
    __shared__ int sc[NBB];
    int b = blockIdx.x, t = threadIdx.x;
    int v0 = blkCnt[(size_t)t * NBUCK + b];
    int v1 = blkCnt[(size_t)(t + 512) * NBUCK + b];
    sc[t] = v0; sc[t + 512] = v1;
    __syncthreads();
    for (int o = 1; o < NBB; o <<= 1) {
        int x0 = (t >= o) ? sc[t - o] : 0;
        int x1 = (t + 512 >= o) ? sc[t + 512 - o] : 0;
        __syncthreads();
        sc[t] += x0; sc[t + 512] += x1;
        __syncthreads();
    }
    blkRel[(size_t)t * NBUCK + b] = sc[t] - v0;
    blkRel[(size_t)(t + 512) * NBUCK + b] = sc[t + 512] - v1;
    if (t == 511) bucketTot[b] = sc[NBB - 1];
}

// Serial scans of 400 bucket totals -> bucket bases (D and S), rowp tail.
__global__ void k_bscan(const int* __restrict__ bucketTotD,
                        const int* __restrict__ bucketTotS,
                        int* __restrict__ binBaseD,
                        int* __restrict__ binBaseS,
                        int* __restrict__ rowp) {
    int t = threadIdx.x;
    if (t == 0) {
        int run = 0;
        for (int i = 0; i < NBUCK; i++) { binBaseD[i] = run; run += bucketTotD[i]; }
        binBaseD[NBUCK] = run;
        rowp[N_NODES] = run;
    } else if (t == 64) {
        int run = 0;
        for (int i = 0; i < NBUCK; i++) { binBaseS[i] = run; run += bucketTotS[i]; }
        binBaseS[NBUCK] = run;
    }
}

// ---------------------------------------------------------------------------
// Pass B fused: BOTH deterministic counting sorts (dst-keyed -> edsD and
// src-keyed -> edsS) in one pass over src/dst/attr. EPB=3200 -> 70.4 KB LDS
// -> 2 blocks/CU (16 waves) for latency hiding of the LDS-atomic scatter.
// edsD: x = (src<<8)|dstLow, y = attr bits.  edsS: x = srcLow, y = attr.
// ---------------------------------------------------------------------------
__global__ __launch_bounds__(512) void k_binB2(const int* __restrict__ src,
                                               const int* __restrict__ dst,
                                               const float* __restrict__ attr,
                                               const int* __restrict__ blkCntD,
                                               const int* __restrict__ blkCntS,
                                               const int* __restrict__ blkRelD,
                                               const int* __restrict__ blkRelS,
                                               const int* __restrict__ binBaseD,
                                               const int* __restrict__ binBaseS,
                                               int2* __restrict__ edsD,
                                               int2* __restrict__ edsS) {
    __shared__ int sxD[EPB];        // D payload x (also D scan scratch)
    __shared__ int syD[EPB];        // D payload y
    __shared__ ushortT spD[EPB];    // D bucket id per slot
    __shared__ int sxS[EPB];        // S payload x (also S scan scratch)
    __shared__ int syS[EPB];        // S payload y
    __shared__ ushortT spS[EPB];    // S bucket id per slot
    __shared__ int lcurD[NBUCK], deltaD[NBUCK];
    __shared__ int lcurS[NBUCK], deltaS[NBUCK];
    int bx = blockIdx.x, t = threadIdx.x;

    // local exclusive scans of this block's 400 bucket counts (512-wide)
    int vD = (t < NBUCK) ? blkCntD[(size_t)bx * NBUCK + t] : 0;
    int vS = (t < NBUCK) ? blkCntS[(size_t)bx * NBUCK + t] : 0;
    sxD[t] = vD; sxS[t] = vS;
    __syncthreads();
    for (int o = 1; o < 512; o <<= 1) {
        int xD = (t >= o) ? sxD[t - o] : 0;
        int xS = (t >= o) ? sxS[t - o] : 0;
        __syncthreads();
        sxD[t] += xD; sxS[t] += xS;
        __syncthreads();
    }
    if (t < NBUCK) {
        int eD = sxD[t] - vD;
        lcurD[t] = eD;
        deltaD[t] = binBaseD[t] + blkRelD[(size_t)bx * NBUCK + t] - eD;
        int eS = sxS[t] - vS;
        lcurS[t] = eS;
        deltaS[t] = binBaseS[t] + blkRelS[(size_t)bx * NBUCK + t] - eS;
    }
    __syncthreads();

    int base = bx * EPB;
    for (int v = t; v < EPB / 2; v += 512) {
        int e0 = base + v * 2;
        int2 s2 = *(const int2*)(src + e0);
        int2 d2 = *(const int2*)(dst + e0);
        float2 a2 = *(const float2*)(attr + e0);
        int bkt, lp;
        // edge 0
        bkt = d2.x >> 8;
        lp = atomicAdd(&lcurD[bkt], 1);
        spD[lp] = (ushortT)bkt; sxD[lp] = (s2.x << 8) | (d2.x & 255);
        syD[lp] = __float_as_int(a2.x);
        bkt = s2.x >> 8;
        lp = atomicAdd(&lcurS[bkt], 1);
        spS[lp] = (ushortT)bkt; sxS[lp] = s2.x & 255;
        syS[lp] = __float_as_int(a2.x);
        // edge 1
        bkt = d2.y >> 8;
        lp = atomicAdd(&lcurD[bkt], 1);
        spD[lp] = (ushortT)bkt; sxD[lp] = (s2.y << 8) | (d2.y & 255);
        syD[lp] = __float_as_int(a2.y);
        bkt = s2.y >> 8;
        lp = atomicAdd(&lcurS[bkt], 1);
        spS[lp] = (ushortT)bkt; sxS[lp] = s2.y & 255;
        syS[lp] = __float_as_int(a2.y);
    }
    __syncthreads();
    // flush: slots sorted by bucket -> near-contiguous global stores
    for (int i = t; i < EPB; i += 512) {
        edsD[i + deltaD[spD[i]]] = make_int2(sxD[i], syD[i]);
        edsS[i + deltaS[spS[i]]] = make_int2(sxS[i], syS[i]);
    }
}

// Per-bucket weighted degree via LDS float accumulation -> dinv directly.
__global__ __launch_bounds__(256) void k_deg(const int2* __restrict__ edsS,
                                             const int* __restrict__ binBaseS,
                                             float* __restrict__ dinv) {
    __shared__ float degL[256];
    int b = blockIdx.x, t = threadIdx.x;
    degL[t] = 0.f;
    __syncthreads();
    int s0 = binBaseS[b], s1 = binBaseS[b + 1];
    for (int i = s0 + t; i < s1; i += 256) {
        int2 e = edsS[i];
        atomicAdd(&degL[e.x], __int_as_float(e.y));
    }
    __syncthreads();
    float d = degL[t];
    dinv[b * 256 + t] = d > 0.f ? rsqrtf(d) : 0.f;
}

// ---------------------------------------------------------------------------
// Per-bucket exact CSR, LDS-staged. cedge = -attr * dinv[src] * dinv[dst].
// Counting-sort key (dstLow, src>>13): rows come out src-banded.
// ---------------------------------------------------------------------------
__global__ __launch_bounds__(512) void k_csr(const int2* __restrict__ edsD,
                                             const int* __restrict__ binBaseD,
                                             const float* __restrict__ dinvG,
                                             int* __restrict__ rowp,
                                             int2* __restrict__ cedge) {
    __shared__ int cnt2[256 * 16];   // (dstLow, src>>13) counters -> cursors
    __shared__ int cntL[256];        // per-row totals -> prefix
    __shared__ float dL[256];
    __shared__ int2 st[MAXB];
    int b = blockIdx.x, t = threadIdx.x;
    for (int i = t; i < 256 * 16; i += 512) cnt2[i] = 0;
    if (t < 256) dL[t] = dinvG[b * 256 + t];
    __syncthreads();
    int s0 = binBaseD[b], s1 = binBaseD[b + 1];
    for (int i = s0 + t; i < s1; i += 512) {
        int2 e = edsD[i];
        atomicAdd(&cnt2[(e.x & 255) * 16 + ((e.x >> 8) >> 13)], 1);
    }
    __syncthreads();
    // per-row totals + in-place exclusive scan over the 16 src bands
    if (t < 256) {
        int run = 0;
#pragma unroll
        for (int o = 0; o < 16; o++) {
            int c = cnt2[t * 16 + o];
            cnt2[t * 16 + o] = run;
            run += c;
        }
        cntL[t] = run;
    }
    __syncthreads();
    int v = (t < 256) ? cntL[t] : 0;
    for (int o = 1; o < 256; o <<= 1) {
        int x = (t < 256 && t >= o) ? cntL[t - o] : 0;
        __syncthreads();
        if (t < 256) cntL[t] += x;
        __syncthreads();
    }
    if (t < 256) {
        int excl = cntL[t] - v;
        rowp[b * 256 + t] = s0 + excl;
        // make band cursors absolute within the staging buffer
#pragma unroll
        for (int o = 0; o < 16; o++) cnt2[t * 16 + o] += excl;
    }
    __syncthreads();
    for (int i = s0 + t; i < s1; i += 512) {
        int2 e = edsD[i];
        int dl = e.x & 255;
        int sg = e.x >> 8;
        float w = -__int_as_float(e.y) * dinvG[sg] * dL[dl];
        int p = atomicAdd(&cnt2[dl * 16 + (sg >> 13)], 1);
        st[p] = make_int2(sg, __float_as_int(w));
    }
    __syncthreads();
    int n = s1 - s0;
    for (int i = t; i < n; i += 512) cedge[s0 + i] = st[i];
}

// ---------------------------------------------------------------------------
// x -> slot-major bf16 hi/lo tables: Xhi/Xlo[s][n][64], s = k>>6
// ---------------------------------------------------------------------------
__global__ __launch_bounds__(256) void k_cast(const float* __restrict__ x,
                                              ushortT* __restrict__ Xhi,
                                              ushortT* __restrict__ Xlo) {
    int i = blockIdx.x * 256 + threadIdx.x;   // [0, N*32)
    int n = i >> 5;
    int kq = (i & 31) * 4;
    float4 v = ((const float4*)x)[i];
    int s = kq >> 6, kk = kq & 63;
    size_t o = (size_t)s * N64 + (size_t)n * 64 + kk;
    ushort4 h, l;
    h.x = f2b(v.x); l.x = f2b(v.x - b2f(h.x));
    h.y = f2b(v.y); l.y = f2b(v.y - b2f(h.y));
    h.z = f2b(v.z); l.z = f2b(v.z - b2f(h.z));
    h.w = f2b(v.w); l.w = f2b(v.w - b2f(h.w));
    *(ushort4*)(Xhi + o) = h;
    *(ushort4*)(Xlo + o) = l;
}

// ---------------------------------------------------------------------------
// Weight prep: transposed [N][K] bf16 hi/lo tables.
// ---------------------------------------------------------------------------
template <int L>
__global__ void k_wprep(const float* __restrict__ w, ushortT* __restrict__ Wth,
                        ushortT* __restrict__ Wtl) {
    int i = blockIdx.x * 256 + threadIdx.x;
    float v;
    if (L == 1) {
        if (i >= 192 * 128) return;
        int n = i / 128, k = i % 128;
        if (n < 64)       v = w[k * 64 + n] - w[16384 + k * 64 + n];
        else if (n < 128) v = w[8192 + k * 64 + (n - 64)];
        else              v = w[16384 + k * 64 + (n - 128)];
    } else if (L == 2) {
        if (i >= 192 * 64) return;
        int n = i / 64, k = i % 64;
        if (n < 64)       v = w[k * 64 + n] - w[8192 + k * 64 + n];
        else if (n < 128) v = w[4096 + k * 64 + (n - 64)];
        else              v = w[8192 + k * 64 + (n - 128)];
    } else {
        if (i >= 128 * 192) return;
        int n = i / 192, k = i % 192;
        v = w[(k >> 6) * 8192 + (k & 63) * 128 + n];
    }
    ushortT h = f2b(v);
    Wth[i] = h;
    Wtl[i] = f2b(v - b2f(h));
}

// ---------------------------------------------------------------------------
// MFMA GEMM v3: one block = 256 rows x ALL NTOT cols. W (hi+lo) staged in
// LDS in 64-wide K-chunks (pad stride 72). 8 waves x (32 rows x NTOT cols).
// acc = Ahi*Whi + Alo*Whi + Ahi*Wlo  (~fp32 accuracy).
// MODE 0: ct<8 -> fp32 out[n*128 + ct*16+m]; ct>=8 -> bf16 outb[n*64 + ...]
// MODE 1: relu(acc+bias) staged in LDS tile, pooled in-kernel (run-length
//         over sorted batch ids) -> atomicAdd into pooled/gcnt. No H3.
// ---------------------------------------------------------------------------
template <int KTOT, int NTOT, int MODE>
__global__ __launch_bounds__(512) void k_mgemm(
    const ushortT* __restrict__ Ah0, const ushortT* __restrict__ Ah1,
    const ushortT* __restrict__ Ah2, const ushortT* __restrict__ Al0,
    const ushortT* __restrict__ Al1, const ushortT* __restrict__ Al2,
    const ushortT* __restrict__ Wth, const ushortT* __restrict__ Wtl,
    const float* __restrict__ bias, float* __restrict__ outf,
    ushortT* __restrict__ outb, const int* __restrict__ batch,
    float* __restrict__ pooled, float* __restrict__ gcnt) {
    constexpr int KPAD = 72;          // 64-chunk + 8 shorts pad
    constexpr int NCT = NTOT / 16;
    constexpr int SMEM_STAGE = 2 * NTOT * KPAD * 2;
    constexpr int SMEM_POOL = (MODE == 1) ? (256 * 128 * 4 + 256 * 4) : 0;
    constexpr int SMEM_BYTES = SMEM_STAGE > SMEM_POOL ? SMEM_STAGE : SMEM_POOL;
    __shared__ __align__(16) char smem[SMEM_BYTES];
    ushortT* Bh = (ushortT*)smem;
    ushortT* Bl = Bh + NTOT * KPAD;
    const ushortT* Ah[3] = {Ah0, Ah1, Ah2};
    const ushortT* Al[3] = {Al0, Al1, Al2};
    int t = threadIdx.x;
    int lane = t & 63;
    int wv = t >> 6;                  // 8 waves
    int m = lane & 15, q = lane >> 4;
    int r0 = blockIdx.x * 256 + wv * 32;
    int ar0 = r0 + m;                 // row frag 0
    int ar1 = r0 + 16 + m;            // row frag 1

    f32x4 acc[2][NCT];
#pragma unroll
    for (int rf = 0; rf < 2; rf++)
#pragma unroll
        for (int ct = 0; ct < NCT; ct++)
#pragma unroll
            for (int j = 0; j < 4; j++) acc[rf][ct][j] = 0.f;

#pragma unroll
    for (int kc = 0; kc < KTOT / 64; kc++) {
        __syncthreads();
        // stage W[*, kc*64 .. kc*64+64) hi+lo into LDS (uint4 = 8 shorts)
        for (int i = t; i < NTOT * 8; i += 512) {
            int col = i >> 3, k = (i & 7) * 8;
            *(uint4*)(Bh + col * KPAD + k) =
                *(const uint4*)(Wth + (size_t)col * KTOT + kc * 64 + k);
            *(uint4*)(Bl + col * KPAD + k) =
                *(const uint4*)(Wtl + (size_t)col * KTOT + kc * 64 + k);
        }
        __syncthreads();
        const ushortT* Ahc = Ah[kc];
        const ushortT* Alc = Al[kc];
#pragma unroll
        for (int ks2 = 0; ks2 < 2; ks2++) {
            int kk = ks2 * 32 + q * 8;
            bf16x8 ah0 = *(const bf16x8*)(Ahc + (size_t)ar0 * 64 + kk);
            bf16x8 al0 = *(const bf16x8*)(Alc + (size_t)ar0 * 64 + kk);
            bf16x8 ah1 = *(const bf16x8*)(Ahc + (size_t)ar1 * 64 + kk);
            bf16x8 al1 = *(const bf16x8*)(Alc + (size_t)ar1 * 64 + kk);
#pragma unroll
            for (int ct = 0; ct < NCT; ct++) {
                int bo = (ct * 16 + m) * KPAD + ks2 * 32 + q * 8;
                bf16x8 bh = *(const bf16x8*)(Bh + bo);
                bf16x8 bl = *(const bf16x8*)(Bl + bo);
                acc[0][ct] = __builtin_amdgcn_mfma_f32_16x16x32_bf16(ah0, bh, acc[0][ct], 0, 0, 0);
                acc[0][ct] = __builtin_amdgcn_mfma_f32_16x16x32_bf16(al0, bh, acc[0][ct], 0, 0, 0);
                acc[0][ct] = __builtin_amdgcn_mfma_f32_16x16x32_bf16(ah0, bl, acc[0][ct], 0, 0, 0);
                acc[1][ct] = __builtin_amdgcn_mfma_f32_16x16x32_bf16(ah1, bh, acc[1][ct], 0, 0, 0);
                acc[1][ct] = __builtin_amdgcn_mfma_f32_16x16x32_bf16(al1, bh, acc[1][ct], 0, 0, 0);
                acc[1][ct] = __builtin_amdgcn_mfma_f32_16x16x32_bf16(ah1, bl, acc[1][ct], 0, 0, 0);
            }
        }
    }

    if (MODE == 0) {
#pragma unroll
        for (int rf = 0; rf < 2; rf++)
#pragma unroll
            for (int ct = 0; ct < NCT; ct++)
#pragma unroll
                for (int rg = 0; rg < 4; rg++) {
                    int row = r0 + rf * 16 + q * 4 + rg;
                    float v = acc[rf][ct][rg];
                    if (ct < 8)
                        outf[(size_t)row * 128 + ct * 16 + m] = v;
                    else
                        outb[(size_t)row * 64 + (ct - 8) * 16 + m] = f2b(v);
                }
    } else {
        // ---- fused global_mean_pool: stage relu tile in LDS, run-length sum
        float* poolB = (float*)smem;                      // [256][128] f32
        int* batchL = (int*)(smem + 256 * 128 * 4);       // 256 ids
        __syncthreads();  // all waves done reading Bh/Bl
        for (int i = t; i < 256; i += 512)
            batchL[i] = batch[blockIdx.x * 256 + i];
#pragma unroll
        for (int rf = 0; rf < 2; rf++)
#pragma unroll
            for (int ct = 0; ct < NCT; ct++)
#pragma unroll
                for (int rg = 0; rg < 4; rg++) {
                    int rl = wv * 32 + rf * 16 + q * 4 + rg;
                    int col = ct * 16 + m;
                    poolB[rl * 128 + col] = fmaxf(acc[rf][ct][rg] + bias[col], 0.f);
                }
        __syncthreads();
        int col = t & 127, seg = t >> 7;   // 4 segments x 64 rows
        int base = seg * 64;
        int g = batchL[base];
        float a = 0.f;
        int c = 0;
        for (int k = 0; k < 64; k++) {
            int gn = batchL[base + k];
            if (gn != g) {
                atomicAdd(&pooled[(size_t)g * 128 + col], a);
                if (col == 0) atomicAdd(&gcnt[g], (float)c);
                g = gn; a = 0.f; c = 0;
            }
            a += poolB[(base + k) * 128 + col];
            c++;
        }
        atomicAdd(&pooled[(size_t)g * 128 + col], a);
        if (col == 0) atomicAdd(&gcnt[g], (float)c);
    }
}

// ---------------------------------------------------------------------------
// SpMM v3: 8 lanes per edge-row, each lane gathers uint4 = 8 bf16 features
// (16 B/lane coalescing sweet spot; one gather inst covers 8 edges, 1024 B).
// 16 edges per iteration via 2 slots -> 2 gather + 2 cedge insts per iter.
// q = lane>>3 edge slot in group of 8; f = (lane&7)*8 feature base.
// Cross-group shfl_xor(8,16,32) reduce; groups 0/1 write Yh/Yl.
// MODE 0: r = acc          MODE 1: r = aux + 2*acc
// MODE 2: r = 2*acc - aux  MODE 3: r = relu(aux + acc + bias)
// ---------------------------------------------------------------------------
template <int MODE, int SA, bool AUXB, bool WLO>
__global__ __launch_bounds__(256) void k_spmm(const int* __restrict__ rowp,
                                              const int2* __restrict__ cedge,
                                              const ushortT* __restrict__ Xb,
                                              const float* __restrict__ auxF,
                                              const ushortT* __restrict__ auxH,
                                              const ushortT* __restrict__ auxL,
                                              const float* __restrict__ bias,
                                              ushortT* __restrict__ Yh,
                                              ushortT* __restrict__ Yl) {
    int node = blockIdx.x * 4 + (threadIdx.x >> 6);
    int lane = threadIdx.x & 63;
    int q = lane >> 3;          // edge slot within group of 8
    int f = (lane & 7) * 8;     // feature base (8 features/lane)
    int s = rowp[node], e = rowp[node + 1];
    const ushortT* Xf = Xb + f;
    float a0 = 0.f, a1 = 0.f, a2 = 0.f, a3 = 0.f;
    float a4 = 0.f, a5 = 0.f, a6 = 0.f, a7 = 0.f;
    for (int i = s; i < e; i += 16) {
        int i0 = min(i + q, e - 1);
        int i1 = min(i + 8 + q, e - 1);
        int2 ed0 = cedge[i0];
        int2 ed1 = cedge[i1];
        float w0 = (i + q < e) ? __int_as_float(ed0.y) : 0.f;
        float w1 = (i + 8 + q < e) ? __int_as_float(ed1.y) : 0.f;
        uint4 u0 = *(const uint4*)(Xf + ((size_t)ed0.x << 6));
        uint4 u1 = *(const uint4*)(Xf + ((size_t)ed1.x << 6));
        a0 = fmaf(w0, loF(u0.x), a0);
        a1 = fmaf(w0, hiF(u0.x), a1);
        a2 = fmaf(w0, loF(u0.y), a2);
        a3 = fmaf(w0, hiF(u0.y), a3);
        a4 = fmaf(w0, loF(u0.z), a4);
        a5 = fmaf(w0, hiF(u0.z), a5);
        a6 = fmaf(w0, loF(u0.w), a6);
        a7 = fmaf(w0, hiF(u0.w), a7);
        a0 = fmaf(w1, loF(u1.x), a0);
        a1 = fmaf(w1, hiF(u1.x), a1);
        a2 = fmaf(w1, loF(u1.y), a2);
        a3 = fmaf(w1, hiF(u1.y), a3);
        a4 = fmaf(w1, loF(u1.z), a4);
        a5 = fmaf(w1, hiF(u1.z), a5);
        a6 = fmaf(w1, loF(u1.w), a6);
        a7 = fmaf(w1, hiF(u1.w), a7);
    }
    // reduce across the 8 groups (xor lane bits 3, 4, 5)
    a0 += __shfl_xor(a0, 8); a0 += __shfl_xor(a0, 16); a0 += __shfl_xor(a0, 32);
    a1 += __shfl_xor(a1, 8); a1 += __shfl_xor(a1, 16); a1 += __shfl_xor(a1, 32);
    a2 += __shfl_xor(a2, 8); a2 += __shfl_xor(a2, 16); a2 += __shfl_xor(a2, 32);
    a3 += __shfl_xor(a3, 8); a3 += __shfl_xor(a3, 16); a3 += __shfl_xor(a3, 32);
    a4 += __shfl_xor(a4, 8); a4 += __shfl_xor(a4, 16); a4 += __shfl_xor(a4, 32);
    a5 += __shfl_xor(a5, 8); a5 += __shfl_xor(a5, 16); a5 += __shfl_xor(a5, 32);
    a6 += __shfl_xor(a6, 8); a6 += __shfl_xor(a6, 16); a6 += __shfl_xor(a6, 32);
    a7 += __shfl_xor(a7, 8); a7 += __shfl_xor(a7, 16); a7 += __shfl_xor(a7, 32);

    if (q == 0 || (WLO && q == 1)) {
        float x0 = 0.f, x1 = 0.f, x2 = 0.f, x3 = 0.f;
        float x4 = 0.f, x5 = 0.f, x6 = 0.f, x7 = 0.f;
        if (MODE != 0) {
            if (AUXB) {
                uint4 ha = *(const uint4*)(auxH + (size_t)node * 64 + f);
                uint4 la = *(const uint4*)(auxL + (size_t)node * 64 + f);
                x0 = loF(ha.x) + loF(la.x);
                x1 = hiF(ha.x) + hiF(la.x);
                x2 = loF(ha.y) + loF(la.y);
                x3 = hiF(ha.y) + hiF(la.y);
                x4 = loF(ha.z) + loF(la.z);
                x5 = hiF(ha.z) + hiF(la.z);
                x6 = loF(ha.w) + loF(la.w);
                x7 = hiF(ha.w) + hiF(la.w);
            } else {
                float4 av0 = *(const float4*)(auxF + (size_t)node * SA + f);
                float4 av1 = *(const float4*)(auxF + (size_t)node * SA + f + 4);
                x0 = av0.x; x1 = av0.y; x2 = av0.z; x3 = av0.w;
                x4 = av1.x; x5 = av1.y; x6 = av1.z; x7 = av1.w;
            }
        }
        float r0, r1, r2, r3, r4, r5, r6, r7;
        if (MODE == 0) {
            r0 = a0; r1 = a1; r2 = a2; r3 = a3;
            r4 = a4; r5 = a5; r6 = a6; r7 = a7;
        } else if (MODE == 1) {
            r0 = x0 + 2.f * a0; r1 = x1 + 2.f * a1;
            r2 = x2 + 2.f * a2; r3 = x3 + 2.f * a3;
            r4 = x4 + 2.f * a4; r5 = x5 + 2.f * a5;
            r6 = x6 + 2.f * a6; r7 = x7 + 2.f * a7;
        } else if (MODE == 2) {
            r0 = 2.f * a0 - x0; r1 = 2.f * a1 - x1;
            r2 = 2.f * a2 - x2; r3 = 2.f * a3 - x3;
            r4 = 2.f * a4 - x4; r5 = 2.f * a5 - x5;
            r6 = 2.f * a6 - x6; r7 = 2.f * a7 - x7;
        } else {
            float4 bv0 = *(const float4*)(bias + f);
            float4 bv1 = *(const float4*)(bias + f + 4);
            r0 = fmaxf(x0 + a0 + bv0.x, 0.f);
            r1 = fmaxf(x1 + a1 + bv0.y, 0.f);
            r2 = fmaxf(x2 + a2 + bv0.z, 0.f);
            r3 = fmaxf(x3 + a3 + bv0.w, 0.f);
            r4 = fmaxf(x4 + a4 + bv1.x, 0.f);
            r5 = fmaxf(x5 + a5 + bv1.y, 0.f);
            r6 = fmaxf(x6 + a6 + bv1.z, 0.f);
            r7 = fmaxf(x7 + a7 + bv1.w, 0.f);
        }
        ushortT h0 = f2b(r0), h1 = f2b(r1), h2 = f2b(r2), h3 = f2b(r3);
        ushortT h4 = f2b(r4), h5 = f2b(r5), h6 = f2b(r6), h7 = f2b(r7);
        if (q == 0) {
            uint4 pk;
            pk.x = (uintT)h0 | ((uintT)h1 << 16);
            pk.y = (uintT)h2 | ((uintT)h3 << 16);
            pk.z = (uintT)h4 | ((uintT)h5 << 16);
            pk.w = (uintT)h6 | ((uintT)h7 << 16);
            *(uint4*)(Yh + (size_t)node * 64 + f) = pk;
        } else {
            uint4 pk;
            pk.x = (uintT)f2b(r0 - b2f(h0)) | ((uintT)f2b(r1 - b2f(h1)) << 16);
            pk.y = (uintT)f2b(r2 - b2f(h2)) | ((uintT)f2b(r3 - b2f(h3)) << 16);
            pk.z = (uintT)f2b(r4 - b2f(h4)) | ((uintT)f2b(r5 - b2f(h5)) << 16);
            pk.w = (uintT)f2b(r6 - b2f(h6)) | ((uintT)f2b(r7 - b2f(h7)) << 16);
            *(uint4*)(Yl + (size_t)node * 64 + f) = pk;
        }
    }
}

__global__ void k_final(const float* __restrict__ pooled, const float* __restrict__ gcnt,
                        const float* __restrict__ lin_w, const float* __restrict__ lin_b,
                        float* __restrict__ out) {
    int g = blockIdx.x * 4 + (threadIdx.x >> 6);
    int lane = threadIdx.x & 63;
    if (g >= N_GRAPHS) return;
    float inv = 1.f / fmaxf(gcnt[g], 1.f);
    float v0 = pooled[(size_t)g * 128 + lane] * inv;
    float v1 = pooled[(size_t)g * 128 + 64 + lane] * inv;
    float p0 = v0 * lin_w[lane * 2 + 0] + v1 * lin_w[(lane + 64) * 2 + 0];
    float p1 = v0 * lin_w[lane * 2 + 1] + v1 * lin_w[(lane + 64) * 2 + 1];
    for (int o = 32; o > 0; o >>= 1) {
        p0 += __shfl_down(p0, o);
        p1 += __shfl_down(p1, o);
    }
    if (lane == 0) {
        out[g * 2 + 0] = p0 + lin_b[0];
        out[g * 2 + 1] = p1 + lin_b[1];
    }
}

// ---------------------------------------------------------------------------
extern "C" void kernel_launch(void* const* d_in, const int* in_sizes, int n_in,
                              void* d_out, int out_size, void* d_ws, size_t ws_size,
                              hipStream_t stream) {
    const float* x     = (const float*)d_in[0];
    const int*   src   = (const int*)d_in[1];
    const int*   dst   = src + N_EDGES;
    const float* eattr = (const float*)d_in[2];
    const int*   batch = (const int*)d_in[3];
    const float* w1    = (const float*)d_in[4];
    const float* b1    = (const float*)d_in[5];
    const float* w2    = (const float*)d_in[6];
    const float* b2    = (const float*)d_in[7];
    const float* w3    = (const float*)d_in[8];
    const float* b3    = (const float*)d_in[9];
    const float* lin_w = (const float*)d_in[10];
    const float* lin_b = (const float*)d_in[11];
    float* out = (float*)d_out;

    char* ws = (char*)d_ws;
    size_t off = 0;
    auto alloc = [&](size_t bytes) -> char* {
        char* p = ws + off;
        off += (bytes + 255) & ~(size_t)255;
        return p;
    };
    int*   blkCntD   = (int*)  alloc((size_t)NBB * NBUCK * 4);   // 1.6 MB
    int*   blkCntS   = (int*)  alloc((size_t)NBB * NBUCK * 4);
    int*   blkRelD   = (int*)  alloc((size_t)NBB * NBUCK * 4);
    int*   blkRelS   = (int*)  alloc((size_t)NBB * NBUCK * 4);
    int*   bucketTotD = (int*) alloc(NBUCK * 4);
    int*   bucketTotS = (int*) alloc(NBUCK * 4);
    int*   binBaseD  = (int*)  alloc((NBUCK + 1) * 4);
    int*   binBaseS  = (int*)  alloc((NBUCK + 1) * 4);
    float* dinv      = (float*)alloc((size_t)N_NODES * 4);
    int*   rowp      = (int*)  alloc((size_t)(N_NODES + 1) * 4);
    ushortT* Wt1h   = (ushortT*)alloc(192 * 128 * 2);
    ushortT* Wt1l   = (ushortT*)alloc(192 * 128 * 2);
    ushortT* Wt2h   = (ushortT*)alloc(192 * 64 * 2);
    ushortT* Wt2l   = (ushortT*)alloc(192 * 64 * 2);
    ushortT* Wt3h   = (ushortT*)alloc(128 * 192 * 2);
    ushortT* Wt3l   = (ushortT*)alloc(128 * 192 * 2);
    float* pooled   = (float*)alloc((size_t)(N_GRAPHS * 128 + N_GRAPHS) * 4);
    float* gcnt     = pooled + (size_t)N_GRAPHS * 128;
    int2*  cedge    = (int2*) alloc((size_t)N_EDGES * 8);      // 26.2 MB
    char*  Buf1     = alloc((size_t)N_EDGES * 16);             // 52.4 MB
    char*  Buf2     = alloc((size_t)N_NODES * 128 * 4);        // 52.4 MB
    char*  Buf3     = alloc(4 * N64 * 2);                      // 52.4 MB

    // Buf1: edsD|edsS (build)  ->  Xhi/Xlo [2][N][64]  ->  GThi [3][N][64]
    int2* edsD = (int2*)Buf1;
    int2* edsS = edsD + N_EDGES;
    ushortT* Xhi  = (ushortT*)Buf1;
    ushortT* Xlo  = Xhi + 2 * N64;
    ushortT* GThi = (ushortT*)Buf1;          // slots 0,1,2 contiguous
    // Buf2: P fp32 [N][128] (P0c | P1)
    float* P  = (float*)Buf2;
    // Buf3: G0 | Qhi | H1hi | H1lo ; GTlo slots alias regions 0,2,3
    ushortT* G0    = (ushortT*)Buf3;
    ushortT* Qhi   = G0 + N64;
    ushortT* H1hi  = G0 + 2 * N64;
    ushortT* H1lo  = G0 + 3 * N64;
    ushortT* GTlo0 = G0;      // written after G0's last read
    ushortT* GTlo1 = H1hi;    // written after H1hi's last read
    ushortT* GTlo2 = H1lo;    // written after H1lo's last read

    hipMemsetAsync(pooled, 0, (size_t)(N_GRAPHS * 128 + N_GRAPHS) * 4, stream);

    // ---- CSR build: deterministic counting sorts, zero global atomics.
    k_binA<<<NBB, 256, 0, stream>>>(src, dst, blkCntD, blkCntS);
    k_bbase<<<NBUCK, 512, 0, stream>>>(blkCntD, blkRelD, bucketTotD);
    k_bbase<<<NBUCK, 512, 0, stream>>>(blkCntS, blkRelS, bucketTotS);
    k_bscan<<<1, 128, 0, stream>>>(bucketTotD, bucketTotS, binBaseD, binBaseS, rowp);
    k_binB2<<<NBB, 512, 0, stream>>>(src, dst, eattr, blkCntD, blkCntS,
                                     blkRelD, blkRelS, binBaseD, binBaseS,
                                     edsD, edsS);
    k_deg<<<NBUCK, 256, 0, stream>>>(edsS, binBaseS, dinv);
    k_csr<<<NBUCK, 512, 0, stream>>>(edsD, binBaseD, dinv, rowp, cedge);

    // ---- Prep: x cast (after edsD/edsS consumed), weight transpose+split
    k_cast<<<N_NODES * 32 / 256, 256, 0, stream>>>(x, Xhi, Xlo);
    k_wprep<1><<<96, 256, 0, stream>>>(w1, Wt1h, Wt1l);
    k_wprep<2><<<48, 256, 0, stream>>>(w2, Wt2h, Wt2l);
    k_wprep<3><<<96, 256, 0, stream>>>(w3, Wt3h, Wt3l);

    // ---- Layer 1 (128 -> 64): P0c,P1 fp32 + P2 bf16 table (G0)
    k_mgemm<128, 192, 0><<<N_NODES / 256, 512, 0, stream>>>(
        Xhi, Xhi + N64, nullptr, Xlo, Xlo + N64, nullptr, Wt1h, Wt1l, nullptr,
        P, G0, nullptr, nullptr, nullptr);
    // Q = P1 + 2*L*P2 -> Qhi
    k_spmm<1, 128, false, false><<<N_NODES / 4, 256, 0, stream>>>(
        rowp, cedge, G0, P + 64, nullptr, nullptr, nullptr, Qhi, nullptr);
    // H1 = relu(P0c + L*Q + b1) -> H1hi/H1lo
    k_spmm<3, 128, false, true><<<N_NODES / 4, 256, 0, stream>>>(
        rowp, cedge, Qhi, P, nullptr, nullptr, b1, H1hi, H1lo);

    // ---- Layer 2 (64 -> 64)
    k_mgemm<64, 192, 0><<<N_NODES / 256, 512, 0, stream>>>(
        H1hi, nullptr, nullptr, H1lo, nullptr, nullptr, Wt2h, Wt2l, nullptr,
        P, G0, nullptr, nullptr, nullptr);
    k_spmm<1, 128, false, false><<<N_NODES / 4, 256, 0, stream>>>(
        rowp, cedge, G0, P + 64, nullptr, nullptr, nullptr, Qhi, nullptr);
    // T0 = relu(P0c + L*Q + b2) -> GThi[0]/GTlo[0]
    k_spmm<3, 128, false, true><<<N_NODES / 4, 256, 0, stream>>>(
        rowp, cedge, Qhi, P, nullptr, nullptr, b2, GThi, GTlo0);

    // ---- Layer 3 (64 -> 128), spmm-first
    // T1 = L*T0 -> GThi[1]/GTlo[1]
    k_spmm<0, 64, false, true><<<N_NODES / 4, 256, 0, stream>>>(
        rowp, cedge, GThi, nullptr, nullptr, nullptr, nullptr, GThi + N64, GTlo1);
    // T2 = 2*L*T1 - T0 -> GThi[2]/GTlo[2]  (Aux = T0 via hi+lo)
    k_spmm<2, 64, true, true><<<N_NODES / 4, 256, 0, stream>>>(
        rowp, cedge, GThi + N64, nullptr, GThi, GTlo0, nullptr, GThi + 2 * N64, GTlo2);
    // relu([T0|T1|T2] @ w3 + b3) pooled in-kernel -> pooled/gcnt (no H3)
    k_mgemm<192, 128, 1><<<N_NODES / 256, 512, 0, stream>>>(
        GThi, GThi + N64, GThi + 2 * N64, GTlo0, GTlo1, GTlo2, Wt3h, Wt3l, b3,
        nullptr, nullptr, batch, pooled, gcnt);

    // ---- Final linear
    k_final<<<N_GRAPHS / 4, 256, 0, stream>>>(pooled, gcnt, lin_w, lin_b, out);
}

// Round 10
// 712.989 us; speedup vs baseline: 1.1185x; 1.0202x over previous
//
#include <hip/hip_runtime.h>
#include <cstddef>
#include <cstdint>

#define N_NODES 102400
#define N_EDGES 3276800
#define N_GRAPHS 1024
#define NBUCK 400            // node >> 8 -> 400 buckets of 256 nodes
#define NBB 1024             // binning blocks
#define EPB 3200             // edges per binning block (NBB*EPB == N_EDGES)
#define N64 ((size_t)N_NODES * 64)

typedef unsigned short ushortT;
typedef unsigned int uintT;
typedef __attribute__((ext_vector_type(8))) short bf16x8;
typedef __attribute__((ext_vector_type(4))) float f32x4;

__device__ __forceinline__ float b2f(ushortT h) {
    return __uint_as_float(((uintT)h) << 16);
}
__device__ __forceinline__ ushortT f2b(float f) {
    uintT u = __float_as_uint(f);
    uintT r = (u + 0x7fffu + ((u >> 16) & 1u)) >> 16;
    return (ushortT)r;
}
__device__ __forceinline__ float loF(uintT w) { return __uint_as_float(w << 16); }
__device__ __forceinline__ float hiF(uintT w) { return __uint_as_float(w & 0xffff0000u); }

// ---------------------------------------------------------------------------
// Pass A: per-block LDS histograms of dst AND src coarse buckets.
// int4 loads (4 edges/inst). Zero global atomics, zero scattered writes.
// ---------------------------------------------------------------------------
__global__ __launch_bounds__(256) void k_binA(const int* __restrict__ src,
                                              const int* __restrict__ dst,
                                              int* __restrict__ blkCntD,
                                              int* __restrict__ blkCntS) {
    __shared__ int hd[NBUCK], hs[NBUCK];
    int t = threadIdx.x;
    for (int i = t; i < NBUCK; i += 256) { hd[i] = 0; hs[i] = 0; }
    __syncthreads();
    int base = blockIdx.x * EPB;
    const int4* s4 = (const int4*)(src + base);
    const int4* d4 = (const int4*)(dst + base);
    for (int v = t; v < EPB / 4; v += 256) {
        int4 d = d4[v];
        int4 s = s4[v];
        atomicAdd(&hd[d.x >> 8], 1);
        atomicAdd(&hd[d.y >> 8], 1);
        atomicAdd(&hd[d.z >> 8], 1);
        atomicAdd(&hd[d.w >> 8], 1);
        atomicAdd(&hs[s.x >> 8], 1);
        atomicAdd(&hs[s.y >> 8], 1);
        atomicAdd(&hs[s.z >> 8], 1);
        atomicAdd(&hs[s.w >> 8], 1);
    }
    __syncthreads();
    for (int i = t; i < NBUCK; i += 256) {
        blkCntD[(size_t)blockIdx.x * NBUCK + i] = hd[i];
        blkCntS[(size_t)blockIdx.x * NBUCK + i] = hs[i];
    }
}

// ---------------------------------------------------------------------------
// Tiled transpose of blkCnt [NBB][NBUCK] -> blkCntT [NBUCK][NBB] so k_bbase
// reads coalesced rows instead of stride-1600B columns. z=0: D, z=1: S.
// ---------------------------------------------------------------------------
__global__ void k_tr(const int* __restrict__ inD, const int* __restrict__ inS,
                     int* __restrict__ outD, int* __restrict__ outS) {
    __shared__ int tile[32][33];
    const int* in = blockIdx.z ? inS : inD;
    int* out = blockIdx.z ? outS : outD;
    int x = blockIdx.x * 32 + threadIdx.x;     // bucket index
    int yb = blockIdx.y * 32;                  // block-index base
    for (int dy = threadIdx.y; dy < 32; dy += 8) {
        int y = yb + dy;
        tile[dy][threadIdx.x] = (x < NBUCK) ? in[(size_t)y * NBUCK + x] : 0;
    }
    __syncthreads();
    int xo = yb + threadIdx.x;                 // block index (NBB%32==0)
    for (int dy = threadIdx.y; dy < 32; dy += 8) {
        int bo = blockIdx.x * 32 + dy;         // bucket index
        if (bo < NBUCK) out[(size_t)bo * NBB + xo] = tile[threadIdx.x][dy];
    }
}

// Per-bucket exclusive scan over NBB block counts (transposed, coalesced
// reads) -> blkRel[block][buck], plus bucket totals.
__global__ __launch_bounds__(512) void k_bbase(const int* __restrict__ blkCntT,
                                               int* __restrict__ blkRel,
                                               int* __restrict__ bucketTot) {
    __shared__ int sc[NBB];
    int b = blockIdx.x, t = threadIdx.x;
    int v0 = blkCntT[(size_t)b * NBB + t];
    int v1 = blkCntT[(size_t)b * NBB + t + 512];
    sc[t] = v0; sc[t + 512] = v1;
    __syncthreads();
    for (int o = 1; o < NBB; o <<= 1) {
        int x0 = (t >= o) ? sc[t - o] : 0;
        int x1 = (t + 512 >= o) ? sc[t + 512 - o] : 0;
        __syncthreads();
        sc[t] += x0; sc[t + 512] += x1;
        __syncthreads();
    }
    blkRel[(size_t)t * NBUCK + b] = sc[t] - v0;
    blkRel[(size_t)(t + 512) * NBUCK + b] = sc[t + 512] - v1;
    if (t == 511) bucketTot[b] = sc[NBB - 1];
}

// Parallel scans of 400 bucket totals -> bucket bases (D and S), rowp tail.
__global__ __launch_bounds__(512) void k_bscan(const int* __restrict__ bucketTotD,
                                               const int* __restrict__ bucketTotS,
                                               int* __restrict__ binBaseD,
                                               int* __restrict__ binBaseS,
                                               int* __restrict__ rowp) {
    __shared__ int sc[512];
    int t = threadIdx.x;
    int vD = (t < NBUCK) ? bucketTotD[t] : 0;
    sc[t] = vD;
    __syncthreads();
    for (int o = 1; o < 512; o <<= 1) {
        int x = (t >= o) ? sc[t - o] : 0;
        __syncthreads();
        sc[t] += x;
        __syncthreads();
    }
    if (t < NBUCK) binBaseD[t] = sc[t] - vD;
    if (t == 511) { binBaseD[NBUCK] = sc[511]; rowp[N_NODES] = sc[511]; }
    __syncthreads();
    int vS = (t < NBUCK) ? bucketTotS[t] : 0;
    sc[t] = vS;
    __syncthreads();
    for (int o = 1; o < 512; o <<= 1) {
        int x = (t >= o) ? sc[t - o] : 0;
        __syncthreads();
        sc[t] += x;
        __syncthreads();
    }
    if (t < NBUCK) binBaseS[t] = sc[t] - vS;
    if (t == 511) binBaseS[NBUCK] = sc[511];
}

// ---------------------------------------------------------------------------
// Pass B fused: BOTH deterministic counting sorts (dst-keyed -> edsD and
// src-keyed -> edsS) in one pass over src/dst/attr. EPB=3200 -> 70.4 KB LDS
// -> 2 blocks/CU (16 waves) for latency hiding of the LDS-atomic scatter.
// edsD: x = (src<<8)|dstLow, y = attr bits.  edsS: x = srcLow, y = attr.
// ---------------------------------------------------------------------------
__global__ __launch_bounds__(512) void k_binB2(const int* __restrict__ src,
                                               const int* __restrict__ dst,
                                               const float* __restrict__ attr,
                                               const int* __restrict__ blkCntD,
                                               const int* __restrict__ blkCntS,
                                               const int* __restrict__ blkRelD,
                                               const int* __restrict__ blkRelS,
                                               const int* __restrict__ binBaseD,
                                               const int* __restrict__ binBaseS,
                                               int2* __restrict__ edsD,
                                               int2* __restrict__ edsS) {
    __shared__ int sxD[EPB];        // D payload x (also D scan scratch)
    __shared__ int syD[EPB];        // D payload y
    __shared__ ushortT spD[EPB];    // D bucket id per slot
    __shared__ int sxS[EPB];        // S payload x (also S scan scratch)
    __shared__ int syS[EPB];        // S payload y
    __shared__ ushortT spS[EPB];    // S bucket id per slot
    __shared__ int lcurD[NBUCK], deltaD[NBUCK];
    __shared__ int lcurS[NBUCK], deltaS[NBUCK];
    int bx = blockIdx.x, t = threadIdx.x;

    // local exclusive scans of this block's 400 bucket counts (512-wide)
    int vD = (t < NBUCK) ? blkCntD[(size_t)bx * NBUCK + t] : 0;
    int vS = (t < NBUCK) ? blkCntS[(size_t)bx * NBUCK + t] : 0;
    sxD[t] = vD; sxS[t] = vS;
    __syncthreads();
    for (int o = 1; o < 512; o <<= 1) {
        int xD = (t >= o) ? sxD[t - o] : 0;
        int xS = (t >= o) ? sxS[t - o] : 0;
        __syncthreads();
        sxD[t] += xD; sxS[t] += xS;
        __syncthreads();
    }
    if (t < NBUCK) {
        int eD = sxD[t] - vD;
        lcurD[t] = eD;
        deltaD[t] = binBaseD[t] + blkRelD[(size_t)bx * NBUCK + t] - eD;
        int eS = sxS[t] - vS;
        lcurS[t] = eS;
        deltaS[t] = binBaseS[t] + blkRelS[(size_t)bx * NBUCK + t] - eS;
    }
    __syncthreads();

    int base = bx * EPB;
    for (int v = t; v < EPB / 2; v += 512) {
        int e0 = base + v * 2;
        int2 s2 = *(const int2*)(src + e0);
        int2 d2 = *(const int2*)(dst + e0);
        float2 a2 = *(const float2*)(attr + e0);
        int bkt, lp;
        // edge 0
        bkt = d2.x >> 8;
        lp = atomicAdd(&lcurD[bkt], 1);
        spD[lp] = (ushortT)bkt; sxD[lp] = (s2.x << 8) | (d2.x & 255);
        syD[lp] = __float_as_int(a2.x);
        bkt = s2.x >> 8;
        lp = atomicAdd(&lcurS[bkt], 1);
        spS[lp] = (ushortT)bkt; sxS[lp] = s2.x & 255;
        syS[lp] = __float_as_int(a2.x);
        // edge 1
        bkt = d2.y >> 8;
        lp = atomicAdd(&lcurD[bkt], 1);
        spD[lp] = (ushortT)bkt; sxD[lp] = (s2.y << 8) | (d2.y & 255);
        syD[lp] = __float_as_int(a2.y);
        bkt = s2.y >> 8;
        lp = atomicAdd(&lcurS[bkt], 1);
        spS[lp] = (ushortT)bkt; sxS[lp] = s2.y & 255;
        syS[lp] = __float_as_int(a2.y);
    }
    __syncthreads();
    // flush: slots sorted by bucket -> near-contiguous global stores
    for (int i = t; i < EPB; i += 512) {
        edsD[i + deltaD[spD[i]]] = make_int2(sxD[i], syD[i]);
        edsS[i + deltaS[spS[i]]] = make_int2(sxS[i], syS[i]);
    }
}

// Per-bucket weighted degree via LDS float accumulation -> dinv directly.
__global__ __launch_bounds__(256) void k_deg(const int2* __restrict__ edsS,
                                             const int* __restrict__ binBaseS,
                                             float* __restrict__ dinv) {
    __shared__ float degL[256];
    int b = blockIdx.x, t = threadIdx.x;
    degL[t] = 0.f;
    __syncthreads();
    int s0 = binBaseS[b], s1 = binBaseS[b + 1];
    for (int i = s0 + t; i < s1; i += 256) {
        int2 e = edsS[i];
        atomicAdd(&degL[e.x], __int_as_float(e.y));
    }
    __syncthreads();
    float d = degL[t];
    dinv[b * 256 + t] = d > 0.f ? rsqrtf(d) : 0.f;
}

// ---------------------------------------------------------------------------
// Per-bucket exact CSR v2: 256-key counting, DIRECT scattered cedge writes
// (bucket region is 64KB L2-resident; L2 write-merging keeps HBM traffic at
// payload). ~3 KB LDS -> 4 blocks/CU (was 114 KB -> 1 block/CU + 400>256
// two-round imbalance). cedge = -attr * dinv[src] * dinv[dst].
// ---------------------------------------------------------------------------
__global__ __launch_bounds__(512) void k_csr(const int2* __restrict__ edsD,
                                             const int* __restrict__ binBaseD,
                                             const float* __restrict__ dinvG,
                                             int* __restrict__ rowp,
                                             int2* __restrict__ cedge) {
    __shared__ int cntL[256];
    __shared__ int curL[256];
    __shared__ float dL[256];
    int b = blockIdx.x, t = threadIdx.x;
    if (t < 256) { cntL[t] = 0; dL[t] = dinvG[b * 256 + t]; }
    __syncthreads();
    int s0 = binBaseD[b], s1 = binBaseD[b + 1];
    for (int i = s0 + t; i < s1; i += 512) {
        atomicAdd(&cntL[edsD[i].x & 255], 1);
    }
    __syncthreads();
    int v = (t < 256) ? cntL[t] : 0;
    for (int o = 1; o < 256; o <<= 1) {
        int x = (t < 256 && t >= o) ? cntL[t - o] : 0;
        __syncthreads();
        if (t < 256) cntL[t] += x;
        __syncthreads();
    }
    if (t < 256) {
        int excl = cntL[t] - v;
        curL[t] = s0 + excl;
        rowp[b * 256 + t] = s0 + excl;
    }
    __syncthreads();
    for (int i = s0 + t; i < s1; i += 512) {
        int2 e = edsD[i];
        int dl = e.x & 255;
        int sg = e.x >> 8;
        float w = -__int_as_float(e.y) * dinvG[sg] * dL[dl];
        int p = atomicAdd(&curL[dl], 1);
        cedge[p] = make_int2(sg, __float_as_int(w));
    }
}

// ---------------------------------------------------------------------------
// x -> slot-major bf16 hi/lo tables: Xhi/Xlo[s][n][64], s = k>>6
// ---------------------------------------------------------------------------
__global__ __launch_bounds__(256) void k_cast(const float* __restrict__ x,
                                              ushortT* __restrict__ Xhi,
                                              ushortT* __restrict__ Xlo) {
    int i = blockIdx.x * 256 + threadIdx.x;   // [0, N*32)
    int n = i >> 5;
    int kq = (i & 31) * 4;
    float4 v = ((const float4*)x)[i];
    int s = kq >> 6, kk = kq & 63;
    size_t o = (size_t)s * N64 + (size_t)n * 64 + kk;
    ushort4 h, l;
    h.x = f2b(v.x); l.x = f2b(v.x - b2f(h.x));
    h.y = f2b(v.y); l.y = f2b(v.y - b2f(h.y));
    h.z = f2b(v.z); l.z = f2b(v.z - b2f(h.z));
    h.w = f2b(v.w); l.w = f2b(v.w - b2f(h.w));
    *(ushort4*)(Xhi + o) = h;
    *(ushort4*)(Xlo + o) = l;
}

// ---------------------------------------------------------------------------
// Weight prep, all three layers in one launch (grid ranges are exact
// multiples of 256 -> no bounds checks): transposed [N][K] bf16 hi/lo.
// ---------------------------------------------------------------------------
__global__ void k_wprepAll(const float* __restrict__ w1f,
                           const float* __restrict__ w2f,
                           const float* __restrict__ w3f,
                           ushortT* __restrict__ Wt1h, ushortT* __restrict__ Wt1l,
                           ushortT* __restrict__ Wt2h, ushortT* __restrict__ Wt2l,
                           ushortT* __restrict__ Wt3h, ushortT* __restrict__ Wt3l) {
    int bid = blockIdx.x;
    float v;
    if (bid < 96) {                      // L1: 192*128 = 96*256
        int i = bid * 256 + threadIdx.x;
        int n = i / 128, k = i % 128;
        const float* w = w1f;
        if (n < 64)       v = w[k * 64 + n] - w[16384 + k * 64 + n];
        else if (n < 128) v = w[8192 + k * 64 + (n - 64)];
        else              v = w[16384 + k * 64 + (n - 128)];
        ushortT h = f2b(v);
        Wt1h[i] = h;
        Wt1l[i] = f2b(v - b2f(h));
    } else if (bid < 144) {              // L2: 192*64 = 48*256
        int i = (bid - 96) * 256 + threadIdx.x;
        int n = i / 64, k = i % 64;
        const float* w = w2f;
        if (n < 64)       v = w[k * 64 + n] - w[8192 + k * 64 + n];
        else if (n < 128) v = w[4096 + k * 64 + (n - 64)];
        else              v = w[8192 + k * 64 + (n - 128)];
        ushortT h = f2b(v);
        Wt2h[i] = h;
        Wt2l[i] = f2b(v - b2f(h));
    } else {                             // L3: 128*192 = 96*256
        int i = (bid - 144) * 256 + threadIdx.x;
        int n = i / 192, k = i % 192;
        v = w3f[(k >> 6) * 8192 + (k & 63) * 128 + n];
        ushortT h = f2b(v);
        Wt3h[i] = h;
        Wt3l[i] = f2b(v - b2f(h));
    }
}

// ---------------------------------------------------------------------------
// MFMA GEMM v3: one block = 256 rows x ALL NTOT cols. W (hi+lo) staged in
// LDS in 64-wide K-chunks (pad stride 72). 8 waves x (32 rows x NTOT cols).
// acc = Ahi*Whi + Alo*Whi + Ahi*Wlo  (~fp32 accuracy).
// MODE 0: ct<8 -> fp32 out[n*128 + ct*16+m]; ct>=8 -> bf16 outb[n*64 + ...]
// MODE 1: relu(acc+bias) staged in LDS tile, pooled in-kernel (run-length
//         over sorted batch ids) -> atomicAdd into pooled/gcnt. No H3.
// ---------------------------------------------------------------------------
template <int KTOT, int NTOT, int MODE>
__global__ __launch_bounds__(512) void k_mgemm(
    const ushortT* __restrict__ Ah0, const ushortT* __restrict__ Ah1,
    const ushortT* __restrict__ Ah2, const ushortT* __restrict__ Al0,
    const ushortT* __restrict__ Al1, const ushortT* __restrict__ Al2,
    const ushortT* __restrict__ Wth, const ushortT* __restrict__ Wtl,
    const float* __restrict__ bias, float* __restrict__ outf,
    ushortT* __restrict__ outb, const int* __restrict__ batch,
    float* __restrict__ pooled, float* __restrict__ gcnt) {
    constexpr int KPAD = 72;          // 64-chunk + 8 shorts pad
    constexpr int NCT = NTOT / 16;
    constexpr int SMEM_STAGE = 2 * NTOT * KPAD * 2;
    constexpr int SMEM_POOL = (MODE == 1) ? (256 * 128 * 4 + 256 * 4) : 0;
    constexpr int SMEM_BYTES = SMEM_STAGE > SMEM_POOL ? SMEM_STAGE : SMEM_POOL;
    __shared__ __align__(16) char smem[SMEM_BYTES];
    ushortT* Bh = (ushortT*)smem;
    ushortT* Bl = Bh + NTOT * KPAD;
    const ushortT* Ah[3] = {Ah0, Ah1, Ah2};
    const ushortT* Al[3] = {Al0, Al1, Al2};
    int t = threadIdx.x;
    int lane = t & 63;
    int wv = t >> 6;                  // 8 waves
    int m = lane & 15, q = lane >> 4;
    int r0 = blockIdx.x * 256 + wv * 32;
    int ar0 = r0 + m;                 // row frag 0
    int ar1 = r0 + 16 + m;            // row frag 1

    f32x4 acc[2][NCT];
#pragma unroll
    for (int rf = 0; rf < 2; rf++)
#pragma unroll
        for (int ct = 0; ct < NCT; ct++)
#pragma unroll
            for (int j = 0; j < 4; j++) acc[rf][ct][j] = 0.f;

#pragma unroll
    for (int kc = 0; kc < KTOT / 64; kc++) {
        __syncthreads();
        // stage W[*, kc*64 .. kc*64+64) hi+lo into LDS (uint4 = 8 shorts)
        for (int i = t; i < NTOT * 8; i += 512) {
            int col = i >> 3, k = (i & 7) * 8;
            *(uint4*)(Bh + col * KPAD + k) =
                *(const uint4*)(Wth + (size_t)col * KTOT + kc * 64 + k);
            *(uint4*)(Bl + col * KPAD + k) =
                *(const uint4*)(Wtl + (size_t)col * KTOT + kc * 64 + k);
        }
        __syncthreads();
        const ushortT* Ahc = Ah[kc];
        const ushortT* Alc = Al[kc];
#pragma unroll
        for (int ks2 = 0; ks2 < 2; ks2++) {
            int kk = ks2 * 32 + q * 8;
            bf16x8 ah0 = *(const bf16x8*)(Ahc + (size_t)ar0 * 64 + kk);
            bf16x8 al0 = *(const bf16x8*)(Alc + (size_t)ar0 * 64 + kk);
            bf16x8 ah1 = *(const bf16x8*)(Ahc + (size_t)ar1 * 64 + kk);
            bf16x8 al1 = *(const bf16x8*)(Alc + (size_t)ar1 * 64 + kk);
#pragma unroll
            for (int ct = 0; ct < NCT; ct++) {
                int bo = (ct * 16 + m) * KPAD + ks2 * 32 + q * 8;
                bf16x8 bh = *(const bf16x8*)(Bh + bo);
                bf16x8 bl = *(const bf16x8*)(Bl + bo);
                acc[0][ct] = __builtin_amdgcn_mfma_f32_16x16x32_bf16(ah0, bh, acc[0][ct], 0, 0, 0);
                acc[0][ct] = __builtin_amdgcn_mfma_f32_16x16x32_bf16(al0, bh, acc[0][ct], 0, 0, 0);
                acc[0][ct] = __builtin_amdgcn_mfma_f32_16x16x32_bf16(ah0, bl, acc[0][ct], 0, 0, 0);
                acc[1][ct] = __builtin_amdgcn_mfma_f32_16x16x32_bf16(ah1, bh, acc[1][ct], 0, 0, 0);
                acc[1][ct] = __builtin_amdgcn_mfma_f32_16x16x32_bf16(al1, bh, acc[1][ct], 0, 0, 0);
                acc[1][ct] = __builtin_amdgcn_mfma_f32_16x16x32_bf16(ah1, bl, acc[1][ct], 0, 0, 0);
            }
        }
    }

    if (MODE == 0) {
#pragma unroll
        for (int rf = 0; rf < 2; rf++)
#pragma unroll
            for (int ct = 0; ct < NCT; ct++)
#pragma unroll
                for (int rg = 0; rg < 4; rg++) {
                    int row = r0 + rf * 16 + q * 4 + rg;
                    float v = acc[rf][ct][rg];
                    if (ct < 8)
                        outf[(size_t)row * 128 + ct * 16 + m] = v;
                    else
                        outb[(size_t)row * 64 + (ct - 8) * 16 + m] = f2b(v);
                }
    } else {
        // ---- fused global_mean_pool: stage relu tile in LDS, run-length sum
        float* poolB = (float*)smem;                      // [256][128] f32
        int* batchL = (int*)(smem + 256 * 128 * 4);       // 256 ids
        __syncthreads();  // all waves done reading Bh/Bl
        for (int i = t; i < 256; i += 512)
            batchL[i] = batch[blockIdx.x * 256 + i];
#pragma unroll
        for (int rf = 0; rf < 2; rf++)
#pragma unroll
            for (int ct = 0; ct < NCT; ct++)
#pragma unroll
                for (int rg = 0; rg < 4; rg++) {
                    int rl = wv * 32 + rf * 16 + q * 4 + rg;
                    int col = ct * 16 + m;
                    poolB[rl * 128 + col] = fmaxf(acc[rf][ct][rg] + bias[col], 0.f);
                }
        __syncthreads();
        int col = t & 127, seg = t >> 7;   // 4 segments x 64 rows
        int base = seg * 64;
        int g = batchL[base];
        float a = 0.f;
        int c = 0;
        for (int k = 0; k < 64; k++) {
            int gn = batchL[base + k];
            if (gn != g) {
                atomicAdd(&pooled[(size_t)g * 128 + col], a);
                if (col == 0) atomicAdd(&gcnt[g], (float)c);
                g = gn; a = 0.f; c = 0;
            }
            a += poolB[(base + k) * 128 + col];
            c++;
        }
        atomicAdd(&pooled[(size_t)g * 128 + col], a);
        if (col == 0) atomicAdd(&gcnt[g], (float)c);
    }
}

// ---------------------------------------------------------------------------
// SpMM v3: 8 lanes per edge-row, each lane gathers uint4 = 8 bf16 features
// (16 B/lane coalescing sweet spot; one gather inst covers 8 edges, 1024 B).
// 16 edges per iteration via 2 slots -> 2 gather + 2 cedge insts per iter.
// q = lane>>3 edge slot in group of 8; f = (lane&7)*8 feature base.
// Cross-group shfl_xor(8,16,32) reduce; groups 0/1 write Yh/Yl.
// MODE 0: r = acc          MODE 1: r = aux + 2*acc
// MODE 2: r = 2*acc - aux  MODE 3: r = relu(aux + acc + bias)
// ---------------------------------------------------------------------------
template <int MODE, int SA, bool AUXB, bool WLO>
__global__ __launch_bounds__(256) void k_spmm(const int* __restrict__ rowp,
                                              const int2* __restrict__ cedge,
                                              const ushortT* __restrict__ Xb,
                                              const float* __restrict__ auxF,
                                              const ushortT* __restrict__ auxH,
                                              const ushortT* __restrict__ auxL,
                                              const float* __restrict__ bias,
                                              ushortT* __restrict__ Yh,
                                              ushortT* __restrict__ Yl) {
    int node = blockIdx.x * 4 + (threadIdx.x >> 6);
    int lane = threadIdx.x & 63;
    int q = lane >> 3;          // edge slot within group of 8
    int f = (lane & 7) * 8;     // feature base (8 features/lane)
    int s = rowp[node], e = rowp[node + 1];
    const ushortT* Xf = Xb + f;
    float a0 = 0.f, a1 = 0.f, a2 = 0.f, a3 = 0.f;
    float a4 = 0.f, a5 = 0.f, a6 = 0.f, a7 = 0.f;
    for (int i = s; i < e; i += 16) {
        int i0 = min(i + q, e - 1);
        int i1 = min(i + 8 + q, e - 1);
        int2 ed0 = cedge[i0];
        int2 ed1 = cedge[i1];
        float w0 = (i + q < e) ? __int_as_float(ed0.y) : 0.f;
        float w1 = (i + 8 + q < e) ? __int_as_float(ed1.y) : 0.f;
        uint4 u0 = *(const uint4*)(Xf + ((size_t)ed0.x << 6));
        uint4 u1 = *(const uint4*)(Xf + ((size_t)ed1.x << 6));
        a0 = fmaf(w0, loF(u0.x), a0);
        a1 = fmaf(w0, hiF(u0.x), a1);
        a2 = fmaf(w0, loF(u0.y), a2);
        a3 = fmaf(w0, hiF(u0.y), a3);
        a4 = fmaf(w0, loF(u0.z), a4);
        a5 = fmaf(w0, hiF(u0.z), a5);
        a6 = fmaf(w0, loF(u0.w), a6);
        a7 = fmaf(w0, hiF(u0.w), a7);
        a0 = fmaf(w1, loF(u1.x), a0);
        a1 = fmaf(w1, hiF(u1.x), a1);
        a2 = fmaf(w1, loF(u1.y), a2);
        a3 = fmaf(w1, hiF(u1.y), a3);
        a4 = fmaf(w1, loF(u1.z), a4);
        a5 = fmaf(w1, hiF(u1.z), a5);
        a6 = fmaf(w1, loF(u1.w), a6);
        a7 = fmaf(w1, hiF(u1.w), a7);
    }
    // reduce across the 8 groups (xor lane bits 3, 4, 5)
    a0 += __shfl_xor(a0, 8); a0 += __shfl_xor(a0, 16); a0 += __shfl_xor(a0, 32);
    a1 += __shfl_xor(a1, 8); a1 += __shfl_xor(a1, 16); a1 += __shfl_xor(a1, 32);
    a2 += __shfl_xor(a2, 8); a2 += __shfl_xor(a2, 16); a2 += __shfl_xor(a2, 32);
    a3 += __shfl_xor(a3, 8); a3 += __shfl_xor(a3, 16); a3 += __shfl_xor(a3, 32);
    a4 += __shfl_xor(a4, 8); a4 += __shfl_xor(a4, 16); a4 += __shfl_xor(a4, 32);
    a5 += __shfl_xor(a5, 8); a5 += __shfl_xor(a5, 16); a5 += __shfl_xor(a5, 32);
    a6 += __shfl_xor(a6, 8); a6 += __shfl_xor(a6, 16); a6 += __shfl_xor(a6, 32);
    a7 += __shfl_xor(a7, 8); a7 += __shfl_xor(a7, 16); a7 += __shfl_xor(a7, 32);

    if (q == 0 || (WLO && q == 1)) {
        float x0 = 0.f, x1 = 0.f, x2 = 0.f, x3 = 0.f;
        float x4 = 0.f, x5 = 0.f, x6 = 0.f, x7 = 0.f;
        if (MODE != 0) {
            if (AUXB) {
                uint4 ha = *(const uint4*)(auxH + (size_t)node * 64 + f);
                uint4 la = *(const uint4*)(auxL + (size_t)node * 64 + f);
                x0 = loF(ha.x) + loF(la.x);
                x1 = hiF(ha.x) + hiF(la.x);
                x2 = loF(ha.y) + loF(la.y);
                x3 = hiF(ha.y) + hiF(la.y);
                x4 = loF(ha.z) + loF(la.z);
                x5 = hiF(ha.z) + hiF(la.z);
                x6 = loF(ha.w) + loF(la.w);
                x7 = hiF(ha.w) + hiF(la.w);
            } else {
                float4 av0 = *(const float4*)(auxF + (size_t)node * SA + f);
                float4 av1 = *(const float4*)(auxF + (size_t)node * SA + f + 4);
                x0 = av0.x; x1 = av0.y; x2 = av0.z; x3 = av0.w;
                x4 = av1.x; x5 = av1.y; x6 = av1.z; x7 = av1.w;
            }
        }
        float r0, r1, r2, r3, r4, r5, r6, r7;
        if (MODE == 0) {
            r0 = a0; r1 = a1; r2 = a2; r3 = a3;
            r4 = a4; r5 = a5; r6 = a6; r7 = a7;
        } else if (MODE == 1) {
            r0 = x0 + 2.f * a0; r1 = x1 + 2.f * a1;
            r2 = x2 + 2.f * a2; r3 = x3 + 2.f * a3;
            r4 = x4 + 2.f * a4; r5 = x5 + 2.f * a5;
            r6 = x6 + 2.f * a6; r7 = x7 + 2.f * a7;
        } else if (MODE == 2) {
            r0 = 2.f * a0 - x0; r1 = 2.f * a1 - x1;
            r2 = 2.f * a2 - x2; r3 = 2.f * a3 - x3;
            r4 = 2.f * a4 - x4; r5 = 2.f * a5 - x5;
            r6 = 2.f * a6 - x6; r7 = 2.f * a7 - x7;
        } else {
            float4 bv0 = *(const float4*)(bias + f);
            float4 bv1 = *(const float4*)(bias + f + 4);
            r0 = fmaxf(x0 + a0 + bv0.x, 0.f);
            r1 = fmaxf(x1 + a1 + bv0.y, 0.f);
            r2 = fmaxf(x2 + a2 + bv0.z, 0.f);
            r3 = fmaxf(x3 + a3 + bv0.w, 0.f);
            r4 = fmaxf(x4 + a4 + bv1.x, 0.f);
            r5 = fmaxf(x5 + a5 + bv1.y, 0.f);
            r6 = fmaxf(x6 + a6 + bv1.z, 0.f);
            r7 = fmaxf(x7 + a7 + bv1.w, 0.f);
        }
        ushortT h0 = f2b(r0), h1 = f2b(r1), h2 = f2b(r2), h3 = f2b(r3);
        ushortT h4 = f2b(r4), h5 = f2b(r5), h6 = f2b(r6), h7 = f2b(r7);
        if (q == 0) {
            uint4 pk;
            pk.x = (uintT)h0 | ((uintT)h1 << 16);
            pk.y = (uintT)h2 | ((uintT)h3 << 16);
            pk.z = (uintT)h4 | ((uintT)h5 << 16);
            pk.w = (uintT)h6 | ((uintT)h7 << 16);
            *(uint4*)(Yh + (size_t)node * 64 + f) = pk;
        } else {
            uint4 pk;
            pk.x = (uintT)f2b(r0 - b2f(h0)) | ((uintT)f2b(r1 - b2f(h1)) << 16);
            pk.y = (uintT)f2b(r2 - b2f(h2)) | ((uintT)f2b(r3 - b2f(h3)) << 16);
            pk.z = (uintT)f2b(r4 - b2f(h4)) | ((uintT)f2b(r5 - b2f(h5)) << 16);
            pk.w = (uintT)f2b(r6 - b2f(h6)) | ((uintT)f2b(r7 - b2f(h7)) << 16);
            *(uint4*)(Yl + (size_t)node * 64 + f) = pk;
        }
    }
}

__global__ void k_final(const float* __restrict__ pooled, const float* __restrict__ gcnt,
                        const float* __restrict__ lin_w, const float* __restrict__ lin_b,
                        float* __restrict__ out) {
    int g = blockIdx.x * 4 + (threadIdx.x >> 6);
    int lane = threadIdx.x & 63;
    if (g >= N_GRAPHS) return;
    float inv = 1.f / fmaxf(gcnt[g], 1.f);
    float v0 = pooled[(size_t)g * 128 + lane] * inv;
    float v1 = pooled[(size_t)g * 128 + 64 + lane] * inv;
    float p0 = v0 * lin_w[lane * 2 + 0] + v1 * lin_w[(lane + 64) * 2 + 0];
    float p1 = v0 * lin_w[lane * 2 + 1] + v1 * lin_w[(lane + 64) * 2 + 1];
    for (int o = 32; o > 0; o >>= 1) {
        p0 += __shfl_down(p0, o);
        p1 += __shfl_down(p1, o);
    }
    if (lane == 0) {
        out[g * 2 + 0] = p0 + lin_b[0];
        out[g * 2 + 1] = p1 + lin_b[1];
    }
}

// ---------------------------------------------------------------------------
extern "C" void kernel_launch(void* const* d_in, const int* in_sizes, int n_in,
                              void* d_out, int out_size, void* d_ws, size_t ws_size,
                              hipStream_t stream) {
    const float* x     = (const float*)d_in[0];
    const int*   src   = (const int*)d_in[1];
    const int*   dst   = src + N_EDGES;
    const float* eattr = (const float*)d_in[2];
    const int*   batch = (const int*)d_in[3];
    const float* w1    = (const float*)d_in[4];
    const float* b1    = (const float*)d_in[5];
    const float* w2    = (const float*)d_in[6];
    const float* b2    = (const float*)d_in[7];
    const float* w3    = (const float*)d_in[8];
    const float* b3    = (const float*)d_in[9];
    const float* lin_w = (const float*)d_in[10];
    const float* lin_b = (const float*)d_in[11];
    float* out = (float*)d_out;

    char* ws = (char*)d_ws;
    size_t off = 0;
    auto alloc = [&](size_t bytes) -> char* {
        char* p = ws + off;
        off += (bytes + 255) & ~(size_t)255;
        return p;
    };
    int*   blkCntD   = (int*)  alloc((size_t)NBB * NBUCK * 4);   // 1.6 MB
    int*   blkCntS   = (int*)  alloc((size_t)NBB * NBUCK * 4);
    int*   blkCntDT  = (int*)  alloc((size_t)NBUCK * NBB * 4);   // transposed
    int*   blkCntST  = (int*)  alloc((size_t)NBUCK * NBB * 4);
    int*   blkRelD   = (int*)  alloc((size_t)NBB * NBUCK * 4);
    int*   blkRelS   = (int*)  alloc((size_t)NBB * NBUCK * 4);
    int*   bucketTotD = (int*) alloc(NBUCK * 4);
    int*   bucketTotS = (int*) alloc(NBUCK * 4);
    int*   binBaseD  = (int*)  alloc((NBUCK + 1) * 4);
    int*   binBaseS  = (int*)  alloc((NBUCK + 1) * 4);
    float* dinv      = (float*)alloc((size_t)N_NODES * 4);
    int*   rowp      = (int*)  alloc((size_t)(N_NODES + 1) * 4);
    ushortT* Wt1h   = (ushortT*)alloc(192 * 128 * 2);
    ushortT* Wt1l   = (ushortT*)alloc(192 * 128 * 2);
    ushortT* Wt2h   = (ushortT*)alloc(192 * 64 * 2);
    ushortT* Wt2l   = (ushortT*)alloc(192 * 64 * 2);
    ushortT* Wt3h   = (ushortT*)alloc(128 * 192 * 2);
    ushortT* Wt3l   = (ushortT*)alloc(128 * 192 * 2);
    float* pooled   = (float*)alloc((size_t)(N_GRAPHS * 128 + N_GRAPHS) * 4);
    float* gcnt     = pooled + (size_t)N_GRAPHS * 128;
    int2*  cedge    = (int2*) alloc((size_t)N_EDGES * 8);      // 26.2 MB
    char*  Buf1     = alloc((size_t)N_EDGES * 16);             // 52.4 MB
    char*  Buf2     = alloc((size_t)N_NODES * 128 * 4);        // 52.4 MB
    char*  Buf3     = alloc(4 * N64 * 2);                      // 52.4 MB

    // Buf1: edsD|edsS (build)  ->  Xhi/Xlo [2][N][64]  ->  GThi [3][N][64]
    int2* edsD = (int2*)Buf1;
    int2* edsS = edsD + N_EDGES;
    ushortT* Xhi  = (ushortT*)Buf1;
    ushortT* Xlo  = Xhi + 2 * N64;
    ushortT* GThi = (ushortT*)Buf1;          // slots 0,1,2 contiguous
    // Buf2: P fp32 [N][128] (P0c | P1)
    float* P  = (float*)Buf2;
    // Buf3: G0 | Qhi | H1hi | H1lo ; GTlo slots alias regions 0,2,3
    ushortT* G0    = (ushortT*)Buf3;
    ushortT* Qhi   = G0 + N64;
    ushortT* H1hi  = G0 + 2 * N64;
    ushortT* H1lo  = G0 + 3 * N64;
    ushortT* GTlo0 = G0;      // written after G0's last read
    ushortT* GTlo1 = H1hi;    // written after H1hi's last read
    ushortT* GTlo2 = H1lo;    // written after H1lo's last read

    hipMemsetAsync(pooled, 0, (size_t)(N_GRAPHS * 128 + N_GRAPHS) * 4, stream);

    // ---- CSR build: deterministic counting sorts, zero global atomics.
    k_binA<<<NBB, 256, 0, stream>>>(src, dst, blkCntD, blkCntS);
    k_tr<<<dim3(13, 32, 2), dim3(32, 8), 0, stream>>>(blkCntD, blkCntS,
                                                      blkCntDT, blkCntST);
    k_bbase<<<NBUCK, 512, 0, stream>>>(blkCntDT, blkRelD, bucketTotD);
    k_bbase<<<NBUCK, 512, 0, stream>>>(blkCntST, blkRelS, bucketTotS);
    k_bscan<<<1, 512, 0, stream>>>(bucketTotD, bucketTotS, binBaseD, binBaseS, rowp);
    k_binB2<<<NBB, 512, 0, stream>>>(src, dst, eattr, blkCntD, blkCntS,
                                     blkRelD, blkRelS, binBaseD, binBaseS,
                                     edsD, edsS);
    k_deg<<<NBUCK, 256, 0, stream>>>(edsS, binBaseS, dinv);
    k_csr<<<NBUCK, 512, 0, stream>>>(edsD, binBaseD, dinv, rowp, cedge);

    // ---- Prep: x cast (after edsD/edsS consumed), weight transpose+split
    k_cast<<<N_NODES * 32 / 256, 256, 0, stream>>>(x, Xhi, Xlo);
    k_wprepAll<<<240, 256, 0, stream>>>(w1, w2, w3, Wt1h, Wt1l, Wt2h, Wt2l,
                                        Wt3h, Wt3l);

    // ---- Layer 1 (128 -> 64): P0c,P1 fp32 + P2 bf16 table (G0)
    k_mgemm<128, 192, 0><<<N_NODES / 256, 512, 0, stream>>>(
        Xhi, Xhi + N64, nullptr, Xlo, Xlo + N64, nullptr, Wt1h, Wt1l, nullptr,
        P, G0, nullptr, nullptr, nullptr);
    // Q = P1 + 2*L*P2 -> Qhi
    k_spmm<1, 128, false, false><<<N_NODES / 4, 256, 0, stream>>>(
        rowp, cedge, G0, P + 64, nullptr, nullptr, nullptr, Qhi, nullptr);
    // H1 = relu(P0c + L*Q + b1) -> H1hi/H1lo
    k_spmm<3, 128, false, true><<<N_NODES / 4, 256, 0, stream>>>(
        rowp, cedge, Qhi, P, nullptr, nullptr, b1, H1hi, H1lo);

    // ---- Layer 2 (64 -> 64)
    k_mgemm<64, 192, 0><<<N_NODES / 256, 512, 0, stream>>>(
        H1hi, nullptr, nullptr, H1lo, nullptr, nullptr, Wt2h, Wt2l, nullptr,
        P, G0, nullptr, nullptr, nullptr);
    k_spmm<1, 128, false, false><<<N_NODES / 4, 256, 0, stream>>>(
        rowp, cedge, G0, P + 64, nullptr, nullptr, nullptr, Qhi, nullptr);
    // T0 = relu(P0c + L*Q + b2) -> GThi[0]/GTlo[0]
    k_spmm<3, 128, false, true><<<N_NODES / 4, 256, 0, stream>>>(
        rowp, cedge, Qhi, P, nullptr, nullptr, b2, GThi, GTlo0);

    // ---- Layer 3 (64 -> 128), spmm-first
    // T1 = L*T0 -> GThi[1]/GTlo[1]
    k_spmm<0, 64, false, true><<<N_NODES / 4, 256, 0, stream>>>(
        rowp, cedge, GThi, nullptr, nullptr, nullptr, nullptr, GThi + N64, GTlo1);
    // T2 = 2*L*T1 - T0 -> GThi[2]/GTlo[2]  (Aux = T0 via hi+lo)
    k_spmm<2, 64, true, true><<<N_NODES / 4, 256, 0, stream>>>(
        rowp, cedge, GThi + N64, nullptr, GThi, GTlo0, nullptr, GThi + 2 * N64, GTlo2);
    // relu([T0|T1|T2] @ w3 + b3) pooled in-kernel -> pooled/gcnt (no H3)
    k_mgemm<192, 128, 1><<<N_NODES / 256, 512, 0, stream>>>(
        GThi, GThi + N64, GThi + 2 * N64, GTlo0, GTlo1, GTlo2, Wt3h, Wt3l, b3,
        nullptr, nullptr, batch, pooled, gcnt);

    // ---- Final linear
    k_final<<<N_GRAPHS / 4, 256, 0, stream>>>(pooled, gcnt, lin_w, lin_b, out);
}